// Round 5
// baseline (1469.020 us; speedup 1.0000x reference)
//
#include <hip/hip_runtime.h>
#include <hip/hip_bf16.h>

typedef unsigned int uint32;

// ---------------- problem constants ----------------
constexpr int Nn = 50000;
constexpr int Ee = 800000;
constexpr int EF = Ee + Nn;   // edges incl self loops

// ---------------- ws layout (BYTE offsets, ~53.5 MB) ----------------
constexpr long B_SC  = 0;            // bf16 [EF*8]     13,600,000 B  scores
constexpr long B_XL  = 13600000;     // bf16 [Nn*128]   12,800,000 B  xl
constexpr long B_X1  = 26400000;     // bf16 [Nn*128]   12,800,000 B  x1 (post-LN1)
constexpr long B_LA  = 39200000;     // bf16 [Nn*32]     3,200,000 B  loop_attr
constexpr long B_EIX = 42400000;     // int  [2*Ee]      6,400,000 B  normalized idx
constexpr long B_CNT = 48800000;     // int  [Nn]
constexpr long B_OFS = 49000000;     // int  [Nn+1]
constexpr long B_CUR = 49200016;     // int  [Nn]
constexpr long B_CSR = 49400016;     // int  [EF]        3,400,000 B
constexpr long B_WF  = 52800016;     // fp32 [169600]      678,400 B  canonical weights
constexpr long B_FLG = 53478416;     // int[2]: {x_is_f32, ea_is_f32}
// end ~53,478,424 B
// d_out (fp32, 25.6 MB): first 12.8 MB doubles as bf16 xr scratch (dead after k_score).

// canonical weight float offsets
constexpr int WF_Wl = 0, WF_bl = 16384, WF_Wr = 16512, WF_br = 32896;
constexpr int WF_We = 33024, WF_att = 37120, WF_bias = 37248;
constexpr int WF_W1 = 37376, WF_b1 = 102912, WF_W2 = 103424, WF_b2 = 168960;
constexpr int WF_g1 = 169088, WF_be1 = 169216, WF_g2 = 169344, WF_be2 = 169472;
constexpr int WF_TOT = 169600;

static __device__ __forceinline__ float b2f(__hip_bfloat16 v) { return __bfloat162float(v); }
static __device__ __forceinline__ float2 up2(uint32 u) {
    union { uint32 i; float f; } a, b;
    a.i = (u & 0xFFFFu) << 16; b.i = u & 0xFFFF0000u;
    return make_float2(a.f, b.f);
}
static __device__ __forceinline__ float san(float v) {  // NaN -> -1e4, clamp
    return fminf(fmaxf(v, -1e4f), 1e4f);
}

// ---------------- 0a: sniff float dtype of x and edge_attr ----------------
// bf16 buffer: low ushort of each 32-bit word is a bf16 of ~N(0,1) data ->
// exponent byte (bits 14..7) in [100,135] with ~99% prob. fp32 buffer: those
// bits are mid-mantissa, ~14% hit rate. Vote over 512 words.
__global__ void k_sniff(const uint32* __restrict__ xu, const uint32* __restrict__ eu,
                        int* __restrict__ flg) {
    int lane = threadIdx.x;   // 64 threads, 1 block
    int xbf = 0, ebf = 0;
    #pragma unroll
    for (int j = 0; j < 8; j++) {
        uint32 ux = xu[lane * 8 + j];
        int ex = (ux >> 7) & 0xFF;
        xbf += (ex >= 100 && ex <= 135) ? 1 : 0;
        uint32 ue = eu[lane * 8 + j];
        int ee = (ue >> 7) & 0xFF;
        ebf += (ee >= 100 && ee <= 135) ? 1 : 0;
    }
    #pragma unroll
    for (int mk = 1; mk < 64; mk <<= 1) {
        xbf += __shfl_xor(xbf, mk);
        ebf += __shfl_xor(ebf, mk);
    }
    if (lane == 0) {
        flg[0] = (xbf > 256) ? 0 : 1;   // 1 = fp32
        flg[1] = (ebf > 256) ? 0 : 1;
    }
}

// ---------------- 0b: normalize edge_index (int32 or int64) + clamp ----------------
__global__ void k_cvt(const int* __restrict__ raw, int* __restrict__ eix) {
    __shared__ int is64;
    if (threadIdx.x == 0) {
        int z = 1;
        #pragma unroll
        for (int j = 1; j < 64; j += 2) z &= (raw[j] == 0);
        is64 = z;
    }
    __syncthreads();
    int i = blockIdx.x * 256 + threadIdx.x;
    if (i < 2 * Ee) {
        int v = is64 ? raw[2 * i] : raw[i];
        v = v < 0 ? 0 : (v >= Nn ? Nn - 1 : v);
        eix[i] = v;
    }
}

// ---------------- 0c: canonicalize all weight tensors to fp32 ----------------
struct WSrc { const void* p[15]; };
__global__ void k_wcanon(WSrc s, const int* __restrict__ flagp, float* __restrict__ dst) {
    const int cum[16] = {0, 16384, 16512, 32896, 33024, 37120, 37248, 37376,
                         102912, 103424, 168960, 169088, 169216, 169344, 169472, 169600};
    int i = blockIdx.x * 256 + threadIdx.x;
    if (i >= WF_TOT) return;
    int isf32 = flagp[0];
    int seg = 0;
    #pragma unroll
    for (int j = 1; j < 16; j++) seg += (i >= cum[j]);
    int off = i - cum[seg];
    float v = isf32 ? ((const float*)s.p[seg])[off]
                    : b2f(((const __hip_bfloat16*)s.p[seg])[off]);
    dst[i] = v;
}

// ---------------- 1: count incoming edges ----------------
__global__ void k_count(const int* __restrict__ dst, int* __restrict__ cnt) {
    int e = blockIdx.x * 256 + threadIdx.x;
    if (e < Ee) atomicAdd(&cnt[dst[e]], 1);
}

// ---------------- 2: exclusive scan -> CSR offsets (deg = cnt+1) ----------------
__global__ void __launch_bounds__(1024) k_scan(const int* __restrict__ cnt,
                                               int* __restrict__ offs, int* __restrict__ cursor) {
    __shared__ int part[1024];
    int t = threadIdx.x;
    const int CH = (Nn + 1023) / 1024; // 49
    int base = t * CH;
    int s = 0;
    for (int i = 0; i < CH; i++) { int n = base + i; if (n < Nn) s += cnt[n] + 1; }
    part[t] = s;
    __syncthreads();
    for (int off = 1; off < 1024; off <<= 1) {
        int v = (t >= off) ? part[t - off] : 0;
        __syncthreads();
        part[t] += v;
        __syncthreads();
    }
    int run = part[t] - s;
    for (int i = 0; i < CH; i++) {
        int n = base + i;
        if (n < Nn) { offs[n] = run; run += cnt[n] + 1; cursor[n] = 0; }
    }
    if (t == 1023) offs[Nn] = part[1023];
}

// ---------------- 3: fill CSR (edge ids; id>=Ee means self loop) ----------------
__global__ void k_fill(const int* __restrict__ eix, int* __restrict__ cursor,
                       const int* __restrict__ offs, int* __restrict__ csr) {
    int e = blockIdx.x * 256 + threadIdx.x;
    if (e >= EF) return;
    int d = (e < Ee) ? eix[Ee + e] : (e - Ee);
    int p = atomicAdd(&cursor[d], 1);
    csr[offs[d] + p] = e;
}

// ---------------- 4: self-loop attr = mean of incoming edge_attr ----------------
__global__ void __launch_bounds__(256) k_loopattr(const void* __restrict__ eattr,
                                                  const int* __restrict__ csr,
                                                  const int* __restrict__ offs,
                                                  const int* __restrict__ flagp,
                                                  __hip_bfloat16* __restrict__ la) {
    int isf32 = flagp[1];
    int lane = threadIdx.x & 63;
    int n = (blockIdx.x * 256 + threadIdx.x) >> 6;
    if (n >= Nn) return;
    int off = offs[n], deg = offs[n + 1] - off;
    int k = lane & 31, half = lane >> 5;
    const float* ef = (const float*)eattr;
    const __hip_bfloat16* eb = (const __hip_bfloat16*)eattr;
    float acc = 0.f;
    for (int i = half; i < deg; i += 2) {
        int e = csr[off + i];
        if (e < Ee) acc += isf32 ? ef[(long)e * 32 + k] : b2f(eb[(long)e * 32 + k]);
    }
    acc += __shfl_xor(acc, 32);
    float inv = 1.0f / fmaxf((float)(deg - 1), 1.0f);   // cnt = deg-1
    if (lane < 32) la[(long)n * 32 + k] = __float2bfloat16(san(acc * inv));
}

// ---------------- 5: xl/xr = x @ W + b, bf16 out ----------------
__global__ void __launch_bounds__(256) k_lin(const void* __restrict__ x,
                                             const float* __restrict__ Wf,
                                             const float* __restrict__ bf_,
                                             const int* __restrict__ flagp,
                                             __hip_bfloat16* __restrict__ out) {
    __shared__ unsigned short Wlds[128][130];   // bf16 bits, 33.3 KB
    __shared__ float xrow[2][128];
    int isf32 = flagp[0];
    int t = threadIdx.x, col = t & 127, sub = t >> 7;
    for (int i = t; i < 16384; i += 256) {
        __hip_bfloat16 w = __float2bfloat16(Wf[i]);
        Wlds[i >> 7][i & 127] = *(unsigned short*)&w;
    }
    float bias = bf_[col];
    const float* xf = (const float*)x;
    const __hip_bfloat16* xb = (const __hip_bfloat16*)x;
    int rpb = (Nn + gridDim.x - 1) / gridDim.x;
    int r0 = blockIdx.x * rpb, r1 = min(r0 + rpb, Nn);
    __syncthreads();
    for (int r = r0; r < r1; r += 2) {
        int rr = r + sub;
        if (rr < r1) xrow[sub][col] = isf32 ? xf[(long)rr * 128 + col]
                                            : b2f(xb[(long)rr * 128 + col]);
        __syncthreads();
        float acc = bias;
        #pragma unroll 16
        for (int k = 0; k < 128; k++) {
            union { uint32 i; float f; } u; u.i = ((uint32)Wlds[k][col]) << 16;
            acc += xrow[sub][k] * u.f;
        }
        if (rr < r1) out[(long)rr * 128 + col] = __float2bfloat16(san(acc));
        __syncthreads();
    }
}

// ---------------- 6: per-edge attention scores (bf16 out) ----------------
__global__ void __launch_bounds__(256) k_score(const void* __restrict__ eattr,
                                               const int* __restrict__ eix,
                                               const __hip_bfloat16* __restrict__ la,
                                               const float* __restrict__ Wef,
                                               const float* __restrict__ attf,
                                               const int* __restrict__ flagp,
                                               const uint32* __restrict__ xlu,
                                               const uint32* __restrict__ xru,
                                               __hip_bfloat16* __restrict__ score) {
    __shared__ float WeL[32][128];
    __shared__ float attL[128];
    int isf32 = flagp[1];
    int t = threadIdx.x;
    for (int i = t; i < 32 * 128; i += 256) WeL[i >> 7][i & 127] = Wef[i];
    if (t < 128) attL[t] = attf[t];
    __syncthreads();
    int lane = t & 63;
    int gw = (blockIdx.x * 256 + t) >> 6;
    int nw = (gridDim.x * 256) >> 6;
    int k32 = lane & 31;
    int d0 = 2 * lane;
    float a0w = attL[d0], a1w = attL[d0 + 1];
    const float* ef = (const float*)eattr;
    const __hip_bfloat16* eb = (const __hip_bfloat16*)eattr;
    for (int e = gw; e < EF; e += nw) {
        float av;
        int srcn, dstn;
        if (e < Ee) {
            av = isf32 ? ef[(long)e * 32 + k32] : b2f(eb[(long)e * 32 + k32]);
            srcn = eix[e]; dstn = eix[Ee + e];
        } else {
            int n = e - Ee;
            av = b2f(la[(long)n * 32 + k32]);
            srcn = n; dstn = n;
        }
        float acc0 = 0.f, acc1 = 0.f;
        #pragma unroll
        for (int k = 0; k < 32; k++) {
            float ak = __shfl(av, k, 32);
            float2 w = ((const float2*)&WeL[k][0])[lane];
            acc0 += ak * w.x; acc1 += ak * w.y;
        }
        float2 xls = up2(xlu[(long)srcn * 64 + lane]);
        float2 xrs = up2(xru[(long)dstn * 64 + lane]);
        acc0 += xls.x + xrs.x; acc1 += xls.y + xrs.y;
        acc0 = acc0 > 0.f ? acc0 : 0.2f * acc0;
        acc1 = acc1 > 0.f ? acc1 : 0.2f * acc1;
        float p = acc0 * a0w + acc1 * a1w;
        p += __shfl_xor(p, 1);
        p += __shfl_xor(p, 2);
        p += __shfl_xor(p, 4);
        if ((lane & 7) == 0) score[(long)e * 8 + (lane >> 3)] = __float2bfloat16(san(p));
    }
}

// ---------------- 7: softmax + aggregate + bias + residual + LN1 -> x1 (bf16, ws) --------
__global__ void __launch_bounds__(256) k_agg(const unsigned short* __restrict__ scu,
                                             const int* __restrict__ csr, const int* __restrict__ offs,
                                             const int* __restrict__ eix,
                                             const uint32* __restrict__ xlu,
                                             const void* __restrict__ x,
                                             const float* __restrict__ wf,
                                             const int* __restrict__ flagp,
                                             __hip_bfloat162* __restrict__ x1) {
    int isf32 = flagp[0];
    int lane = threadIdx.x & 63;
    int n = (blockIdx.x * 256 + threadIdx.x) >> 6;   // grid exact: n < Nn
    int off = offs[n], deg = offs[n + 1] - off;
    float m[8], s[8];
    #pragma unroll
    for (int h = 0; h < 8; h++) { m[h] = -1e30f; s[h] = 0.f; }
    for (int i = lane; i < deg; i += 64) {
        int e = csr[off + i];
        uint4 q = *((const uint4*)(scu + (long)e * 8));
        float2 p0 = up2(q.x), p1 = up2(q.y), p2 = up2(q.z), p3 = up2(q.w);
        float sc[8] = {p0.x, p0.y, p1.x, p1.y, p2.x, p2.y, p3.x, p3.y};
        #pragma unroll
        for (int h = 0; h < 8; h++) {
            float mn = fmaxf(m[h], sc[h]);
            s[h] = s[h] * __expf(m[h] - mn) + __expf(sc[h] - mn);
            m[h] = mn;
        }
    }
    #pragma unroll
    for (int mask = 1; mask < 64; mask <<= 1) {
        #pragma unroll
        for (int h = 0; h < 8; h++) {
            float m2 = __shfl_xor(m[h], mask);
            float s2 = __shfl_xor(s[h], mask);
            float mn = fmaxf(m[h], m2);
            s[h] = s[h] * __expf(m[h] - mn) + s2 * __expf(m2 - mn);
            m[h] = mn;
        }
    }
    int h = lane >> 3;
    float mh = m[0], sh = s[0];
    #pragma unroll
    for (int j = 1; j < 8; j++) { if (h == j) { mh = m[j]; sh = s[j]; } }
    float inv = 1.0f / sh;
    float acc0 = 0.f, acc1 = 0.f;
    const __hip_bfloat16* scb = (const __hip_bfloat16*)scu;
    for (int i = 0; i < deg; i++) {
        int e = csr[off + i];
        float alpha = __expf(b2f(scb[(long)e * 8 + h]) - mh) * inv;
        int srcn = (e < Ee) ? eix[e] : (e - Ee);
        float2 v = up2(xlu[(long)srcn * 64 + lane]);
        acc0 += alpha * v.x; acc1 += alpha * v.y;
    }
    int d0 = 2 * lane;
    float2 xv;
    if (isf32) xv = ((const float2*)x)[(long)n * 64 + lane];
    else       xv = up2(((const uint32*)x)[(long)n * 64 + lane]);
    acc0 += xv.x + wf[WF_bias + d0];
    acc1 += xv.y + wf[WF_bias + d0 + 1];
    // fused LayerNorm1
    float sum = acc0 + acc1, sq = acc0 * acc0 + acc1 * acc1;
    #pragma unroll
    for (int mk = 1; mk < 64; mk <<= 1) { sum += __shfl_xor(sum, mk); sq += __shfl_xor(sq, mk); }
    float mean = sum * (1.0f / 128.0f);
    float var = sq * (1.0f / 128.0f) - mean * mean;
    float rstd = rsqrtf(var + 1e-5f);
    float o0 = san((acc0 - mean) * rstd * wf[WF_g1 + d0] + wf[WF_be1 + d0]);
    float o1 = san((acc1 - mean) * rstd * wf[WF_g1 + d0 + 1] + wf[WF_be1 + d0 + 1]);
    __hip_bfloat162 pk; pk.x = __float2bfloat16(o0); pk.y = __float2bfloat16(o1);
    x1[(long)n * 64 + lane] = pk;
}

// ---------------- 8: FFN + residual + LN2 -> fp32 out ----------------
__global__ void __launch_bounds__(256) k_ffn(const __hip_bfloat16* __restrict__ x1,
                                             const float* __restrict__ wf,
                                             float2* __restrict__ out) {
    __shared__ float xs[16][128];
    __shared__ float hbuf[16][512];
    int t = threadIdx.x;
    long nb = (long)blockIdx.x * 16;
    for (int i = t; i < 16 * 128; i += 256) xs[i >> 7][i & 127] = b2f(x1[nb * 128 + i]);
    __syncthreads();
    const float* W1 = wf + WF_W1;
    const float* W2 = wf + WF_W2;
    // phase 1: h = relu(x1 @ W1 + b1)
    int f0 = t, f1 = t + 256;
    float acc[16], accB[16];
    float bb0 = wf[WF_b1 + f0], bb1 = wf[WF_b1 + f1];
    #pragma unroll
    for (int j = 0; j < 16; j++) { acc[j] = bb0; accB[j] = bb1; }
    #pragma unroll 4
    for (int k = 0; k < 128; k++) {
        float w0 = W1[(long)k * 512 + f0], w1 = W1[(long)k * 512 + f1];
        #pragma unroll
        for (int j = 0; j < 16; j++) { float xv = xs[j][k]; acc[j] += xv * w0; accB[j] += xv * w1; }
    }
    #pragma unroll
    for (int j = 0; j < 16; j++) { hbuf[j][f0] = fmaxf(acc[j], 0.f); hbuf[j][f1] = fmaxf(accB[j], 0.f); }
    __syncthreads();
    // phase 2: y = x1 + h @ W2 + b2
    int d = t & 127, grp = t >> 7, n0 = grp * 8;
    float o[8];
    float bb2 = wf[WF_b2 + d];
    #pragma unroll
    for (int j = 0; j < 8; j++) o[j] = bb2;
    #pragma unroll 4
    for (int f = 0; f < 512; f++) {
        float w = W2[(long)f * 128 + d];
        #pragma unroll
        for (int j = 0; j < 8; j++) o[j] += hbuf[n0 + j][f] * w;
    }
    #pragma unroll
    for (int j = 0; j < 8; j++) o[j] += xs[n0 + j][d];
    __syncthreads();
    #pragma unroll
    for (int j = 0; j < 8; j++) xs[n0 + j][d] = o[j];   // reuse xs as y
    __syncthreads();
    // fused LayerNorm2: 4 waves x 4 rows, fp32 output
    int lane = t & 63, wv = t >> 6;
    int d0 = 2 * lane;
    float gg0 = wf[WF_g2 + d0], gg1 = wf[WF_g2 + d0 + 1];
    float eb0 = wf[WF_be2 + d0], eb1 = wf[WF_be2 + d0 + 1];
    for (int i = 0; i < 4; i++) {
        int r = wv * 4 + i;
        float v0 = xs[r][d0], v1 = xs[r][d0 + 1];
        float sum = v0 + v1, sq = v0 * v0 + v1 * v1;
        #pragma unroll
        for (int mk = 1; mk < 64; mk <<= 1) { sum += __shfl_xor(sum, mk); sq += __shfl_xor(sq, mk); }
        float mean = sum * (1.0f / 128.0f);
        float var = sq * (1.0f / 128.0f) - mean * mean;
        float rstd = rsqrtf(var + 1e-5f);
        float o0 = san((v0 - mean) * rstd * gg0 + eb0);
        float o1 = san((v1 - mean) * rstd * gg1 + eb1);
        out[(nb + r) * 64 + lane] = make_float2(o0, o1);
    }
}

// ---------------- launch ----------------
extern "C" void kernel_launch(void* const* d_in, const int* in_sizes, int n_in,
                              void* d_out, int out_size, void* d_ws, size_t ws_size,
                              hipStream_t stream) {
    const void* x     = d_in[0];
    const int*  eraw  = (const int*)d_in[1];
    const void* eattr = d_in[2];

    char* wsb = (char*)d_ws;
    __hip_bfloat16* sc  = (__hip_bfloat16*)(wsb + B_SC);
    __hip_bfloat16* xl  = (__hip_bfloat16*)(wsb + B_XL);
    __hip_bfloat16* x1  = (__hip_bfloat16*)(wsb + B_X1);
    __hip_bfloat16* la  = (__hip_bfloat16*)(wsb + B_LA);
    int*   eix  = (int*)(wsb + B_EIX);
    int*   cnt  = (int*)(wsb + B_CNT);
    int*   offs = (int*)(wsb + B_OFS);
    int*   cur  = (int*)(wsb + B_CUR);
    int*   csr  = (int*)(wsb + B_CSR);
    float* wf   = (float*)(wsb + B_WF);
    int*   flg  = (int*)(wsb + B_FLG);
    __hip_bfloat16* xr  = (__hip_bfloat16*)d_out;   // bf16 scratch in fp32 d_out, dead after k_score

    WSrc wsrc;
    for (int i = 0; i < 15; i++) wsrc.p[i] = d_in[3 + i];

    hipMemsetAsync(cnt, 0, Nn * sizeof(int), stream);

    k_sniff<<<1, 64, 0, stream>>>((const uint32*)x, (const uint32*)eattr, flg);
    k_cvt<<<(2 * Ee + 255) / 256, 256, 0, stream>>>(eraw, eix);
    k_wcanon<<<(WF_TOT + 255) / 256, 256, 0, stream>>>(wsrc, flg, wf);
    k_count<<<(Ee + 255) / 256, 256, 0, stream>>>(eix + Ee, cnt);
    k_scan<<<1, 1024, 0, stream>>>(cnt, offs, cur);
    k_fill<<<(EF + 255) / 256, 256, 0, stream>>>(eix, cur, offs, csr);
    k_loopattr<<<(Nn + 3) / 4, 256, 0, stream>>>(eattr, csr, offs, flg, la);
    k_lin<<<512, 256, 0, stream>>>(x, wf + WF_Wl, wf + WF_bl, flg, xl);
    k_lin<<<512, 256, 0, stream>>>(x, wf + WF_Wr, wf + WF_br, flg, xr);
    k_score<<<2048, 256, 0, stream>>>(eattr, eix, la, wf + WF_We, wf + WF_att, flg,
                                      (const uint32*)xl, (const uint32*)xr, sc);
    k_agg<<<(Nn + 3) / 4, 256, 0, stream>>>((const unsigned short*)sc, csr, offs, eix,
                                            (const uint32*)xl, x, wf, flg,
                                            (__hip_bfloat162*)x1);
    k_ffn<<<Nn / 16, 256, 0, stream>>>(x1, wf, (float2*)d_out);
}

// Round 6
// 1135.450 us; speedup vs baseline: 1.2938x; 1.2938x over previous
//
#include <hip/hip_runtime.h>
#include <hip/hip_bf16.h>

typedef unsigned int uint32;
typedef unsigned short ushort;
typedef __attribute__((ext_vector_type(8))) short short8;   // 8 bf16 (4 VGPRs)
typedef __attribute__((ext_vector_type(4))) float float4v;  // MFMA acc

// ---------------- problem constants ----------------
constexpr int Nn = 50000;
constexpr int Ee = 800000;
constexpr int EF = Ee + Nn;          // 850000, divisible by 16
constexpr int NT = EF / 16;          // 53125 MFMA edge-tiles
constexpr int TE = Ee / 16;          // 50000 (tiles below are real edges)

// ---------------- ws layout (BYTE offsets, ~53.5 MB) ----------------
constexpr long B_SC  = 0;            // bf16 [EF*8]     13,600,000 B  scores
constexpr long B_XL  = 13600000;     // bf16 [Nn*128]   12,800,000 B  xl
constexpr long B_X1  = 26400000;     // bf16 [Nn*128]   12,800,000 B  x1 (post-LN1)
constexpr long B_LA  = 39200000;     // bf16 [Nn*32]     3,200,000 B  loop_attr
constexpr long B_EIX = 42400000;     // int  [2*Ee]      6,400,000 B  normalized idx
constexpr long B_CNT = 48800000;     // int  [Nn]
constexpr long B_OFS = 49000000;     // int  [Nn+1]
constexpr long B_CUR = 49200016;     // int  [Nn]
constexpr long B_CSR = 49400016;     // int  [EF]        3,400,000 B
constexpr long B_WF  = 52800016;     // fp32 [169600]      678,400 B  canonical weights
constexpr long B_FLG = 53478416;     // int[2]: {x_is_f32, ea_is_f32}

// canonical weight float offsets
constexpr int WF_Wl = 0, WF_bl = 16384, WF_Wr = 16512, WF_br = 32896;
constexpr int WF_We = 33024, WF_att = 37120, WF_bias = 37248;
constexpr int WF_W1 = 37376, WF_b1 = 102912, WF_W2 = 103424, WF_b2 = 168960;
constexpr int WF_g1 = 169088, WF_be1 = 169216, WF_g2 = 169344, WF_be2 = 169472;
constexpr int WF_TOT = 169600;

static __device__ __forceinline__ float b2f(__hip_bfloat16 v) { return __bfloat162float(v); }
static __device__ __forceinline__ float2 up2(uint32 u) {
    union { uint32 i; float f; } a, b;
    a.i = (u & 0xFFFFu) << 16; b.i = u & 0xFFFF0000u;
    return make_float2(a.f, b.f);
}
static __device__ __forceinline__ ushort f2bu(float f) {
    __hip_bfloat16 h = __float2bfloat16(f); return *(ushort*)&h;
}
static __device__ __forceinline__ float san(float v) { return fminf(fmaxf(v, -1e4f), 1e4f); }

// ---------------- 0a: sniff float dtype of x and edge_attr ----------------
__global__ void k_sniff(const uint32* __restrict__ xu, const uint32* __restrict__ eu,
                        int* __restrict__ flg) {
    int lane = threadIdx.x;
    int xbf = 0, ebf = 0;
    #pragma unroll
    for (int j = 0; j < 8; j++) {
        uint32 ux = xu[lane * 8 + j];
        int ex = (ux >> 7) & 0xFF;
        xbf += (ex >= 100 && ex <= 135) ? 1 : 0;
        uint32 ue = eu[lane * 8 + j];
        int ee = (ue >> 7) & 0xFF;
        ebf += (ee >= 100 && ee <= 135) ? 1 : 0;
    }
    #pragma unroll
    for (int mk = 1; mk < 64; mk <<= 1) { xbf += __shfl_xor(xbf, mk); ebf += __shfl_xor(ebf, mk); }
    if (lane == 0) { flg[0] = (xbf > 256) ? 0 : 1; flg[1] = (ebf > 256) ? 0 : 1; }
}

// ---------------- 0b: normalize edge_index + clamp + count (fused) ----------------
__global__ void k_cvt(const int* __restrict__ raw, int* __restrict__ eix,
                      int* __restrict__ cnt) {
    __shared__ int is64;
    if (threadIdx.x == 0) {
        int z = 1;
        #pragma unroll
        for (int j = 1; j < 64; j += 2) z &= (raw[j] == 0);
        is64 = z;
    }
    __syncthreads();
    int i = blockIdx.x * 256 + threadIdx.x;
    if (i < 2 * Ee) {
        int v = is64 ? raw[2 * i] : raw[i];
        v = v < 0 ? 0 : (v >= Nn ? Nn - 1 : v);
        eix[i] = v;
        if (i >= Ee) atomicAdd(&cnt[v], 1);   // dst-degree count fused here
    }
}

// ---------------- 0c: canonicalize all weight tensors to fp32 ----------------
struct WSrc { const void* p[15]; };
__global__ void k_wcanon(WSrc s, const int* __restrict__ flagp, float* __restrict__ dst) {
    const int cum[16] = {0, 16384, 16512, 32896, 33024, 37120, 37248, 37376,
                         102912, 103424, 168960, 169088, 169216, 169344, 169472, 169600};
    int i = blockIdx.x * 256 + threadIdx.x;
    if (i >= WF_TOT) return;
    int isf32 = flagp[0];
    int seg = 0;
    #pragma unroll
    for (int j = 1; j < 16; j++) seg += (i >= cum[j]);
    int off = i - cum[seg];
    float v = isf32 ? ((const float*)s.p[seg])[off]
                    : b2f(((const __hip_bfloat16*)s.p[seg])[off]);
    dst[i] = v;
}

// ---------------- 2: exclusive scan -> CSR offsets (deg = cnt+1) ----------------
__global__ void __launch_bounds__(1024) k_scan(const int* __restrict__ cnt,
                                               int* __restrict__ offs, int* __restrict__ cursor) {
    __shared__ int part[1024];
    int t = threadIdx.x;
    const int CH = (Nn + 1023) / 1024;
    int base = t * CH;
    int s = 0;
    for (int i = 0; i < CH; i++) { int n = base + i; if (n < Nn) s += cnt[n] + 1; }
    part[t] = s;
    __syncthreads();
    for (int off = 1; off < 1024; off <<= 1) {
        int v = (t >= off) ? part[t - off] : 0;
        __syncthreads();
        part[t] += v;
        __syncthreads();
    }
    int run = part[t] - s;
    for (int i = 0; i < CH; i++) {
        int n = base + i;
        if (n < Nn) { offs[n] = run; run += cnt[n] + 1; cursor[n] = 0; }
    }
    if (t == 1023) offs[Nn] = part[1023];
}

// ---------------- 3: fill CSR ----------------
__global__ void k_fill(const int* __restrict__ eix, int* __restrict__ cursor,
                       const int* __restrict__ offs, int* __restrict__ csr) {
    int e = blockIdx.x * 256 + threadIdx.x;
    if (e >= EF) return;
    int d = (e < Ee) ? eix[Ee + e] : (e - Ee);
    int p = atomicAdd(&cursor[d], 1);
    csr[offs[d] + p] = e;
}

// ---------------- 4: self-loop attr = mean of incoming edge_attr ----------------
__global__ void __launch_bounds__(256) k_loopattr(const void* __restrict__ eattr,
                                                  const int* __restrict__ csr,
                                                  const int* __restrict__ offs,
                                                  const int* __restrict__ flagp,
                                                  __hip_bfloat16* __restrict__ la) {
    int isf32 = flagp[1];
    int lane = threadIdx.x & 63;
    int n = (blockIdx.x * 256 + threadIdx.x) >> 6;
    if (n >= Nn) return;
    int off = offs[n], deg = offs[n + 1] - off;
    int k = lane & 31, half = lane >> 5;
    const float* ef = (const float*)eattr;
    const __hip_bfloat16* eb = (const __hip_bfloat16*)eattr;
    float acc = 0.f;
    for (int i = half; i < deg; i += 2) {
        int e = csr[off + i];
        if (e < Ee) acc += isf32 ? ef[(long)e * 32 + k] : b2f(eb[(long)e * 32 + k]);
    }
    acc += __shfl_xor(acc, 32);
    float inv = 1.0f / fmaxf((float)(deg - 1), 1.0f);
    if (lane < 32) la[(long)n * 32 + k] = __float2bfloat16(san(acc * inv));
}

// ---------------- 5: xl/xr = x @ W + b, bf16 out ----------------
__global__ void __launch_bounds__(256) k_lin(const void* __restrict__ x,
                                             const float* __restrict__ Wf,
                                             const float* __restrict__ bf_,
                                             const int* __restrict__ flagp,
                                             __hip_bfloat16* __restrict__ out) {
    __shared__ ushort Wlds[128][130];
    __shared__ float xrow[2][128];
    int isf32 = flagp[0];
    int t = threadIdx.x, col = t & 127, sub = t >> 7;
    for (int i = t; i < 16384; i += 256) Wlds[i >> 7][i & 127] = f2bu(Wf[i]);
    float bias = bf_[col];
    const float* xf = (const float*)x;
    const __hip_bfloat16* xb = (const __hip_bfloat16*)x;
    int rpb = (Nn + gridDim.x - 1) / gridDim.x;
    int r0 = blockIdx.x * rpb, r1 = min(r0 + rpb, Nn);
    __syncthreads();
    for (int r = r0; r < r1; r += 2) {
        int rr = r + sub;
        if (rr < r1) xrow[sub][col] = isf32 ? xf[(long)rr * 128 + col]
                                            : b2f(xb[(long)rr * 128 + col]);
        __syncthreads();
        float acc = bias;
        #pragma unroll 16
        for (int k = 0; k < 128; k++) {
            union { uint32 i; float f; } u; u.i = ((uint32)Wlds[k][col]) << 16;
            acc += xrow[sub][k] * u.f;
        }
        if (rr < r1) out[(long)rr * 128 + col] = __float2bfloat16(san(acc));
        __syncthreads();
    }
}

// ---------------- 6: MFMA edge scores ----------------
// D[m=d-in-tile][n=edge16] = We^T . ea^T  via 8x mfma_f32_16x16x32_bf16.
// A frag (lane c0=lane&15,q=lane>>4):  A[m=c0][k=q*8+j] = We[q*8+j][t*16+c0]
// B frag:                              B[k=q*8+j][n=c0] = ea[tile*16+c0][q*8+j]
// D frag reg r:                        D[m=q*4+r][n=c0] = ep[edge=tile*16+c0][d=t*16+q*4+r]
// head(t*16+q*4+r) == t, so lane accumulates one partial score per tile t;
// reduce over q (shfl_xor 16,32); lanes<16 store 8 heads x bf16 = 16B/edge.
__global__ void __launch_bounds__(256) k_score(const void* __restrict__ eattr,
                                               const int* __restrict__ eix,
                                               const uint32* __restrict__ la_u,
                                               const float* __restrict__ wf,
                                               const int* __restrict__ flagp,
                                               const uint32* __restrict__ xlu,
                                               const uint32* __restrict__ xru,
                                               uint4* __restrict__ score16) {
    int isf32 = flagp[1];
    int t256 = threadIdx.x;
    int lane = t256 & 63;
    int c0 = lane & 15, q = lane >> 4;
    int w = (blockIdx.x * 256 + t256) >> 6;
    int nw = (gridDim.x * 256) >> 6;

    // preload A frags (We^T) and att
    short8 A[8];
    float att[8][4];
    #pragma unroll
    for (int t = 0; t < 8; t++) {
        #pragma unroll
        for (int j = 0; j < 8; j++)
            A[t][j] = (short)f2bu(wf[WF_We + (q * 8 + j) * 128 + t * 16 + c0]);
        #pragma unroll
        for (int r = 0; r < 4; r++)
            att[t][r] = wf[WF_att + t * 16 + q * 4 + r];
    }

    const float* ef = (const float*)eattr;
    const uint4* eb4 = (const uint4*)eattr;   // bf16 rows: 64B = 4 x uint4

    for (int T = w; T < NT; T += nw) {
        int row = T * 16 + c0;               // this lane's edge id
        int srcn, dstn;
        short8 B;
        if (T < TE) {
            srcn = eix[row]; dstn = eix[Ee + row];
            if (isf32) {
                const float* p = ef + (long)row * 32 + q * 8;
                #pragma unroll
                for (int j = 0; j < 8; j++) B[j] = (short)f2bu(p[j]);
            } else {
                union { uint4 u; short8 s; } cv;
                cv.u = eb4[(long)row * 4 + q];
                B = cv.s;
            }
        } else {
            int n = row - Ee;                // row = T*16+c0, T>=TE
            srcn = n; dstn = n;
            union { uint4 u; short8 s; } cv;
            cv.u = ((const uint4*)la_u)[(long)n * 4 + q];
            B = cv.s;
        }

        // 8 MFMAs (one per 16-col d-tile == head)
        float4v acc[8];
        #pragma unroll
        for (int t = 0; t < 8; t++) {
            acc[t] = (float4v){0.f, 0.f, 0.f, 0.f};
            acc[t] = __builtin_amdgcn_mfma_f32_16x16x32_bf16(A[t], B, acc[t], 0, 0, 0);
        }

        // gather xl[src][d..d+3], xr[dst][d..d+3] per tile (8B each)
        uint2 xg[8], rg[8];
        #pragma unroll
        for (int t = 0; t < 8; t++) {
            xg[t] = ((const uint2*)xlu)[(long)srcn * 32 + t * 4 + q];
            rg[t] = ((const uint2*)xru)[(long)dstn * 32 + t * 4 + q];
        }

        float st[8];
        #pragma unroll
        for (int t = 0; t < 8; t++) {
            float2 xa = up2(xg[t].x), xb2 = up2(xg[t].y);
            float2 ra = up2(rg[t].x), rb = up2(rg[t].y);
            float v0 = acc[t][0] + xa.x + ra.x;
            float v1 = acc[t][1] + xa.y + ra.y;
            float v2 = acc[t][2] + xb2.x + rb.x;
            float v3 = acc[t][3] + xb2.y + rb.y;
            v0 = v0 > 0.f ? v0 : 0.2f * v0;
            v1 = v1 > 0.f ? v1 : 0.2f * v1;
            v2 = v2 > 0.f ? v2 : 0.2f * v2;
            v3 = v3 > 0.f ? v3 : 0.2f * v3;
            st[t] = att[t][0] * v0 + att[t][1] * v1 + att[t][2] * v2 + att[t][3] * v3;
        }
        #pragma unroll
        for (int t = 0; t < 8; t++) {
            st[t] += __shfl_xor(st[t], 16);
            st[t] += __shfl_xor(st[t], 32);
        }
        if (q == 0) {
            uint4 o;
            o.x = (uint32)f2bu(san(st[0])) | ((uint32)f2bu(san(st[1])) << 16);
            o.y = (uint32)f2bu(san(st[2])) | ((uint32)f2bu(san(st[3])) << 16);
            o.z = (uint32)f2bu(san(st[4])) | ((uint32)f2bu(san(st[5])) << 16);
            o.w = (uint32)f2bu(san(st[6])) | ((uint32)f2bu(san(st[7])) << 16);
            score16[row] = o;
        }
    }
}

// ---------------- 7: softmax + aggregate + bias + residual + LN1 -> x1 ----------------
// Phase A: online-softmax stats, lanes stride edges (16B score loads).
// Phase B: 8 lane-groups x 8 edges in flight; lane = g*8 + head; 16 dims/lane.
// Phase C: reduce over groups (xor 8,16,32), LN1 on lanes 0..7.
__global__ void __launch_bounds__(256) k_agg(const ushort* __restrict__ scu,
                                             const int* __restrict__ csr, const int* __restrict__ offs,
                                             const int* __restrict__ eix,
                                             const uint32* __restrict__ xlu,
                                             const void* __restrict__ x,
                                             const float* __restrict__ wf,
                                             const int* __restrict__ flagp,
                                             uint4* __restrict__ x1) {
    int isf32 = flagp[0];
    int lane = threadIdx.x & 63;
    int n = (blockIdx.x * 256 + threadIdx.x) >> 6;   // grid exact
    int off = offs[n], deg = offs[n + 1] - off;

    float m[8], s[8];
    #pragma unroll
    for (int h = 0; h < 8; h++) { m[h] = -1e30f; s[h] = 0.f; }
    for (int i = lane; i < deg; i += 64) {
        int e = csr[off + i];
        uint4 qv = *((const uint4*)(scu + (long)e * 8));
        float2 p0 = up2(qv.x), p1 = up2(qv.y), p2 = up2(qv.z), p3 = up2(qv.w);
        float sc[8] = {p0.x, p0.y, p1.x, p1.y, p2.x, p2.y, p3.x, p3.y};
        #pragma unroll
        for (int h = 0; h < 8; h++) {
            float mn = fmaxf(m[h], sc[h]);
            s[h] = s[h] * __expf(m[h] - mn) + __expf(sc[h] - mn);
            m[h] = mn;
        }
    }
    #pragma unroll
    for (int mask = 1; mask < 64; mask <<= 1) {
        #pragma unroll
        for (int h = 0; h < 8; h++) {
            float m2 = __shfl_xor(m[h], mask);
            float s2 = __shfl_xor(s[h], mask);
            float mn = fmaxf(m[h], m2);
            s[h] = s[h] * __expf(m[h] - mn) + s2 * __expf(m2 - mn);
            m[h] = mn;
        }
    }

    int g = lane >> 3;        // edge group
    int hh = lane & 7;        // head handled by this lane (dims hh*16..hh*16+15)
    float mh = m[0], sh = s[0];
    #pragma unroll
    for (int j = 1; j < 8; j++) { if (hh == j) { mh = m[j]; sh = s[j]; } }
    float inv = 1.0f / sh;

    float acc[16];
    #pragma unroll
    for (int j = 0; j < 16; j++) acc[j] = 0.f;
    for (int i = g; i < deg; i += 8) {
        int e = csr[off + i];
        float alpha = __expf(b2f(*(const __hip_bfloat16*)(scu + (long)e * 8 + hh)) - mh) * inv;
        int srcn = (e < Ee) ? eix[e] : (e - Ee);
        uint4 a = ((const uint4*)xlu)[(long)srcn * 16 + hh * 2];
        uint4 b = ((const uint4*)xlu)[(long)srcn * 16 + hh * 2 + 1];
        float2 v0 = up2(a.x), v1 = up2(a.y), v2 = up2(a.z), v3 = up2(a.w);
        float2 v4 = up2(b.x), v5 = up2(b.y), v6 = up2(b.z), v7 = up2(b.w);
        acc[0] += alpha * v0.x;  acc[1] += alpha * v0.y;
        acc[2] += alpha * v1.x;  acc[3] += alpha * v1.y;
        acc[4] += alpha * v2.x;  acc[5] += alpha * v2.y;
        acc[6] += alpha * v3.x;  acc[7] += alpha * v3.y;
        acc[8] += alpha * v4.x;  acc[9] += alpha * v4.y;
        acc[10] += alpha * v5.x; acc[11] += alpha * v5.y;
        acc[12] += alpha * v6.x; acc[13] += alpha * v6.y;
        acc[14] += alpha * v7.x; acc[15] += alpha * v7.y;
    }
    #pragma unroll
    for (int mask = 8; mask < 64; mask <<= 1) {
        #pragma unroll
        for (int j = 0; j < 16; j++) acc[j] += __shfl_xor(acc[j], mask);
    }

    // lanes 0..7: residual + bias, LN1, store 16 bf16 (32B) each
    float y[16];
    if (g == 0) {
        int d0 = hh * 16;
        if (isf32) {
            const float4* xf = (const float4*)x;
            #pragma unroll
            for (int c = 0; c < 4; c++) {
                float4 xv = xf[(long)n * 32 + hh * 4 + c];
                y[c*4+0] = acc[c*4+0] + xv.x + wf[WF_bias + d0 + c*4+0];
                y[c*4+1] = acc[c*4+1] + xv.y + wf[WF_bias + d0 + c*4+1];
                y[c*4+2] = acc[c*4+2] + xv.z + wf[WF_bias + d0 + c*4+2];
                y[c*4+3] = acc[c*4+3] + xv.w + wf[WF_bias + d0 + c*4+3];
            }
        } else {
            const uint4* xb = (const uint4*)x;
            uint4 a = xb[(long)n * 16 + hh * 2];
            uint4 b = xb[(long)n * 16 + hh * 2 + 1];
            uint32 ww[8] = {a.x, a.y, a.z, a.w, b.x, b.y, b.z, b.w};
            #pragma unroll
            for (int c = 0; c < 8; c++) {
                float2 v = up2(ww[c]);
                y[c*2+0] = acc[c*2+0] + v.x + wf[WF_bias + d0 + c*2+0];
                y[c*2+1] = acc[c*2+1] + v.y + wf[WF_bias + d0 + c*2+1];
            }
        }
    }
    float sum = 0.f, sq = 0.f;
    if (g == 0) {
        #pragma unroll
        for (int j = 0; j < 16; j++) { sum += y[j]; sq += y[j] * y[j]; }
    }
    #pragma unroll
    for (int mask = 1; mask < 8; mask <<= 1) { sum += __shfl_xor(sum, mask); sq += __shfl_xor(sq, mask); }
    if (g == 0) {
        int d0 = hh * 16;
        float mean = sum * (1.0f / 128.0f);
        float var = sq * (1.0f / 128.0f) - mean * mean;
        float rstd = rsqrtf(var + 1e-5f);
        uint32 o[8];
        #pragma unroll
        for (int c = 0; c < 8; c++) {
            float o0 = san((y[c*2+0] - mean) * rstd * wf[WF_g1 + d0 + c*2+0] + wf[WF_be1 + d0 + c*2+0]);
            float o1 = san((y[c*2+1] - mean) * rstd * wf[WF_g1 + d0 + c*2+1] + wf[WF_be1 + d0 + c*2+1]);
            o[c] = (uint32)f2bu(o0) | ((uint32)f2bu(o1) << 16);
        }
        x1[(long)n * 16 + hh * 2]     = make_uint4(o[0], o[1], o[2], o[3]);
        x1[(long)n * 16 + hh * 2 + 1] = make_uint4(o[4], o[5], o[6], o[7]);
    }
}

// ---------------- 8: FFN + residual + LN2 -> fp32 out ----------------
__global__ void __launch_bounds__(256) k_ffn(const __hip_bfloat16* __restrict__ x1,
                                             const float* __restrict__ wf,
                                             float2* __restrict__ out) {
    __shared__ float xs[16][128];
    __shared__ float hbuf[16][512];
    int t = threadIdx.x;
    long nb = (long)blockIdx.x * 16;
    for (int i = t; i < 16 * 128; i += 256) xs[i >> 7][i & 127] = b2f(x1[nb * 128 + i]);
    __syncthreads();
    const float* W1 = wf + WF_W1;
    const float* W2 = wf + WF_W2;
    int f0 = t, f1 = t + 256;
    float acc[16], accB[16];
    float bb0 = wf[WF_b1 + f0], bb1 = wf[WF_b1 + f1];
    #pragma unroll
    for (int j = 0; j < 16; j++) { acc[j] = bb0; accB[j] = bb1; }
    #pragma unroll 4
    for (int k = 0; k < 128; k++) {
        float w0 = W1[(long)k * 512 + f0], w1 = W1[(long)k * 512 + f1];
        #pragma unroll
        for (int j = 0; j < 16; j++) { float xv = xs[j][k]; acc[j] += xv * w0; accB[j] += xv * w1; }
    }
    #pragma unroll
    for (int j = 0; j < 16; j++) { hbuf[j][f0] = fmaxf(acc[j], 0.f); hbuf[j][f1] = fmaxf(accB[j], 0.f); }
    __syncthreads();
    int d = t & 127, grp = t >> 7, n0 = grp * 8;
    float o[8];
    float bb2 = wf[WF_b2 + d];
    #pragma unroll
    for (int j = 0; j < 8; j++) o[j] = bb2;
    #pragma unroll 4
    for (int f = 0; f < 512; f++) {
        float w = W2[(long)f * 128 + d];
        #pragma unroll
        for (int j = 0; j < 8; j++) o[j] += hbuf[n0 + j][f] * w;
    }
    #pragma unroll
    for (int j = 0; j < 8; j++) o[j] += xs[n0 + j][d];
    __syncthreads();
    #pragma unroll
    for (int j = 0; j < 8; j++) xs[n0 + j][d] = o[j];
    __syncthreads();
    int lane = t & 63, wv = t >> 6;
    int d0 = 2 * lane;
    float gg0 = wf[WF_g2 + d0], gg1 = wf[WF_g2 + d0 + 1];
    float eb0 = wf[WF_be2 + d0], eb1 = wf[WF_be2 + d0 + 1];
    for (int i = 0; i < 4; i++) {
        int r = wv * 4 + i;
        float v0 = xs[r][d0], v1 = xs[r][d0 + 1];
        float sum = v0 + v1, sq = v0 * v0 + v1 * v1;
        #pragma unroll
        for (int mk = 1; mk < 64; mk <<= 1) { sum += __shfl_xor(sum, mk); sq += __shfl_xor(sq, mk); }
        float mean = sum * (1.0f / 128.0f);
        float var = sq * (1.0f / 128.0f) - mean * mean;
        float rstd = rsqrtf(var + 1e-5f);
        float o0 = san((v0 - mean) * rstd * gg0 + eb0);
        float o1 = san((v1 - mean) * rstd * gg1 + eb1);
        out[(nb + r) * 64 + lane] = make_float2(o0, o1);
    }
}

// ---------------- launch ----------------
extern "C" void kernel_launch(void* const* d_in, const int* in_sizes, int n_in,
                              void* d_out, int out_size, void* d_ws, size_t ws_size,
                              hipStream_t stream) {
    const void* x     = d_in[0];
    const int*  eraw  = (const int*)d_in[1];
    const void* eattr = d_in[2];

    char* wsb = (char*)d_ws;
    __hip_bfloat16* sc  = (__hip_bfloat16*)(wsb + B_SC);
    __hip_bfloat16* xl  = (__hip_bfloat16*)(wsb + B_XL);
    __hip_bfloat16* x1  = (__hip_bfloat16*)(wsb + B_X1);
    __hip_bfloat16* la  = (__hip_bfloat16*)(wsb + B_LA);
    int*   eix  = (int*)(wsb + B_EIX);
    int*   cnt  = (int*)(wsb + B_CNT);
    int*   offs = (int*)(wsb + B_OFS);
    int*   cur  = (int*)(wsb + B_CUR);
    int*   csr  = (int*)(wsb + B_CSR);
    float* wf   = (float*)(wsb + B_WF);
    int*   flg  = (int*)(wsb + B_FLG);
    __hip_bfloat16* xr  = (__hip_bfloat16*)d_out;   // bf16 scratch in fp32 d_out

    WSrc wsrc;
    for (int i = 0; i < 15; i++) wsrc.p[i] = d_in[3 + i];

    hipMemsetAsync(cnt, 0, Nn * sizeof(int), stream);

    k_sniff<<<1, 64, 0, stream>>>((const uint32*)x, (const uint32*)eattr, flg);
    k_cvt<<<(2 * Ee + 255) / 256, 256, 0, stream>>>(eraw, eix, cnt);
    k_wcanon<<<(WF_TOT + 255) / 256, 256, 0, stream>>>(wsrc, flg, wf);
    k_scan<<<1, 1024, 0, stream>>>(cnt, offs, cur);
    k_fill<<<(EF + 255) / 256, 256, 0, stream>>>(eix, cur, offs, csr);
    k_loopattr<<<(Nn + 3) / 4, 256, 0, stream>>>(eattr, csr, offs, flg, la);
    k_lin<<<512, 256, 0, stream>>>(x, wf + WF_Wl, wf + WF_bl, flg, xl);
    k_lin<<<512, 256, 0, stream>>>(x, wf + WF_Wr, wf + WF_br, flg, xr);
    k_score<<<2048, 256, 0, stream>>>(eattr, eix, (const uint32*)la, wf, flg,
                                      (const uint32*)xl, (const uint32*)xr,
                                      (uint4*)sc);
    k_agg<<<(Nn + 3) / 4, 256, 0, stream>>>((const ushort*)sc, csr, offs, eix,
                                            (const uint32*)xl, x, wf, flg,
                                            (uint4*)x1);
    k_ffn<<<Nn / 16, 256, 0, stream>>>(x1, wf, (float2*)d_out);
}

// Round 7
// 929.367 us; speedup vs baseline: 1.5807x; 1.2217x over previous
//
#include <hip/hip_runtime.h>
#include <hip/hip_bf16.h>

typedef unsigned int uint32;
typedef unsigned short ushort;
typedef __attribute__((ext_vector_type(8))) short short8;   // 8 bf16 (4 VGPRs)
typedef __attribute__((ext_vector_type(4))) float float4v;  // MFMA acc

// ---------------- problem constants ----------------
constexpr int Nn = 50000;
constexpr int Ee = 800000;
constexpr int EF = Ee + Nn;          // 850000, divisible by 16
constexpr int NT = EF / 16;          // 53125 MFMA edge-tiles
constexpr int TE = Ee / 16;          // 50000 (tiles below are real edges)

// ---------------- ws layout (BYTE offsets, ~53.5 MB) ----------------
constexpr long B_SC  = 0;            // bf16 [EF*8]     13,600,000 B  scores; reused as W1s/W2s for k_ffn
constexpr long B_XL  = 13600000;     // bf16 [Nn*128]   12,800,000 B  xl
constexpr long B_X1  = 26400000;     // bf16 [Nn*128]   12,800,000 B  x1 (post-LN1)
constexpr long B_LA  = 39200000;     // bf16 [Nn*32]     3,200,000 B  loop_attr
constexpr long B_EIX = 42400000;     // int  [2*Ee]      6,400,000 B  normalized idx
constexpr long B_CNT = 48800000;     // int  [Nn]
constexpr long B_OFS = 49000000;     // int  [Nn+1]
constexpr long B_CUR = 49200016;     // int  [Nn]
constexpr long B_CSR = 49400016;     // int  [EF]        3,400,000 B
constexpr long B_WF  = 52800016;     // fp32 [169600]      678,400 B  canonical weights
constexpr long B_FLG = 53478416;     // int[2]: {x_is_f32, ea_is_f32}

// canonical weight float offsets
constexpr int WF_Wl = 0, WF_bl = 16384, WF_Wr = 16512, WF_br = 32896;
constexpr int WF_We = 33024, WF_att = 37120, WF_bias = 37248;
constexpr int WF_W1 = 37376, WF_b1 = 102912, WF_W2 = 103424, WF_b2 = 168960;
constexpr int WF_g1 = 169088, WF_be1 = 169216, WF_g2 = 169344, WF_be2 = 169472;
constexpr int WF_TOT = 169600;

static __device__ __forceinline__ float b2f(__hip_bfloat16 v) { return __bfloat162float(v); }
static __device__ __forceinline__ float2 up2(uint32 u) {
    union { uint32 i; float f; } a, b;
    a.i = (u & 0xFFFFu) << 16; b.i = u & 0xFFFF0000u;
    return make_float2(a.f, b.f);
}
static __device__ __forceinline__ float up1(ushort u) {
    union { uint32 i; float f; } a; a.i = ((uint32)u) << 16; return a.f;
}
static __device__ __forceinline__ ushort f2bu(float f) {
    __hip_bfloat16 h = __float2bfloat16(f); return *(ushort*)&h;
}
static __device__ __forceinline__ float san(float v) { return fminf(fmaxf(v, -1e4f), 1e4f); }

// ---------------- 0a: sniff float dtype of x and edge_attr ----------------
__global__ void k_sniff(const uint32* __restrict__ xu, const uint32* __restrict__ eu,
                        int* __restrict__ flg) {
    int lane = threadIdx.x;
    int xbf = 0, ebf = 0;
    #pragma unroll
    for (int j = 0; j < 8; j++) {
        uint32 ux = xu[lane * 8 + j];
        int ex = (ux >> 7) & 0xFF;
        xbf += (ex >= 100 && ex <= 135) ? 1 : 0;
        uint32 ue = eu[lane * 8 + j];
        int ee = (ue >> 7) & 0xFF;
        ebf += (ee >= 100 && ee <= 135) ? 1 : 0;
    }
    #pragma unroll
    for (int mk = 1; mk < 64; mk <<= 1) { xbf += __shfl_xor(xbf, mk); ebf += __shfl_xor(ebf, mk); }
    if (lane == 0) { flg[0] = (xbf > 256) ? 0 : 1; flg[1] = (ebf > 256) ? 0 : 1; }
}

// ---------------- 0b: normalize edge_index + clamp + count (fused) ----------------
__global__ void k_cvt(const int* __restrict__ raw, int* __restrict__ eix,
                      int* __restrict__ cnt) {
    __shared__ int is64;
    if (threadIdx.x == 0) {
        int z = 1;
        #pragma unroll
        for (int j = 1; j < 64; j += 2) z &= (raw[j] == 0);
        is64 = z;
    }
    __syncthreads();
    int i = blockIdx.x * 256 + threadIdx.x;
    if (i < 2 * Ee) {
        int v = is64 ? raw[2 * i] : raw[i];
        v = v < 0 ? 0 : (v >= Nn ? Nn - 1 : v);
        eix[i] = v;
        if (i >= Ee) atomicAdd(&cnt[v], 1);
    }
}

// ---------------- 0c: canonicalize all weight tensors to fp32 ----------------
struct WSrc { const void* p[15]; };
__global__ void k_wcanon(WSrc s, const int* __restrict__ flagp, float* __restrict__ dst) {
    const int cum[16] = {0, 16384, 16512, 32896, 33024, 37120, 37248, 37376,
                         102912, 103424, 168960, 169088, 169216, 169344, 169472, 169600};
    int i = blockIdx.x * 256 + threadIdx.x;
    if (i >= WF_TOT) return;
    int isf32 = flagp[0];
    int seg = 0;
    #pragma unroll
    for (int j = 1; j < 16; j++) seg += (i >= cum[j]);
    int off = i - cum[seg];
    float v = isf32 ? ((const float*)s.p[seg])[off]
                    : b2f(((const __hip_bfloat16*)s.p[seg])[off]);
    dst[i] = v;
}

// ---------------- 2: exclusive scan -> CSR offsets (deg = cnt+1) ----------------
__global__ void __launch_bounds__(1024) k_scan(const int* __restrict__ cnt,
                                               int* __restrict__ offs, int* __restrict__ cursor) {
    __shared__ int part[1024];
    int t = threadIdx.x;
    const int CH = (Nn + 1023) / 1024;
    int base = t * CH;
    int s = 0;
    for (int i = 0; i < CH; i++) { int n = base + i; if (n < Nn) s += cnt[n] + 1; }
    part[t] = s;
    __syncthreads();
    for (int off = 1; off < 1024; off <<= 1) {
        int v = (t >= off) ? part[t - off] : 0;
        __syncthreads();
        part[t] += v;
        __syncthreads();
    }
    int run = part[t] - s;
    for (int i = 0; i < CH; i++) {
        int n = base + i;
        if (n < Nn) { offs[n] = run; run += cnt[n] + 1; cursor[n] = 0; }
    }
    if (t == 1023) offs[Nn] = part[1023];
}

// ---------------- 3: fill CSR ----------------
__global__ void k_fill(const int* __restrict__ eix, int* __restrict__ cursor,
                       const int* __restrict__ offs, int* __restrict__ csr) {
    int e = blockIdx.x * 256 + threadIdx.x;
    if (e >= EF) return;
    int d = (e < Ee) ? eix[Ee + e] : (e - Ee);
    int p = atomicAdd(&cursor[d], 1);
    csr[offs[d] + p] = e;
}

// ---------------- 4: self-loop attr = mean of incoming edge_attr ----------------
__global__ void __launch_bounds__(256) k_loopattr(const void* __restrict__ eattr,
                                                  const int* __restrict__ csr,
                                                  const int* __restrict__ offs,
                                                  const int* __restrict__ flagp,
                                                  __hip_bfloat16* __restrict__ la) {
    int isf32 = flagp[1];
    int lane = threadIdx.x & 63;
    int n = (blockIdx.x * 256 + threadIdx.x) >> 6;
    if (n >= Nn) return;
    int off = offs[n], deg = offs[n + 1] - off;
    int k = lane & 31, half = lane >> 5;
    const float* ef = (const float*)eattr;
    const __hip_bfloat16* eb = (const __hip_bfloat16*)eattr;
    float acc = 0.f;
    for (int i = half; i < deg; i += 2) {
        int e = csr[off + i];
        if (e < Ee) acc += isf32 ? ef[(long)e * 32 + k] : b2f(eb[(long)e * 32 + k]);
    }
    acc += __shfl_xor(acc, 32);
    float inv = 1.0f / fmaxf((float)(deg - 1), 1.0f);
    if (lane < 32) la[(long)n * 32 + k] = __float2bfloat16(san(acc * inv));
}

// ---------------- 5: xl/xr = x @ W + b, bf16 out ----------------
__global__ void __launch_bounds__(256) k_lin(const void* __restrict__ x,
                                             const float* __restrict__ Wf,
                                             const float* __restrict__ bf_,
                                             const int* __restrict__ flagp,
                                             __hip_bfloat16* __restrict__ out) {
    __shared__ ushort Wlds[128][130];
    __shared__ float xrow[2][128];
    int isf32 = flagp[0];
    int t = threadIdx.x, col = t & 127, sub = t >> 7;
    for (int i = t; i < 16384; i += 256) Wlds[i >> 7][i & 127] = f2bu(Wf[i]);
    float bias = bf_[col];
    const float* xf = (const float*)x;
    const __hip_bfloat16* xb = (const __hip_bfloat16*)x;
    int rpb = (Nn + gridDim.x - 1) / gridDim.x;
    int r0 = blockIdx.x * rpb, r1 = min(r0 + rpb, Nn);
    __syncthreads();
    for (int r = r0; r < r1; r += 2) {
        int rr = r + sub;
        if (rr < r1) xrow[sub][col] = isf32 ? xf[(long)rr * 128 + col]
                                            : b2f(xb[(long)rr * 128 + col]);
        __syncthreads();
        float acc = bias;
        #pragma unroll 16
        for (int k = 0; k < 128; k++) {
            union { uint32 i; float f; } u; u.i = ((uint32)Wlds[k][col]) << 16;
            acc += xrow[sub][k] * u.f;
        }
        if (rr < r1) out[(long)rr * 128 + col] = __float2bfloat16(san(acc));
        __syncthreads();
    }
}

// ---------------- 6: MFMA edge scores ----------------
__global__ void __launch_bounds__(256) k_score(const void* __restrict__ eattr,
                                               const int* __restrict__ eix,
                                               const uint32* __restrict__ la_u,
                                               const float* __restrict__ wf,
                                               const int* __restrict__ flagp,
                                               const uint32* __restrict__ xlu,
                                               const uint32* __restrict__ xru,
                                               uint4* __restrict__ score16) {
    int isf32 = flagp[1];
    int t256 = threadIdx.x;
    int lane = t256 & 63;
    int c0 = lane & 15, q = lane >> 4;
    int w = (blockIdx.x * 256 + t256) >> 6;
    int nw = (gridDim.x * 256) >> 6;

    short8 A[8];
    float att[8][4];
    #pragma unroll
    for (int t = 0; t < 8; t++) {
        #pragma unroll
        for (int j = 0; j < 8; j++)
            A[t][j] = (short)f2bu(wf[WF_We + (q * 8 + j) * 128 + t * 16 + c0]);
        #pragma unroll
        for (int r = 0; r < 4; r++)
            att[t][r] = wf[WF_att + t * 16 + q * 4 + r];
    }

    const float* ef = (const float*)eattr;
    const uint4* eb4 = (const uint4*)eattr;

    for (int T = w; T < NT; T += nw) {
        int row = T * 16 + c0;
        int srcn, dstn;
        short8 B;
        if (T < TE) {
            srcn = eix[row]; dstn = eix[Ee + row];
            if (isf32) {
                const float* p = ef + (long)row * 32 + q * 8;
                #pragma unroll
                for (int j = 0; j < 8; j++) B[j] = (short)f2bu(p[j]);
            } else {
                union { uint4 u; short8 s; } cv;
                cv.u = eb4[(long)row * 4 + q];
                B = cv.s;
            }
        } else {
            int n = row - Ee;
            srcn = n; dstn = n;
            union { uint4 u; short8 s; } cv;
            cv.u = ((const uint4*)la_u)[(long)n * 4 + q];
            B = cv.s;
        }

        float4v acc[8];
        #pragma unroll
        for (int t = 0; t < 8; t++) {
            acc[t] = (float4v){0.f, 0.f, 0.f, 0.f};
            acc[t] = __builtin_amdgcn_mfma_f32_16x16x32_bf16(A[t], B, acc[t], 0, 0, 0);
        }

        uint2 xg[8], rg[8];
        #pragma unroll
        for (int t = 0; t < 8; t++) {
            xg[t] = ((const uint2*)xlu)[(long)srcn * 32 + t * 4 + q];
            rg[t] = ((const uint2*)xru)[(long)dstn * 32 + t * 4 + q];
        }

        float st[8];
        #pragma unroll
        for (int t = 0; t < 8; t++) {
            float2 xa = up2(xg[t].x), xb2 = up2(xg[t].y);
            float2 ra = up2(rg[t].x), rb = up2(rg[t].y);
            float v0 = acc[t][0] + xa.x + ra.x;
            float v1 = acc[t][1] + xa.y + ra.y;
            float v2 = acc[t][2] + xb2.x + rb.x;
            float v3 = acc[t][3] + xb2.y + rb.y;
            v0 = v0 > 0.f ? v0 : 0.2f * v0;
            v1 = v1 > 0.f ? v1 : 0.2f * v1;
            v2 = v2 > 0.f ? v2 : 0.2f * v2;
            v3 = v3 > 0.f ? v3 : 0.2f * v3;
            st[t] = att[t][0] * v0 + att[t][1] * v1 + att[t][2] * v2 + att[t][3] * v3;
        }
        #pragma unroll
        for (int t = 0; t < 8; t++) {
            st[t] += __shfl_xor(st[t], 16);
            st[t] += __shfl_xor(st[t], 32);
        }
        if (q == 0) {
            uint4 o;
            o.x = (uint32)f2bu(san(st[0])) | ((uint32)f2bu(san(st[1])) << 16);
            o.y = (uint32)f2bu(san(st[2])) | ((uint32)f2bu(san(st[3])) << 16);
            o.z = (uint32)f2bu(san(st[4])) | ((uint32)f2bu(san(st[5])) << 16);
            o.w = (uint32)f2bu(san(st[6])) | ((uint32)f2bu(san(st[7])) << 16);
            score16[row] = o;
        }
    }
}

// ---------------- 7: softmax + aggregate + bias + residual + LN1 -> x1 ----------------
__global__ void __launch_bounds__(256) k_agg(const ushort* __restrict__ scu,
                                             const int* __restrict__ csr, const int* __restrict__ offs,
                                             const int* __restrict__ eix,
                                             const uint32* __restrict__ xlu,
                                             const void* __restrict__ x,
                                             const float* __restrict__ wf,
                                             const int* __restrict__ flagp,
                                             uint4* __restrict__ x1) {
    int isf32 = flagp[0];
    int lane = threadIdx.x & 63;
    int n = (blockIdx.x * 256 + threadIdx.x) >> 6;
    int off = offs[n], deg = offs[n + 1] - off;

    float m[8], s[8];
    #pragma unroll
    for (int h = 0; h < 8; h++) { m[h] = -1e30f; s[h] = 0.f; }
    for (int i = lane; i < deg; i += 64) {
        int e = csr[off + i];
        uint4 qv = *((const uint4*)(scu + (long)e * 8));
        float2 p0 = up2(qv.x), p1 = up2(qv.y), p2 = up2(qv.z), p3 = up2(qv.w);
        float sc[8] = {p0.x, p0.y, p1.x, p1.y, p2.x, p2.y, p3.x, p3.y};
        #pragma unroll
        for (int h = 0; h < 8; h++) {
            float mn = fmaxf(m[h], sc[h]);
            s[h] = s[h] * __expf(m[h] - mn) + __expf(sc[h] - mn);
            m[h] = mn;
        }
    }
    #pragma unroll
    for (int mask = 1; mask < 64; mask <<= 1) {
        #pragma unroll
        for (int h = 0; h < 8; h++) {
            float m2 = __shfl_xor(m[h], mask);
            float s2 = __shfl_xor(s[h], mask);
            float mn = fmaxf(m[h], m2);
            s[h] = s[h] * __expf(m[h] - mn) + s2 * __expf(m2 - mn);
            m[h] = mn;
        }
    }

    int g = lane >> 3;
    int hh = lane & 7;
    float mh = m[0], sh = s[0];
    #pragma unroll
    for (int j = 1; j < 8; j++) { if (hh == j) { mh = m[j]; sh = s[j]; } }
    float inv = 1.0f / sh;

    float acc[16];
    #pragma unroll
    for (int j = 0; j < 16; j++) acc[j] = 0.f;
    for (int i = g; i < deg; i += 8) {
        int e = csr[off + i];
        float alpha = __expf(b2f(*(const __hip_bfloat16*)(scu + (long)e * 8 + hh)) - mh) * inv;
        int srcn = (e < Ee) ? eix[e] : (e - Ee);
        uint4 a = ((const uint4*)xlu)[(long)srcn * 16 + hh * 2];
        uint4 b = ((const uint4*)xlu)[(long)srcn * 16 + hh * 2 + 1];
        float2 v0 = up2(a.x), v1 = up2(a.y), v2 = up2(a.z), v3 = up2(a.w);
        float2 v4 = up2(b.x), v5 = up2(b.y), v6 = up2(b.z), v7 = up2(b.w);
        acc[0] += alpha * v0.x;  acc[1] += alpha * v0.y;
        acc[2] += alpha * v1.x;  acc[3] += alpha * v1.y;
        acc[4] += alpha * v2.x;  acc[5] += alpha * v2.y;
        acc[6] += alpha * v3.x;  acc[7] += alpha * v3.y;
        acc[8] += alpha * v4.x;  acc[9] += alpha * v4.y;
        acc[10] += alpha * v5.x; acc[11] += alpha * v5.y;
        acc[12] += alpha * v6.x; acc[13] += alpha * v6.y;
        acc[14] += alpha * v7.x; acc[15] += alpha * v7.y;
    }
    #pragma unroll
    for (int mask = 8; mask < 64; mask <<= 1) {
        #pragma unroll
        for (int j = 0; j < 16; j++) acc[j] += __shfl_xor(acc[j], mask);
    }

    float y[16];
    if (g == 0) {
        int d0 = hh * 16;
        if (isf32) {
            const float4* xf = (const float4*)x;
            #pragma unroll
            for (int c = 0; c < 4; c++) {
                float4 xv = xf[(long)n * 32 + hh * 4 + c];
                y[c*4+0] = acc[c*4+0] + xv.x + wf[WF_bias + d0 + c*4+0];
                y[c*4+1] = acc[c*4+1] + xv.y + wf[WF_bias + d0 + c*4+1];
                y[c*4+2] = acc[c*4+2] + xv.z + wf[WF_bias + d0 + c*4+2];
                y[c*4+3] = acc[c*4+3] + xv.w + wf[WF_bias + d0 + c*4+3];
            }
        } else {
            const uint4* xb = (const uint4*)x;
            uint4 a = xb[(long)n * 16 + hh * 2];
            uint4 b = xb[(long)n * 16 + hh * 2 + 1];
            uint32 ww[8] = {a.x, a.y, a.z, a.w, b.x, b.y, b.z, b.w};
            #pragma unroll
            for (int c = 0; c < 8; c++) {
                float2 v = up2(ww[c]);
                y[c*2+0] = acc[c*2+0] + v.x + wf[WF_bias + d0 + c*2+0];
                y[c*2+1] = acc[c*2+1] + v.y + wf[WF_bias + d0 + c*2+1];
            }
        }
    }
    float sum = 0.f, sq = 0.f;
    if (g == 0) {
        #pragma unroll
        for (int j = 0; j < 16; j++) { sum += y[j]; sq += y[j] * y[j]; }
    }
    #pragma unroll
    for (int mask = 1; mask < 8; mask <<= 1) { sum += __shfl_xor(sum, mask); sq += __shfl_xor(sq, mask); }
    if (g == 0) {
        int d0 = hh * 16;
        float mean = sum * (1.0f / 128.0f);
        float var = sq * (1.0f / 128.0f) - mean * mean;
        float rstd = rsqrtf(var + 1e-5f);
        uint32 o[8];
        #pragma unroll
        for (int c = 0; c < 8; c++) {
            float o0 = san((y[c*2+0] - mean) * rstd * wf[WF_g1 + d0 + c*2+0] + wf[WF_be1 + d0 + c*2+0]);
            float o1 = san((y[c*2+1] - mean) * rstd * wf[WF_g1 + d0 + c*2+1] + wf[WF_be1 + d0 + c*2+1]);
            o[c] = (uint32)f2bu(o0) | ((uint32)f2bu(o1) << 16);
        }
        x1[(long)n * 16 + hh * 2]     = make_uint4(o[0], o[1], o[2], o[3]);
        x1[(long)n * 16 + hh * 2 + 1] = make_uint4(o[4], o[5], o[6], o[7]);
    }
}

// ---------------- 7b: pre-swizzle W1/W2 into MFMA fragment order ----------------
// W1s[((ht*4+kk)*64 + lane)*8 + j] = bf16(W1[kk*32+q*8+j][ht*16+c]), lane=(q<<4)|c
// W2s[((nt*16+kk2)*64 + lane)*8 + j] = bf16(W2[kk2*32+q*8+j][nt*16+c])
__global__ void k_wprep(const float* __restrict__ wf,
                        ushort* __restrict__ W1s, ushort* __restrict__ W2s) {
    int i = blockIdx.x * 256 + threadIdx.x;   // 0..65535
    if (i >= 65536) return;
    int j = i & 7, lane = (i >> 3) & 63, g = i >> 9;
    int c = lane & 15, q = lane >> 4;
    int kk = g & 3, ht = g >> 2;
    W1s[i] = f2bu(wf[WF_W1 + (kk * 32 + q * 8 + j) * 512 + ht * 16 + c]);
    int kk2 = g & 15, nt = g >> 4;
    W2s[i] = f2bu(wf[WF_W2 + (kk2 * 32 + q * 8 + j) * 128 + nt * 16 + c]);
}

// ---------------- 8: MFMA FFN + residual + LN2 -> fp32 out ----------------
// Per wave: 16 nodes. GEMM1 D[m=hdim][n=node] (A=W1^T frags, B=x1 rows),
// h->LDS (stride 520 bf16), GEMM2 D[m=node][n=outd] (A=h from LDS, B=W2 frags),
// epilogue: +b2 +residual(x1 LDS) + LN2 (reduce over c-group lanes).
__global__ void __launch_bounds__(128) k_ffn(const ushort* __restrict__ x1b,
                                             const float* __restrict__ wf,
                                             const ushort* __restrict__ W1s,
                                             const ushort* __restrict__ W2s,
                                             float* __restrict__ out) {
    __shared__ ushort hb[2][16 * 520];    // 33,280 B
    __shared__ ushort xsb[2][16 * 136];   //  8,704 B
    int wv = threadIdx.x >> 6;
    int lane = threadIdx.x & 63;
    int c = lane & 15, q = lane >> 4;
    long n0 = (long)blockIdx.x * 32 + wv * 16;
    if (n0 >= Nn) return;
    ushort* h = hb[wv];
    ushort* xs = xsb[wv];

    // B-frags of GEMM1: x1 row of this lane's node (k-window per kk)
    short8 B1[4];
    const uint4* x1row = (const uint4*)(x1b + (n0 + c) * 128);
    #pragma unroll
    for (int kk = 0; kk < 4; kk++) {
        union { uint4 u; short8 s; } cv; cv.u = x1row[kk * 4 + q]; B1[kk] = cv.s;
    }

    // stage x1 tile for residual (16 rows x 128 bf16, row stride 136)
    for (int i = lane; i < 256; i += 64) {
        int row = i >> 4, col = i & 15;
        *(uint4*)(xs + row * 136 + col * 8) = *(const uint4*)(x1b + (n0 + row) * 128 + col * 8);
    }

    // GEMM1: h = relu(x1 @ W1 + b1), written transposed-per-lane to LDS
    const uint4* W1v = (const uint4*)W1s;
    for (int ht = 0; ht < 32; ht++) {
        float4v acc = (float4v){0.f, 0.f, 0.f, 0.f};
        #pragma unroll
        for (int kk = 0; kk < 4; kk++) {
            union { uint4 u; short8 s; } a; a.u = W1v[(ht * 4 + kk) * 64 + lane];
            acc = __builtin_amdgcn_mfma_f32_16x16x32_bf16(a.s, B1[kk], acc, 0, 0, 0);
        }
        float4 bb = *(const float4*)(wf + WF_b1 + ht * 16 + q * 4);
        float v0 = fmaxf(acc[0] + bb.x, 0.f);
        float v1 = fmaxf(acc[1] + bb.y, 0.f);
        float v2 = fmaxf(acc[2] + bb.z, 0.f);
        float v3 = fmaxf(acc[3] + bb.w, 0.f);
        uint2 pk;
        pk.x = (uint32)f2bu(v0) | ((uint32)f2bu(v1) << 16);
        pk.y = (uint32)f2bu(v2) | ((uint32)f2bu(v3) << 16);
        *(uint2*)(h + c * 520 + ht * 16 + q * 4) = pk;
    }

    // GEMM2: y = h @ W2
    const uint4* W2v = (const uint4*)W2s;
    float4v acc2[8];
    #pragma unroll
    for (int nt = 0; nt < 8; nt++) acc2[nt] = (float4v){0.f, 0.f, 0.f, 0.f};
    for (int kk2 = 0; kk2 < 16; kk2++) {
        union { uint4 u; short8 s; } a2;
        a2.u = *(const uint4*)(h + c * 520 + kk2 * 32 + q * 8);
        #pragma unroll
        for (int nt = 0; nt < 8; nt++) {
            union { uint4 u; short8 s; } b2f_;
            b2f_.u = W2v[(nt * 16 + kk2) * 64 + lane];
            acc2[nt] = __builtin_amdgcn_mfma_f32_16x16x32_bf16(a2.s, b2f_.s, acc2[nt], 0, 0, 0);
        }
    }

    // epilogue: lane holds y[node q*4+r][outd nt*16+c]
    float b2v[8], g2v[8], be2v[8];
    #pragma unroll
    for (int nt = 0; nt < 8; nt++) {
        b2v[nt]  = wf[WF_b2  + nt * 16 + c];
        g2v[nt]  = wf[WF_g2  + nt * 16 + c];
        be2v[nt] = wf[WF_be2 + nt * 16 + c];
    }
    float yv[8][4];
    float sum[4] = {0.f, 0.f, 0.f, 0.f}, sq[4] = {0.f, 0.f, 0.f, 0.f};
    #pragma unroll
    for (int nt = 0; nt < 8; nt++) {
        #pragma unroll
        for (int r = 0; r < 4; r++) {
            float v = acc2[nt][r] + b2v[nt] + up1(xs[(q * 4 + r) * 136 + nt * 16 + c]);
            yv[nt][r] = v;
            sum[r] += v; sq[r] += v * v;
        }
    }
    #pragma unroll
    for (int mask = 1; mask < 16; mask <<= 1) {
        #pragma unroll
        for (int r = 0; r < 4; r++) {
            sum[r] += __shfl_xor(sum[r], mask);
            sq[r]  += __shfl_xor(sq[r], mask);
        }
    }
    #pragma unroll
    for (int r = 0; r < 4; r++) {
        float mean = sum[r] * (1.0f / 128.0f);
        float var = sq[r] * (1.0f / 128.0f) - mean * mean;
        float rstd = rsqrtf(var + 1e-5f);
        long nodeb = (n0 + q * 4 + r) * 128;
        #pragma unroll
        for (int nt = 0; nt < 8; nt++) {
            out[nodeb + nt * 16 + c] = san((yv[nt][r] - mean) * rstd * g2v[nt] + be2v[nt]);
        }
    }
}

// ---------------- launch ----------------
extern "C" void kernel_launch(void* const* d_in, const int* in_sizes, int n_in,
                              void* d_out, int out_size, void* d_ws, size_t ws_size,
                              hipStream_t stream) {
    const void* x     = d_in[0];
    const int*  eraw  = (const int*)d_in[1];
    const void* eattr = d_in[2];

    char* wsb = (char*)d_ws;
    __hip_bfloat16* sc  = (__hip_bfloat16*)(wsb + B_SC);
    __hip_bfloat16* xl  = (__hip_bfloat16*)(wsb + B_XL);
    __hip_bfloat16* x1  = (__hip_bfloat16*)(wsb + B_X1);
    __hip_bfloat16* la  = (__hip_bfloat16*)(wsb + B_LA);
    int*   eix  = (int*)(wsb + B_EIX);
    int*   cnt  = (int*)(wsb + B_CNT);
    int*   offs = (int*)(wsb + B_OFS);
    int*   cur  = (int*)(wsb + B_CUR);
    int*   csr  = (int*)(wsb + B_CSR);
    float* wf   = (float*)(wsb + B_WF);
    int*   flg  = (int*)(wsb + B_FLG);
    __hip_bfloat16* xr  = (__hip_bfloat16*)d_out;         // bf16 scratch in fp32 d_out
    ushort* W1s = (ushort*)(wsb + B_SC);                  // score buffer dead after k_agg
    ushort* W2s = (ushort*)(wsb + B_SC + 131072);

    WSrc wsrc;
    for (int i = 0; i < 15; i++) wsrc.p[i] = d_in[3 + i];

    hipMemsetAsync(cnt, 0, Nn * sizeof(int), stream);

    k_sniff<<<1, 64, 0, stream>>>((const uint32*)x, (const uint32*)eattr, flg);
    k_cvt<<<(2 * Ee + 255) / 256, 256, 0, stream>>>(eraw, eix, cnt);
    k_wcanon<<<(WF_TOT + 255) / 256, 256, 0, stream>>>(wsrc, flg, wf);
    k_scan<<<1, 1024, 0, stream>>>(cnt, offs, cur);
    k_fill<<<(EF + 255) / 256, 256, 0, stream>>>(eix, cur, offs, csr);
    k_loopattr<<<(Nn + 3) / 4, 256, 0, stream>>>(eattr, csr, offs, flg, la);
    k_lin<<<512, 256, 0, stream>>>(x, wf + WF_Wl, wf + WF_bl, flg, xl);
    k_lin<<<512, 256, 0, stream>>>(x, wf + WF_Wr, wf + WF_br, flg, xr);
    k_score<<<2048, 256, 0, stream>>>(eattr, eix, (const uint32*)la, wf, flg,
                                      (const uint32*)xl, (const uint32*)xr,
                                      (uint4*)sc);
    k_agg<<<(Nn + 3) / 4, 256, 0, stream>>>((const ushort*)sc, csr, offs, eix,
                                            (const uint32*)xl, x, wf, flg,
                                            (uint4*)x1);
    k_wprep<<<256, 256, 0, stream>>>(wf, W1s, W2s);
    k_ffn<<<(Nn + 31) / 32, 128, 0, stream>>>((const ushort*)x1, wf, W1s, W2s,
                                              (float*)d_out);
}

// Round 8
// 699.849 us; speedup vs baseline: 2.0991x; 1.3280x over previous
//
#include <hip/hip_runtime.h>
#include <hip/hip_bf16.h>

typedef unsigned int uint32;
typedef unsigned short ushort;
typedef __attribute__((ext_vector_type(8))) short short8;   // 8 bf16 (4 VGPRs)
typedef __attribute__((ext_vector_type(4))) float float4v;  // MFMA acc

// ---------------- problem constants ----------------
constexpr int Nn = 50000;
constexpr int Ee = 800000;
constexpr int EF = Ee + Nn;          // 850000, divisible by 16
constexpr int NT = EF / 16;          // 53125 MFMA tiles
constexpr int TE = Ee / 16;          // 50000

// ---------------- PLAN B (round-7) ws layout ----------------
constexpr long B_SC  = 0;
constexpr long B_XL  = 13600000;
constexpr long B_X1  = 26400000;
constexpr long B_LA  = 39200000;
constexpr long B_EIX = 42400000;
constexpr long B_CNT = 48800000;
constexpr long B_OFS = 49000000;
constexpr long B_CUR = 49200016;
constexpr long B_CSR = 49400016;
constexpr long B_WF  = 52800016;
constexpr long B_FLG = 53478416;

// ---------------- PLAN A ws layout (CSR-ordered edge data) ----------------
constexpr long A_EAP = 0;            // bf16 [EF*32]  54,400,000 (x1 aliases here after k_score2)
constexpr long A_SRC = 54400000;     // int  [EF]      3,400,000
constexpr long A_DST = 57800000;     // int  [EF]      3,400,000
constexpr long A_SCO = 61200000;     // bf16 [EF*8]   13,600,000 (Wls/Wrs then W1s/W2s alias)
constexpr long A_EIX = 74800000;     // int  [2*Ee]    6,400,000
constexpr long A_CNT = 81200000;
constexpr long A_OFS = 81400000;
constexpr long A_CUR = 81600016;
constexpr long A_WF  = 81800016;     // fp32 [169600]
constexpr long A_FLG = 82478416;
constexpr long NEED_A = 82478432;

// canonical weight float offsets
constexpr int WF_Wl = 0, WF_bl = 16384, WF_Wr = 16512, WF_br = 32896;
constexpr int WF_We = 33024, WF_att = 37120, WF_bias = 37248;
constexpr int WF_W1 = 37376, WF_b1 = 102912, WF_W2 = 103424, WF_b2 = 168960;
constexpr int WF_g1 = 169088, WF_be1 = 169216, WF_g2 = 169344, WF_be2 = 169472;
constexpr int WF_TOT = 169600;

static __device__ __forceinline__ float b2f(__hip_bfloat16 v) { return __bfloat162float(v); }
static __device__ __forceinline__ float2 up2(uint32 u) {
    union { uint32 i; float f; } a, b;
    a.i = (u & 0xFFFFu) << 16; b.i = u & 0xFFFF0000u;
    return make_float2(a.f, b.f);
}
static __device__ __forceinline__ float up1(ushort u) {
    union { uint32 i; float f; } a; a.i = ((uint32)u) << 16; return a.f;
}
static __device__ __forceinline__ ushort f2bu(float f) {
    __hip_bfloat16 h = __float2bfloat16(f); return *(ushort*)&h;
}
static __device__ __forceinline__ float san(float v) { return fminf(fmaxf(v, -1e4f), 1e4f); }

// ================= shared kernels =================
__global__ void k_sniff(const uint32* __restrict__ xu, const uint32* __restrict__ eu,
                        int* __restrict__ flg) {
    int lane = threadIdx.x;
    int xbf = 0, ebf = 0;
    #pragma unroll
    for (int j = 0; j < 8; j++) {
        uint32 ux = xu[lane * 8 + j];
        int ex = (ux >> 7) & 0xFF;
        xbf += (ex >= 100 && ex <= 135) ? 1 : 0;
        uint32 ue = eu[lane * 8 + j];
        int ee = (ue >> 7) & 0xFF;
        ebf += (ee >= 100 && ee <= 135) ? 1 : 0;
    }
    #pragma unroll
    for (int mk = 1; mk < 64; mk <<= 1) { xbf += __shfl_xor(xbf, mk); ebf += __shfl_xor(ebf, mk); }
    if (lane == 0) { flg[0] = (xbf > 256) ? 0 : 1; flg[1] = (ebf > 256) ? 0 : 1; }
}

__global__ void k_cvt(const int* __restrict__ raw, int* __restrict__ eix,
                      int* __restrict__ cnt) {
    __shared__ int is64;
    if (threadIdx.x == 0) {
        int z = 1;
        #pragma unroll
        for (int j = 1; j < 64; j += 2) z &= (raw[j] == 0);
        is64 = z;
    }
    __syncthreads();
    int i = blockIdx.x * 256 + threadIdx.x;
    if (i < 2 * Ee) {
        int v = is64 ? raw[2 * i] : raw[i];
        v = v < 0 ? 0 : (v >= Nn ? Nn - 1 : v);
        eix[i] = v;
        if (i >= Ee) atomicAdd(&cnt[v], 1);
    }
}

struct WSrc { const void* p[15]; };
__global__ void k_wcanon(WSrc s, const int* __restrict__ flagp, float* __restrict__ dst) {
    const int cum[16] = {0, 16384, 16512, 32896, 33024, 37120, 37248, 37376,
                         102912, 103424, 168960, 169088, 169216, 169344, 169472, 169600};
    int i = blockIdx.x * 256 + threadIdx.x;
    if (i >= WF_TOT) return;
    int isf32 = flagp[0];
    int seg = 0;
    #pragma unroll
    for (int j = 1; j < 16; j++) seg += (i >= cum[j]);
    int off = i - cum[seg];
    float v = isf32 ? ((const float*)s.p[seg])[off]
                    : b2f(((const __hip_bfloat16*)s.p[seg])[off]);
    dst[i] = v;
}

__global__ void __launch_bounds__(1024) k_scan(const int* __restrict__ cnt,
                                               int* __restrict__ offs, int* __restrict__ cursor) {
    __shared__ int part[1024];
    int t = threadIdx.x;
    const int CH = (Nn + 1023) / 1024;
    int base = t * CH;
    int s = 0;
    for (int i = 0; i < CH; i++) { int n = base + i; if (n < Nn) s += cnt[n] + 1; }
    part[t] = s;
    __syncthreads();
    for (int off = 1; off < 1024; off <<= 1) {
        int v = (t >= off) ? part[t - off] : 0;
        __syncthreads();
        part[t] += v;
        __syncthreads();
    }
    int run = part[t] - s;
    for (int i = 0; i < CH; i++) {
        int n = base + i;
        if (n < Nn) { offs[n] = run; run += cnt[n] + 1; cursor[n] = 0; }
    }
    if (t == 1023) offs[Nn] = part[1023];
}

// W1/W2 -> MFMA frag order (for k_ffn)
__global__ void k_wprep(const float* __restrict__ wf,
                        ushort* __restrict__ W1s, ushort* __restrict__ W2s) {
    int i = blockIdx.x * 256 + threadIdx.x;
    if (i >= 65536) return;
    int j = i & 7, lane = (i >> 3) & 63, g = i >> 9;
    int c = lane & 15, q = lane >> 4;
    int kk = g & 3, ht = g >> 2;
    W1s[i] = f2bu(wf[WF_W1 + (kk * 32 + q * 8 + j) * 512 + ht * 16 + c]);
    int kk2 = g & 15, nt = g >> 4;
    W2s[i] = f2bu(wf[WF_W2 + (kk2 * 32 + q * 8 + j) * 128 + nt * 16 + c]);
}

// MFMA FFN + residual + LN2 -> fp32 out (shared by both plans)
__global__ void __launch_bounds__(128) k_ffn(const ushort* __restrict__ x1b,
                                             const float* __restrict__ wf,
                                             const ushort* __restrict__ W1s,
                                             const ushort* __restrict__ W2s,
                                             float* __restrict__ out) {
    __shared__ ushort hb[2][16 * 520];
    __shared__ ushort xsb[2][16 * 136];
    int wv = threadIdx.x >> 6;
    int lane = threadIdx.x & 63;
    int c = lane & 15, q = lane >> 4;
    long n0 = (long)blockIdx.x * 32 + wv * 16;
    if (n0 >= Nn) return;
    ushort* h = hb[wv];
    ushort* xs = xsb[wv];

    short8 B1[4];
    const uint4* x1row = (const uint4*)(x1b + (n0 + c) * 128);
    #pragma unroll
    for (int kk = 0; kk < 4; kk++) {
        union { uint4 u; short8 s; } cv; cv.u = x1row[kk * 4 + q]; B1[kk] = cv.s;
    }
    for (int i = lane; i < 256; i += 64) {
        int row = i >> 4, col = i & 15;
        *(uint4*)(xs + row * 136 + col * 8) = *(const uint4*)(x1b + (n0 + row) * 128 + col * 8);
    }
    const uint4* W1v = (const uint4*)W1s;
    for (int ht = 0; ht < 32; ht++) {
        float4v acc = (float4v){0.f, 0.f, 0.f, 0.f};
        #pragma unroll
        for (int kk = 0; kk < 4; kk++) {
            union { uint4 u; short8 s; } a; a.u = W1v[(ht * 4 + kk) * 64 + lane];
            acc = __builtin_amdgcn_mfma_f32_16x16x32_bf16(a.s, B1[kk], acc, 0, 0, 0);
        }
        float4 bb = *(const float4*)(wf + WF_b1 + ht * 16 + q * 4);
        uint2 pk;
        pk.x = (uint32)f2bu(fmaxf(acc[0] + bb.x, 0.f)) | ((uint32)f2bu(fmaxf(acc[1] + bb.y, 0.f)) << 16);
        pk.y = (uint32)f2bu(fmaxf(acc[2] + bb.z, 0.f)) | ((uint32)f2bu(fmaxf(acc[3] + bb.w, 0.f)) << 16);
        *(uint2*)(h + c * 520 + ht * 16 + q * 4) = pk;
    }
    const uint4* W2v = (const uint4*)W2s;
    float4v acc2[8];
    #pragma unroll
    for (int nt = 0; nt < 8; nt++) acc2[nt] = (float4v){0.f, 0.f, 0.f, 0.f};
    for (int kk2 = 0; kk2 < 16; kk2++) {
        union { uint4 u; short8 s; } a2;
        a2.u = *(const uint4*)(h + c * 520 + kk2 * 32 + q * 8);
        #pragma unroll
        for (int nt = 0; nt < 8; nt++) {
            union { uint4 u; short8 s; } b2f_;
            b2f_.u = W2v[(nt * 16 + kk2) * 64 + lane];
            acc2[nt] = __builtin_amdgcn_mfma_f32_16x16x32_bf16(a2.s, b2f_.s, acc2[nt], 0, 0, 0);
        }
    }
    float b2v[8], g2v[8], be2v[8];
    #pragma unroll
    for (int nt = 0; nt < 8; nt++) {
        b2v[nt]  = wf[WF_b2  + nt * 16 + c];
        g2v[nt]  = wf[WF_g2  + nt * 16 + c];
        be2v[nt] = wf[WF_be2 + nt * 16 + c];
    }
    float yv[8][4];
    float sum[4] = {0.f, 0.f, 0.f, 0.f}, sq[4] = {0.f, 0.f, 0.f, 0.f};
    #pragma unroll
    for (int nt = 0; nt < 8; nt++) {
        #pragma unroll
        for (int r = 0; r < 4; r++) {
            float v = acc2[nt][r] + b2v[nt] + up1(xs[(q * 4 + r) * 136 + nt * 16 + c]);
            yv[nt][r] = v;
            sum[r] += v; sq[r] += v * v;
        }
    }
    #pragma unroll
    for (int mask = 1; mask < 16; mask <<= 1) {
        #pragma unroll
        for (int r = 0; r < 4; r++) {
            sum[r] += __shfl_xor(sum[r], mask);
            sq[r]  += __shfl_xor(sq[r], mask);
        }
    }
    #pragma unroll
    for (int r = 0; r < 4; r++) {
        float mean = sum[r] * (1.0f / 128.0f);
        float var = sq[r] * (1.0f / 128.0f) - mean * mean;
        float rstd = rsqrtf(var + 1e-5f);
        long nodeb = (n0 + q * 4 + r) * 128;
        #pragma unroll
        for (int nt = 0; nt < 8; nt++) {
            out[nodeb + nt * 16 + c] = san((yv[nt][r] - mean) * rstd * g2v[nt] + be2v[nt]);
        }
    }
}

// ================= PLAN A kernels =================
// Wl/Wr -> MFMA frag order
__global__ void k_wprepL(const float* __restrict__ wf,
                         ushort* __restrict__ Wls, ushort* __restrict__ Wrs) {
    int i = blockIdx.x * 256 + threadIdx.x;
    if (i >= 16384) return;
    int j = i & 7, lane = (i >> 3) & 63, g = i >> 9;   // g = ot*4+kk
    int c = lane & 15, q = lane >> 4;
    int kk = g & 3, ot = g >> 2;
    int kin = kk * 32 + q * 8 + j, outd = ot * 16 + c;
    Wls[i] = f2bu(wf[WF_Wl + kin * 128 + outd]);
    Wrs[i] = f2bu(wf[WF_Wr + kin * 128 + outd]);
}

// fused xl = x@Wl+bl, xr = x@Wr+br via MFMA; 16 nodes/wave
__global__ void __launch_bounds__(256) k_linlr(const void* __restrict__ x,
                                               const float* __restrict__ wf,
                                               const ushort* __restrict__ Wls,
                                               const ushort* __restrict__ Wrs,
                                               const int* __restrict__ flagp,
                                               ushort* __restrict__ xl,
                                               ushort* __restrict__ xr) {
    int isf32 = flagp[0];
    int wv = threadIdx.x >> 6, lane = threadIdx.x & 63;
    int c = lane & 15, q = lane >> 4;
    long n0 = ((long)blockIdx.x * 4 + wv) * 16;
    if (n0 >= Nn) return;
    short8 B[4];
    if (isf32) {
        const float* xrow = (const float*)x + (n0 + c) * 128;
        #pragma unroll
        for (int kk = 0; kk < 4; kk++)
            #pragma unroll
            for (int j = 0; j < 8; j++)
                B[kk][j] = (short)f2bu(xrow[kk * 32 + q * 8 + j]);
    } else {
        const uint4* xrow = (const uint4*)((const ushort*)x + (n0 + c) * 128);
        #pragma unroll
        for (int kk = 0; kk < 4; kk++) {
            union { uint4 u; short8 s; } cv; cv.u = xrow[kk * 4 + q]; B[kk] = cv.s;
        }
    }
    const uint4* Al = (const uint4*)Wls;
    const uint4* Ar = (const uint4*)Wrs;
    #pragma unroll
    for (int ot = 0; ot < 8; ot++) {
        float4v aL = (float4v){0.f, 0.f, 0.f, 0.f};
        float4v aR = (float4v){0.f, 0.f, 0.f, 0.f};
        #pragma unroll
        for (int kk = 0; kk < 4; kk++) {
            union { uint4 u; short8 s; } a, b;
            a.u = Al[(ot * 4 + kk) * 64 + lane];
            b.u = Ar[(ot * 4 + kk) * 64 + lane];
            aL = __builtin_amdgcn_mfma_f32_16x16x32_bf16(a.s, B[kk], aL, 0, 0, 0);
            aR = __builtin_amdgcn_mfma_f32_16x16x32_bf16(b.s, B[kk], aR, 0, 0, 0);
        }
        float4 bl4 = *(const float4*)(wf + WF_bl + ot * 16 + q * 4);
        float4 br4 = *(const float4*)(wf + WF_br + ot * 16 + q * 4);
        uint2 pl, pr;
        pl.x = (uint32)f2bu(san(aL[0] + bl4.x)) | ((uint32)f2bu(san(aL[1] + bl4.y)) << 16);
        pl.y = (uint32)f2bu(san(aL[2] + bl4.z)) | ((uint32)f2bu(san(aL[3] + bl4.w)) << 16);
        pr.x = (uint32)f2bu(san(aR[0] + br4.x)) | ((uint32)f2bu(san(aR[1] + br4.y)) << 16);
        pr.y = (uint32)f2bu(san(aR[2] + br4.z)) | ((uint32)f2bu(san(aR[3] + br4.w)) << 16);
        *(uint2*)(xl + (n0 + c) * 128 + ot * 16 + q * 4) = pl;
        *(uint2*)(xr + (n0 + c) * 128 + ot * 16 + q * 4) = pr;
    }
}

// scatter edges into CSR slot order: eap (bf16 rows), srcp, dstp
__global__ void __launch_bounds__(256) k_fill2(const int* __restrict__ eix,
                                               const void* __restrict__ eattr,
                                               const int* __restrict__ flagp,
                                               int* __restrict__ cur,
                                               const int* __restrict__ offs,
                                               ushort* __restrict__ eap,
                                               int* __restrict__ srcp,
                                               int* __restrict__ dstp) {
    int isf32 = flagp[1];
    int gid = blockIdx.x * 256 + threadIdx.x;   // grid exact: Ee*4 threads
    int e = gid >> 2, sub = gid & 3;
    int lane = threadIdx.x & 63;
    int d = eix[Ee + e];
    int p = 0;
    if (sub == 0) p = offs[d] + atomicAdd(&cur[d], 1);
    p = __shfl(p, lane & ~3);
    if (sub == 0) { srcp[p] = eix[e]; dstp[p] = d; }
    uint4 o;
    if (isf32) {
        const float* r = (const float*)eattr + (long)e * 32 + sub * 8;
        o.x = (uint32)f2bu(r[0]) | ((uint32)f2bu(r[1]) << 16);
        o.y = (uint32)f2bu(r[2]) | ((uint32)f2bu(r[3]) << 16);
        o.z = (uint32)f2bu(r[4]) | ((uint32)f2bu(r[5]) << 16);
        o.w = (uint32)f2bu(r[6]) | ((uint32)f2bu(r[7]) << 16);
    } else {
        o = ((const uint4*)eattr)[(long)e * 4 + sub];
    }
    *(uint4*)(eap + (long)p * 32 + sub * 8) = o;
}

// self-loop slot = mean of incoming (sequential bf16 rows)
__global__ void __launch_bounds__(256) k_self(const int* __restrict__ offs,
                                              ushort* __restrict__ eap,
                                              int* __restrict__ srcp,
                                              int* __restrict__ dstp) {
    int lane = threadIdx.x & 63;
    int n = (blockIdx.x * 256 + threadIdx.x) >> 6;
    if (n >= Nn) return;
    int off = offs[n], deg1 = offs[n + 1] - 1 - off;   // real incoming count
    int k = lane & 31, half = lane >> 5;
    float acc = 0.f;
    for (int i = half; i < deg1; i += 2)
        acc += up1(eap[(long)(off + i) * 32 + k]);
    acc += __shfl_xor(acc, 32);
    float inv = 1.0f / fmaxf((float)deg1, 1.0f);
    long ps = off + deg1;
    if (lane < 32) eap[ps * 32 + k] = f2bu(san(acc * inv));
    if (lane == 0) { srcp[ps] = n; dstp[ps] = n; }
}

// branchless slot-major MFMA scores
__global__ void __launch_bounds__(256) k_score2(const ushort* __restrict__ eap,
                                                const int* __restrict__ srcp,
                                                const int* __restrict__ dstp,
                                                const float* __restrict__ wf,
                                                const uint32* __restrict__ xlu,
                                                const uint32* __restrict__ xru,
                                                uint4* __restrict__ score16) {
    int t256 = threadIdx.x;
    int lane = t256 & 63;
    int c0 = lane & 15, q = lane >> 4;
    int w = (blockIdx.x * 256 + t256) >> 6;
    int nw = (gridDim.x * 256) >> 6;

    short8 A[8];
    float att[8][4];
    #pragma unroll
    for (int t = 0; t < 8; t++) {
        #pragma unroll
        for (int j = 0; j < 8; j++)
            A[t][j] = (short)f2bu(wf[WF_We + (q * 8 + j) * 128 + t * 16 + c0]);
        #pragma unroll
        for (int r = 0; r < 4; r++)
            att[t][r] = wf[WF_att + t * 16 + q * 4 + r];
    }

    for (int T = w; T < NT; T += nw) {
        int slot = T * 16 + c0;
        int srcn = srcp[slot], dstn = dstp[slot];
        union { uint4 u; short8 s; } cv;
        cv.u = *(const uint4*)(eap + (long)slot * 32 + q * 8);
        short8 B = cv.s;

        float4v acc[8];
        #pragma unroll
        for (int t = 0; t < 8; t++) {
            acc[t] = (float4v){0.f, 0.f, 0.f, 0.f};
            acc[t] = __builtin_amdgcn_mfma_f32_16x16x32_bf16(A[t], B, acc[t], 0, 0, 0);
        }
        uint2 xg[8], rg[8];
        #pragma unroll
        for (int t = 0; t < 8; t++) {
            xg[t] = ((const uint2*)xlu)[(long)srcn * 32 + t * 4 + q];
            rg[t] = ((const uint2*)xru)[(long)dstn * 32 + t * 4 + q];
        }
        float st[8];
        #pragma unroll
        for (int t = 0; t < 8; t++) {
            float2 xa = up2(xg[t].x), xb2 = up2(xg[t].y);
            float2 ra = up2(rg[t].x), rb = up2(rg[t].y);
            float v0 = acc[t][0] + xa.x + ra.x;
            float v1 = acc[t][1] + xa.y + ra.y;
            float v2 = acc[t][2] + xb2.x + rb.x;
            float v3 = acc[t][3] + xb2.y + rb.y;
            v0 = v0 > 0.f ? v0 : 0.2f * v0;
            v1 = v1 > 0.f ? v1 : 0.2f * v1;
            v2 = v2 > 0.f ? v2 : 0.2f * v2;
            v3 = v3 > 0.f ? v3 : 0.2f * v3;
            st[t] = att[t][0] * v0 + att[t][1] * v1 + att[t][2] * v2 + att[t][3] * v3;
        }
        #pragma unroll
        for (int t = 0; t < 8; t++) {
            st[t] += __shfl_xor(st[t], 16);
            st[t] += __shfl_xor(st[t], 32);
        }
        if (q == 0) {
            uint4 o;
            o.x = (uint32)f2bu(san(st[0])) | ((uint32)f2bu(san(st[1])) << 16);
            o.y = (uint32)f2bu(san(st[2])) | ((uint32)f2bu(san(st[3])) << 16);
            o.z = (uint32)f2bu(san(st[4])) | ((uint32)f2bu(san(st[5])) << 16);
            o.w = (uint32)f2bu(san(st[6])) | ((uint32)f2bu(san(st[7])) << 16);
            score16[slot] = o;
        }
    }
}

// softmax + aggregate + bias + residual + LN1 (sequential scores/srcp)
__global__ void __launch_bounds__(256) k_agg2(const ushort* __restrict__ scu,
                                              const int* __restrict__ offs,
                                              const int* __restrict__ srcp,
                                              const uint32* __restrict__ xlu,
                                              const void* __restrict__ x,
                                              const float* __restrict__ wf,
                                              const int* __restrict__ flagp,
                                              uint4* __restrict__ x1) {
    int isf32 = flagp[0];
    int lane = threadIdx.x & 63;
    int n = (blockIdx.x * 256 + threadIdx.x) >> 6;
    int off = offs[n], deg = offs[n + 1] - off;

    float m[8], s[8];
    #pragma unroll
    for (int h = 0; h < 8; h++) { m[h] = -1e30f; s[h] = 0.f; }
    for (int i = lane; i < deg; i += 64) {
        uint4 qv = *((const uint4*)(scu + (long)(off + i) * 8));
        float2 p0 = up2(qv.x), p1 = up2(qv.y), p2 = up2(qv.z), p3 = up2(qv.w);
        float sc[8] = {p0.x, p0.y, p1.x, p1.y, p2.x, p2.y, p3.x, p3.y};
        #pragma unroll
        for (int h = 0; h < 8; h++) {
            float mn = fmaxf(m[h], sc[h]);
            s[h] = s[h] * __expf(m[h] - mn) + __expf(sc[h] - mn);
            m[h] = mn;
        }
    }
    #pragma unroll
    for (int mask = 1; mask < 64; mask <<= 1) {
        #pragma unroll
        for (int h = 0; h < 8; h++) {
            float m2 = __shfl_xor(m[h], mask);
            float s2 = __shfl_xor(s[h], mask);
            float mn = fmaxf(m[h], m2);
            s[h] = s[h] * __expf(m[h] - mn) + s2 * __expf(m2 - mn);
            m[h] = mn;
        }
    }
    int g = lane >> 3, hh = lane & 7;
    float mh = m[0], sh = s[0];
    #pragma unroll
    for (int j = 1; j < 8; j++) { if (hh == j) { mh = m[j]; sh = s[j]; } }
    float inv = 1.0f / sh;

    float acc[16];
    #pragma unroll
    for (int j = 0; j < 16; j++) acc[j] = 0.f;
    for (int i = g; i < deg; i += 8) {
        long sl = off + i;
        float alpha = __expf(up1(scu[sl * 8 + hh]) - mh) * inv;
        int srcn = srcp[sl];
        uint4 a = ((const uint4*)xlu)[(long)srcn * 16 + hh * 2];
        uint4 b = ((const uint4*)xlu)[(long)srcn * 16 + hh * 2 + 1];
        float2 v0 = up2(a.x), v1 = up2(a.y), v2 = up2(a.z), v3 = up2(a.w);
        float2 v4 = up2(b.x), v5 = up2(b.y), v6 = up2(b.z), v7 = up2(b.w);
        acc[0] += alpha * v0.x;  acc[1] += alpha * v0.y;
        acc[2] += alpha * v1.x;  acc[3] += alpha * v1.y;
        acc[4] += alpha * v2.x;  acc[5] += alpha * v2.y;
        acc[6] += alpha * v3.x;  acc[7] += alpha * v3.y;
        acc[8] += alpha * v4.x;  acc[9] += alpha * v4.y;
        acc[10] += alpha * v5.x; acc[11] += alpha * v5.y;
        acc[12] += alpha * v6.x; acc[13] += alpha * v6.y;
        acc[14] += alpha * v7.x; acc[15] += alpha * v7.y;
    }
    #pragma unroll
    for (int mask = 8; mask < 64; mask <<= 1) {
        #pragma unroll
        for (int j = 0; j < 16; j++) acc[j] += __shfl_xor(acc[j], mask);
    }
    float y[16];
    if (g == 0) {
        int d0 = hh * 16;
        if (isf32) {
            const float4* xf = (const float4*)x;
            #pragma unroll
            for (int c = 0; c < 4; c++) {
                float4 xv = xf[(long)n * 32 + hh * 4 + c];
                y[c*4+0] = acc[c*4+0] + xv.x + wf[WF_bias + d0 + c*4+0];
                y[c*4+1] = acc[c*4+1] + xv.y + wf[WF_bias + d0 + c*4+1];
                y[c*4+2] = acc[c*4+2] + xv.z + wf[WF_bias + d0 + c*4+2];
                y[c*4+3] = acc[c*4+3] + xv.w + wf[WF_bias + d0 + c*4+3];
            }
        } else {
            const uint4* xb = (const uint4*)x;
            uint4 a = xb[(long)n * 16 + hh * 2];
            uint4 b = xb[(long)n * 16 + hh * 2 + 1];
            uint32 ww[8] = {a.x, a.y, a.z, a.w, b.x, b.y, b.z, b.w};
            #pragma unroll
            for (int c = 0; c < 8; c++) {
                float2 v = up2(ww[c]);
                y[c*2+0] = acc[c*2+0] + v.x + wf[WF_bias + d0 + c*2+0];
                y[c*2+1] = acc[c*2+1] + v.y + wf[WF_bias + d0 + c*2+1];
            }
        }
    }
    float sum = 0.f, sq = 0.f;
    if (g == 0) {
        #pragma unroll
        for (int j = 0; j < 16; j++) { sum += y[j]; sq += y[j] * y[j]; }
    }
    #pragma unroll
    for (int mask = 1; mask < 8; mask <<= 1) { sum += __shfl_xor(sum, mask); sq += __shfl_xor(sq, mask); }
    if (g == 0) {
        int d0 = hh * 16;
        float mean = sum * (1.0f / 128.0f);
        float var = sq * (1.0f / 128.0f) - mean * mean;
        float rstd = rsqrtf(var + 1e-5f);
        uint32 o[8];
        #pragma unroll
        for (int c = 0; c < 8; c++) {
            float o0 = san((y[c*2+0] - mean) * rstd * wf[WF_g1 + d0 + c*2+0] + wf[WF_be1 + d0 + c*2+0]);
            float o1 = san((y[c*2+1] - mean) * rstd * wf[WF_g1 + d0 + c*2+1] + wf[WF_be1 + d0 + c*2+1]);
            o[c] = (uint32)f2bu(o0) | ((uint32)f2bu(o1) << 16);
        }
        x1[(long)n * 16 + hh * 2]     = make_uint4(o[0], o[1], o[2], o[3]);
        x1[(long)n * 16 + hh * 2 + 1] = make_uint4(o[4], o[5], o[6], o[7]);
    }
}

// ================= PLAN B (round-7) kernels =================
__global__ void k_fill(const int* __restrict__ eix, int* __restrict__ cursor,
                       const int* __restrict__ offs, int* __restrict__ csr) {
    int e = blockIdx.x * 256 + threadIdx.x;
    if (e >= EF) return;
    int d = (e < Ee) ? eix[Ee + e] : (e - Ee);
    int p = atomicAdd(&cursor[d], 1);
    csr[offs[d] + p] = e;
}

__global__ void __launch_bounds__(256) k_loopattr(const void* __restrict__ eattr,
                                                  const int* __restrict__ csr,
                                                  const int* __restrict__ offs,
                                                  const int* __restrict__ flagp,
                                                  __hip_bfloat16* __restrict__ la) {
    int isf32 = flagp[1];
    int lane = threadIdx.x & 63;
    int n = (blockIdx.x * 256 + threadIdx.x) >> 6;
    if (n >= Nn) return;
    int off = offs[n], deg = offs[n + 1] - off;
    int k = lane & 31, half = lane >> 5;
    const float* ef = (const float*)eattr;
    const __hip_bfloat16* eb = (const __hip_bfloat16*)eattr;
    float acc = 0.f;
    for (int i = half; i < deg; i += 2) {
        int e = csr[off + i];
        if (e < Ee) acc += isf32 ? ef[(long)e * 32 + k] : b2f(eb[(long)e * 32 + k]);
    }
    acc += __shfl_xor(acc, 32);
    float inv = 1.0f / fmaxf((float)(deg - 1), 1.0f);
    if (lane < 32) la[(long)n * 32 + k] = __float2bfloat16(san(acc * inv));
}

__global__ void __launch_bounds__(256) k_lin(const void* __restrict__ x,
                                             const float* __restrict__ Wf,
                                             const float* __restrict__ bf_,
                                             const int* __restrict__ flagp,
                                             __hip_bfloat16* __restrict__ out) {
    __shared__ ushort Wlds[128][130];
    __shared__ float xrow[2][128];
    int isf32 = flagp[0];
    int t = threadIdx.x, col = t & 127, sub = t >> 7;
    for (int i = t; i < 16384; i += 256) Wlds[i >> 7][i & 127] = f2bu(Wf[i]);
    float bias = bf_[col];
    const float* xf = (const float*)x;
    const __hip_bfloat16* xb = (const __hip_bfloat16*)x;
    int rpb = (Nn + gridDim.x - 1) / gridDim.x;
    int r0 = blockIdx.x * rpb, r1 = min(r0 + rpb, Nn);
    __syncthreads();
    for (int r = r0; r < r1; r += 2) {
        int rr = r + sub;
        if (rr < r1) xrow[sub][col] = isf32 ? xf[(long)rr * 128 + col]
                                            : b2f(xb[(long)rr * 128 + col]);
        __syncthreads();
        float acc = bias;
        #pragma unroll 16
        for (int k = 0; k < 128; k++) {
            union { uint32 i; float f; } u; u.i = ((uint32)Wlds[k][col]) << 16;
            acc += xrow[sub][k] * u.f;
        }
        if (rr < r1) out[(long)rr * 128 + col] = __float2bfloat16(san(acc));
        __syncthreads();
    }
}

__global__ void __launch_bounds__(256) k_score(const void* __restrict__ eattr,
                                               const int* __restrict__ eix,
                                               const uint32* __restrict__ la_u,
                                               const float* __restrict__ wf,
                                               const int* __restrict__ flagp,
                                               const uint32* __restrict__ xlu,
                                               const uint32* __restrict__ xru,
                                               uint4* __restrict__ score16) {
    int isf32 = flagp[1];
    int t256 = threadIdx.x;
    int lane = t256 & 63;
    int c0 = lane & 15, q = lane >> 4;
    int w = (blockIdx.x * 256 + t256) >> 6;
    int nw = (gridDim.x * 256) >> 6;
    short8 A[8];
    float att[8][4];
    #pragma unroll
    for (int t = 0; t < 8; t++) {
        #pragma unroll
        for (int j = 0; j < 8; j++)
            A[t][j] = (short)f2bu(wf[WF_We + (q * 8 + j) * 128 + t * 16 + c0]);
        #pragma unroll
        for (int r = 0; r < 4; r++)
            att[t][r] = wf[WF_att + t * 16 + q * 4 + r];
    }
    const float* ef = (const float*)eattr;
    const uint4* eb4 = (const uint4*)eattr;
    for (int T = w; T < NT; T += nw) {
        int row = T * 16 + c0;
        int srcn, dstn;
        short8 B;
        if (T < TE) {
            srcn = eix[row]; dstn = eix[Ee + row];
            if (isf32) {
                const float* p = ef + (long)row * 32 + q * 8;
                #pragma unroll
                for (int j = 0; j < 8; j++) B[j] = (short)f2bu(p[j]);
            } else {
                union { uint4 u; short8 s; } cv;
                cv.u = eb4[(long)row * 4 + q];
                B = cv.s;
            }
        } else {
            int n = row - Ee;
            srcn = n; dstn = n;
            union { uint4 u; short8 s; } cv;
            cv.u = ((const uint4*)la_u)[(long)n * 4 + q];
            B = cv.s;
        }
        float4v acc[8];
        #pragma unroll
        for (int t = 0; t < 8; t++) {
            acc[t] = (float4v){0.f, 0.f, 0.f, 0.f};
            acc[t] = __builtin_amdgcn_mfma_f32_16x16x32_bf16(A[t], B, acc[t], 0, 0, 0);
        }
        uint2 xg[8], rg[8];
        #pragma unroll
        for (int t = 0; t < 8; t++) {
            xg[t] = ((const uint2*)xlu)[(long)srcn * 32 + t * 4 + q];
            rg[t] = ((const uint2*)xru)[(long)dstn * 32 + t * 4 + q];
        }
        float st[8];
        #pragma unroll
        for (int t = 0; t < 8; t++) {
            float2 xa = up2(xg[t].x), xb2 = up2(xg[t].y);
            float2 ra = up2(rg[t].x), rb = up2(rg[t].y);
            float v0 = acc[t][0] + xa.x + ra.x;
            float v1 = acc[t][1] + xa.y + ra.y;
            float v2 = acc[t][2] + xb2.x + rb.x;
            float v3 = acc[t][3] + xb2.y + rb.y;
            v0 = v0 > 0.f ? v0 : 0.2f * v0;
            v1 = v1 > 0.f ? v1 : 0.2f * v1;
            v2 = v2 > 0.f ? v2 : 0.2f * v2;
            v3 = v3 > 0.f ? v3 : 0.2f * v3;
            st[t] = att[t][0] * v0 + att[t][1] * v1 + att[t][2] * v2 + att[t][3] * v3;
        }
        #pragma unroll
        for (int t = 0; t < 8; t++) {
            st[t] += __shfl_xor(st[t], 16);
            st[t] += __shfl_xor(st[t], 32);
        }
        if (q == 0) {
            uint4 o;
            o.x = (uint32)f2bu(san(st[0])) | ((uint32)f2bu(san(st[1])) << 16);
            o.y = (uint32)f2bu(san(st[2])) | ((uint32)f2bu(san(st[3])) << 16);
            o.z = (uint32)f2bu(san(st[4])) | ((uint32)f2bu(san(st[5])) << 16);
            o.w = (uint32)f2bu(san(st[6])) | ((uint32)f2bu(san(st[7])) << 16);
            score16[row] = o;
        }
    }
}

__global__ void __launch_bounds__(256) k_agg(const ushort* __restrict__ scu,
                                             const int* __restrict__ csr, const int* __restrict__ offs,
                                             const int* __restrict__ eix,
                                             const uint32* __restrict__ xlu,
                                             const void* __restrict__ x,
                                             const float* __restrict__ wf,
                                             const int* __restrict__ flagp,
                                             uint4* __restrict__ x1) {
    int isf32 = flagp[0];
    int lane = threadIdx.x & 63;
    int n = (blockIdx.x * 256 + threadIdx.x) >> 6;
    int off = offs[n], deg = offs[n + 1] - off;
    float m[8], s[8];
    #pragma unroll
    for (int h = 0; h < 8; h++) { m[h] = -1e30f; s[h] = 0.f; }
    for (int i = lane; i < deg; i += 64) {
        int e = csr[off + i];
        uint4 qv = *((const uint4*)(scu + (long)e * 8));
        float2 p0 = up2(qv.x), p1 = up2(qv.y), p2 = up2(qv.z), p3 = up2(qv.w);
        float sc[8] = {p0.x, p0.y, p1.x, p1.y, p2.x, p2.y, p3.x, p3.y};
        #pragma unroll
        for (int h = 0; h < 8; h++) {
            float mn = fmaxf(m[h], sc[h]);
            s[h] = s[h] * __expf(m[h] - mn) + __expf(sc[h] - mn);
            m[h] = mn;
        }
    }
    #pragma unroll
    for (int mask = 1; mask < 64; mask <<= 1) {
        #pragma unroll
        for (int h = 0; h < 8; h++) {
            float m2 = __shfl_xor(m[h], mask);
            float s2 = __shfl_xor(s[h], mask);
            float mn = fmaxf(m[h], m2);
            s[h] = s[h] * __expf(m[h] - mn) + s2 * __expf(m2 - mn);
            m[h] = mn;
        }
    }
    int g = lane >> 3, hh = lane & 7;
    float mh = m[0], sh = s[0];
    #pragma unroll
    for (int j = 1; j < 8; j++) { if (hh == j) { mh = m[j]; sh = s[j]; } }
    float inv = 1.0f / sh;
    float acc[16];
    #pragma unroll
    for (int j = 0; j < 16; j++) acc[j] = 0.f;
    for (int i = g; i < deg; i += 8) {
        int e = csr[off + i];
        float alpha = __expf(up1(scu[(long)e * 8 + hh]) - mh) * inv;
        int srcn = (e < Ee) ? eix[e] : (e - Ee);
        uint4 a = ((const uint4*)xlu)[(long)srcn * 16 + hh * 2];
        uint4 b = ((const uint4*)xlu)[(long)srcn * 16 + hh * 2 + 1];
        float2 v0 = up2(a.x), v1 = up2(a.y), v2 = up2(a.z), v3 = up2(a.w);
        float2 v4 = up2(b.x), v5 = up2(b.y), v6 = up2(b.z), v7 = up2(b.w);
        acc[0] += alpha * v0.x;  acc[1] += alpha * v0.y;
        acc[2] += alpha * v1.x;  acc[3] += alpha * v1.y;
        acc[4] += alpha * v2.x;  acc[5] += alpha * v2.y;
        acc[6] += alpha * v3.x;  acc[7] += alpha * v3.y;
        acc[8] += alpha * v4.x;  acc[9] += alpha * v4.y;
        acc[10] += alpha * v5.x; acc[11] += alpha * v5.y;
        acc[12] += alpha * v6.x; acc[13] += alpha * v6.y;
        acc[14] += alpha * v7.x; acc[15] += alpha * v7.y;
    }
    #pragma unroll
    for (int mask = 8; mask < 64; mask <<= 1) {
        #pragma unroll
        for (int j = 0; j < 16; j++) acc[j] += __shfl_xor(acc[j], mask);
    }
    float y[16];
    if (g == 0) {
        int d0 = hh * 16;
        if (isf32) {
            const float4* xf = (const float4*)x;
            #pragma unroll
            for (int c = 0; c < 4; c++) {
                float4 xv = xf[(long)n * 32 + hh * 4 + c];
                y[c*4+0] = acc[c*4+0] + xv.x + wf[WF_bias + d0 + c*4+0];
                y[c*4+1] = acc[c*4+1] + xv.y + wf[WF_bias + d0 + c*4+1];
                y[c*4+2] = acc[c*4+2] + xv.z + wf[WF_bias + d0 + c*4+2];
                y[c*4+3] = acc[c*4+3] + xv.w + wf[WF_bias + d0 + c*4+3];
            }
        } else {
            const uint4* xb = (const uint4*)x;
            uint4 a = xb[(long)n * 16 + hh * 2];
            uint4 b = xb[(long)n * 16 + hh * 2 + 1];
            uint32 ww[8] = {a.x, a.y, a.z, a.w, b.x, b.y, b.z, b.w};
            #pragma unroll
            for (int c = 0; c < 8; c++) {
                float2 v = up2(ww[c]);
                y[c*2+0] = acc[c*2+0] + v.x + wf[WF_bias + d0 + c*2+0];
                y[c*2+1] = acc[c*2+1] + v.y + wf[WF_bias + d0 + c*2+1];
            }
        }
    }
    float sum = 0.f, sq = 0.f;
    if (g == 0) {
        #pragma unroll
        for (int j = 0; j < 16; j++) { sum += y[j]; sq += y[j] * y[j]; }
    }
    #pragma unroll
    for (int mask = 1; mask < 8; mask <<= 1) { sum += __shfl_xor(sum, mask); sq += __shfl_xor(sq, mask); }
    if (g == 0) {
        int d0 = hh * 16;
        float mean = sum * (1.0f / 128.0f);
        float var = sq * (1.0f / 128.0f) - mean * mean;
        float rstd = rsqrtf(var + 1e-5f);
        uint32 o[8];
        #pragma unroll
        for (int c = 0; c < 8; c++) {
            float o0 = san((y[c*2+0] - mean) * rstd * wf[WF_g1 + d0 + c*2+0] + wf[WF_be1 + d0 + c*2+0]);
            float o1 = san((y[c*2+1] - mean) * rstd * wf[WF_g1 + d0 + c*2+1] + wf[WF_be1 + d0 + c*2+1]);
            o[c] = (uint32)f2bu(o0) | ((uint32)f2bu(o1) << 16);
        }
        x1[(long)n * 16 + hh * 2]     = make_uint4(o[0], o[1], o[2], o[3]);
        x1[(long)n * 16 + hh * 2 + 1] = make_uint4(o[4], o[5], o[6], o[7]);
    }
}

// ---------------- launch ----------------
extern "C" void kernel_launch(void* const* d_in, const int* in_sizes, int n_in,
                              void* d_out, int out_size, void* d_ws, size_t ws_size,
                              hipStream_t stream) {
    const void* x     = d_in[0];
    const int*  eraw  = (const int*)d_in[1];
    const void* eattr = d_in[2];
    char* wsb = (char*)d_ws;
    WSrc wsrc;
    for (int i = 0; i < 15; i++) wsrc.p[i] = d_in[3 + i];

    if (ws_size >= (size_t)NEED_A) {
        // ---- PLAN A: CSR-ordered edge pipeline ----
        ushort* eap = (ushort*)(wsb + A_EAP);
        int*   srcp = (int*)(wsb + A_SRC);
        int*   dstp = (int*)(wsb + A_DST);
        ushort* sc  = (ushort*)(wsb + A_SCO);
        ushort* Wls = (ushort*)(wsb + A_SCO);
        ushort* Wrs = (ushort*)(wsb + A_SCO + 32768);
        ushort* W1s = (ushort*)(wsb + A_SCO);
        ushort* W2s = (ushort*)(wsb + A_SCO + 131072);
        int*   eix  = (int*)(wsb + A_EIX);
        int*   cnt  = (int*)(wsb + A_CNT);
        int*   offs = (int*)(wsb + A_OFS);
        int*   cur  = (int*)(wsb + A_CUR);
        float* wf   = (float*)(wsb + A_WF);
        int*   flg  = (int*)(wsb + A_FLG);
        ushort* x1  = (ushort*)(wsb + A_EAP);            // alias: eap dead after k_score2
        ushort* xl  = (ushort*)d_out;                     // d_out first half (bf16)
        ushort* xr  = (ushort*)d_out + (long)Nn * 128;    // d_out second half

        hipMemsetAsync(cnt, 0, Nn * sizeof(int), stream);
        k_sniff<<<1, 64, 0, stream>>>((const uint32*)x, (const uint32*)eattr, flg);
        k_cvt<<<(2 * Ee + 255) / 256, 256, 0, stream>>>(eraw, eix, cnt);
        k_wcanon<<<(WF_TOT + 255) / 256, 256, 0, stream>>>(wsrc, flg, wf);
        k_scan<<<1, 1024, 0, stream>>>(cnt, offs, cur);
        k_wprepL<<<64, 256, 0, stream>>>(wf, Wls, Wrs);
        k_linlr<<<(Nn / 16 + 3) / 4, 256, 0, stream>>>(x, wf, Wls, Wrs, flg, xl, xr);
        k_fill2<<<Ee * 4 / 256, 256, 0, stream>>>(eix, eattr, flg, cur, offs, eap, srcp, dstp);
        k_self<<<(Nn + 3) / 4, 256, 0, stream>>>(offs, eap, srcp, dstp);
        k_score2<<<2048, 256, 0, stream>>>(eap, srcp, dstp, wf,
                                           (const uint32*)xl, (const uint32*)xr, (uint4*)sc);
        k_agg2<<<(Nn + 3) / 4, 256, 0, stream>>>(sc, offs, srcp, (const uint32*)xl,
                                                 x, wf, flg, (uint4*)x1);
        k_wprep<<<256, 256, 0, stream>>>(wf, W1s, W2s);
        k_ffn<<<(Nn + 31) / 32, 128, 0, stream>>>(x1, wf, W1s, W2s, (float*)d_out);
    } else {
        // ---- PLAN B: proven round-7 pipeline ----
        __hip_bfloat16* sc  = (__hip_bfloat16*)(wsb + B_SC);
        __hip_bfloat16* xl  = (__hip_bfloat16*)(wsb + B_XL);
        __hip_bfloat16* x1  = (__hip_bfloat16*)(wsb + B_X1);
        __hip_bfloat16* la  = (__hip_bfloat16*)(wsb + B_LA);
        int*   eix  = (int*)(wsb + B_EIX);
        int*   cnt  = (int*)(wsb + B_CNT);
        int*   offs = (int*)(wsb + B_OFS);
        int*   cur  = (int*)(wsb + B_CUR);
        int*   csr  = (int*)(wsb + B_CSR);
        float* wf   = (float*)(wsb + B_WF);
        int*   flg  = (int*)(wsb + B_FLG);
        __hip_bfloat16* xr  = (__hip_bfloat16*)d_out;
        ushort* W1s = (ushort*)(wsb + B_SC);
        ushort* W2s = (ushort*)(wsb + B_SC + 131072);

        hipMemsetAsync(cnt, 0, Nn * sizeof(int), stream);
        k_sniff<<<1, 64, 0, stream>>>((const uint32*)x, (const uint32*)eattr, flg);
        k_cvt<<<(2 * Ee + 255) / 256, 256, 0, stream>>>(eraw, eix, cnt);
        k_wcanon<<<(WF_TOT + 255) / 256, 256, 0, stream>>>(wsrc, flg, wf);
        k_scan<<<1, 1024, 0, stream>>>(cnt, offs, cur);
        k_fill<<<(EF + 255) / 256, 256, 0, stream>>>(eix, cur, offs, csr);
        k_loopattr<<<(Nn + 3) / 4, 256, 0, stream>>>(eattr, csr, offs, flg, la);
        k_lin<<<512, 256, 0, stream>>>(x, wf + WF_Wl, wf + WF_bl, flg, xl);
        k_lin<<<512, 256, 0, stream>>>(x, wf + WF_Wr, wf + WF_br, flg, xr);
        k_score<<<2048, 256, 0, stream>>>(eattr, eix, (const uint32*)la, wf, flg,
                                          (const uint32*)xl, (const uint32*)xr, (uint4*)sc);
        k_agg<<<(Nn + 3) / 4, 256, 0, stream>>>((const ushort*)sc, csr, offs, eix,
                                                (const uint32*)xl, x, wf, flg, (uint4*)x1);
        k_wprep<<<256, 256, 0, stream>>>(wf, W1s, W2s);
        k_ffn<<<(Nn + 31) / 32, 128, 0, stream>>>((const ushort*)x1, wf, W1s, W2s,
                                                  (float*)d_out);
    }
}

// Round 9
// 587.391 us; speedup vs baseline: 2.5009x; 1.1915x over previous
//
#include <hip/hip_runtime.h>
#include <hip/hip_bf16.h>

typedef unsigned int uint32;
typedef unsigned short ushort;
typedef __attribute__((ext_vector_type(8))) short short8;   // 8 bf16 (4 VGPRs)
typedef __attribute__((ext_vector_type(4))) float float4v;  // MFMA acc

// ---------------- problem constants ----------------
constexpr int Nn = 50000;
constexpr int Ee = 800000;
constexpr int EF = Ee + Nn;          // 850000, divisible by 16
constexpr int NT = EF / 16;          // 53125 MFMA tiles
constexpr int TE = Ee / 16;          // 50000
constexpr int SCAN_NB = 200;         // 200*256 = 51200 >= Nn

// ---------------- PLAN B (round-7) ws layout ----------------
constexpr long B_SC  = 0;
constexpr long B_XL  = 13600000;
constexpr long B_X1  = 26400000;
constexpr long B_LA  = 39200000;
constexpr long B_EIX = 42400000;
constexpr long B_CNT = 48800000;
constexpr long B_OFS = 49000000;
constexpr long B_CUR = 49200016;
constexpr long B_CSR = 49400016;
constexpr long B_WF  = 52800016;
constexpr long B_FLG = 53478416;

// ---------------- PLAN A ws layout (CSR-ordered edge data) ----------------
constexpr long A_EAP = 0;            // bf16 [EF*32]  54,400,000 (x1 aliases here after k_score2)
constexpr long A_SRC = 54400000;     // int  [EF]      3,400,000
constexpr long A_DST = 57800000;     // int  [EF]      3,400,000
constexpr long A_SCO = 61200000;     // bf16 [EF*8]   13,600,000 (bsum/bpre, Wls/Wrs, W1s/W2s alias)
constexpr long A_EIX = 74800000;     // int  [2*Ee]    6,400,000
constexpr long A_CNT = 81200000;
constexpr long A_OFS = 81400000;
constexpr long A_CUR = 81600016;
constexpr long A_WF  = 81800016;     // fp32 [169600]
constexpr long A_FLG = 82478416;
constexpr long NEED_A = 82478432;

// canonical weight float offsets
constexpr int WF_Wl = 0, WF_bl = 16384, WF_Wr = 16512, WF_br = 32896;
constexpr int WF_We = 33024, WF_att = 37120, WF_bias = 37248;
constexpr int WF_W1 = 37376, WF_b1 = 102912, WF_W2 = 103424, WF_b2 = 168960;
constexpr int WF_g1 = 169088, WF_be1 = 169216, WF_g2 = 169344, WF_be2 = 169472;
constexpr int WF_TOT = 169600;

static __device__ __forceinline__ float b2f(__hip_bfloat16 v) { return __bfloat162float(v); }
static __device__ __forceinline__ float2 up2(uint32 u) {
    union { uint32 i; float f; } a, b;
    a.i = (u & 0xFFFFu) << 16; b.i = u & 0xFFFF0000u;
    return make_float2(a.f, b.f);
}
static __device__ __forceinline__ float up1(ushort u) {
    union { uint32 i; float f; } a; a.i = ((uint32)u) << 16; return a.f;
}
static __device__ __forceinline__ ushort f2bu(float f) {
    __hip_bfloat16 h = __float2bfloat16(f); return *(ushort*)&h;
}
static __device__ __forceinline__ float san(float v) { return fminf(fmaxf(v, -1e4f), 1e4f); }

// ================= shared kernels =================
__global__ void k_sniff(const uint32* __restrict__ xu, const uint32* __restrict__ eu,
                        int* __restrict__ flg) {
    int lane = threadIdx.x;
    int xbf = 0, ebf = 0;
    #pragma unroll
    for (int j = 0; j < 8; j++) {
        uint32 ux = xu[lane * 8 + j];
        int ex = (ux >> 7) & 0xFF;
        xbf += (ex >= 100 && ex <= 135) ? 1 : 0;
        uint32 ue = eu[lane * 8 + j];
        int ee = (ue >> 7) & 0xFF;
        ebf += (ee >= 100 && ee <= 135) ? 1 : 0;
    }
    #pragma unroll
    for (int mk = 1; mk < 64; mk <<= 1) { xbf += __shfl_xor(xbf, mk); ebf += __shfl_xor(ebf, mk); }
    if (lane == 0) { flg[0] = (xbf > 256) ? 0 : 1; flg[1] = (ebf > 256) ? 0 : 1; }
}

__global__ void k_cvt(const int* __restrict__ raw, int* __restrict__ eix,
                      int* __restrict__ cnt) {
    __shared__ int is64;
    if (threadIdx.x == 0) {
        int z = 1;
        #pragma unroll
        for (int j = 1; j < 64; j += 2) z &= (raw[j] == 0);
        is64 = z;
    }
    __syncthreads();
    int i = blockIdx.x * 256 + threadIdx.x;
    if (i < 2 * Ee) {
        int v = is64 ? raw[2 * i] : raw[i];
        v = v < 0 ? 0 : (v >= Nn ? Nn - 1 : v);
        eix[i] = v;
        if (i >= Ee) atomicAdd(&cnt[v], 1);
    }
}

struct WSrc { const void* p[15]; };
__global__ void k_wcanon(WSrc s, const int* __restrict__ flagp, float* __restrict__ dst) {
    const int cum[16] = {0, 16384, 16512, 32896, 33024, 37120, 37248, 37376,
                         102912, 103424, 168960, 169088, 169216, 169344, 169472, 169600};
    int i = blockIdx.x * 256 + threadIdx.x;
    if (i >= WF_TOT) return;
    int isf32 = flagp[0];
    int seg = 0;
    #pragma unroll
    for (int j = 1; j < 16; j++) seg += (i >= cum[j]);
    int off = i - cum[seg];
    float v = isf32 ? ((const float*)s.p[seg])[off]
                    : b2f(((const __hip_bfloat16*)s.p[seg])[off]);
    dst[i] = v;
}

// ---- hierarchical scan (offs[n] = sum_{m<n}(cnt[m]+1), cursor=0) ----
__global__ void __launch_bounds__(256) k_scanA(const int* __restrict__ cnt,
                                               int* __restrict__ bsum) {
    int i = blockIdx.x * 256 + threadIdx.x;
    int v = (i < Nn) ? cnt[i] + 1 : 0;
    #pragma unroll
    for (int mk = 1; mk < 64; mk <<= 1) v += __shfl_xor(v, mk);
    __shared__ int wt[4];
    if ((threadIdx.x & 63) == 0) wt[threadIdx.x >> 6] = v;
    __syncthreads();
    if (threadIdx.x == 0) bsum[blockIdx.x] = wt[0] + wt[1] + wt[2] + wt[3];
}

__global__ void __launch_bounds__(256) k_scanB(const int* __restrict__ bsum,
                                               int* __restrict__ bpre) {
    int t = threadIdx.x;
    int lane = t & 63, wv = t >> 6;
    int orig = (t < SCAN_NB) ? bsum[t] : 0;
    int v = orig;
    #pragma unroll
    for (int off = 1; off < 64; off <<= 1) {
        int u = __shfl_up(v, off);
        if (lane >= off) v += u;
    }
    __shared__ int wt[4];
    if (lane == 63) wt[wv] = v;
    __syncthreads();
    int add = 0;
    for (int w = 0; w < wv; w++) add += wt[w];
    if (t < SCAN_NB) bpre[t] = v + add - orig;   // exclusive
}

__global__ void __launch_bounds__(256) k_scanC(const int* __restrict__ cnt,
                                               const int* __restrict__ bpre,
                                               int* __restrict__ offs,
                                               int* __restrict__ cursor) {
    int i = blockIdx.x * 256 + threadIdx.x;
    int lane = threadIdx.x & 63, wv = threadIdx.x >> 6;
    int v = (i < Nn) ? cnt[i] + 1 : 0;
    int inc = v;
    #pragma unroll
    for (int off = 1; off < 64; off <<= 1) {
        int u = __shfl_up(inc, off);
        if (lane >= off) inc += u;
    }
    __shared__ int wt[4];
    if (lane == 63) wt[wv] = inc;
    __syncthreads();
    int add = bpre[blockIdx.x];
    for (int w = 0; w < wv; w++) add += wt[w];
    int exc = add + inc - v;
    if (i < Nn) { offs[i] = exc; cursor[i] = 0; }
    if (i == Nn - 1) offs[Nn] = exc + v;
}

// legacy single-block scan (Plan B only)
__global__ void __launch_bounds__(1024) k_scan(const int* __restrict__ cnt,
                                               int* __restrict__ offs, int* __restrict__ cursor) {
    __shared__ int part[1024];
    int t = threadIdx.x;
    const int CH = (Nn + 1023) / 1024;
    int base = t * CH;
    int s = 0;
    for (int i = 0; i < CH; i++) { int n = base + i; if (n < Nn) s += cnt[n] + 1; }
    part[t] = s;
    __syncthreads();
    for (int off = 1; off < 1024; off <<= 1) {
        int v = (t >= off) ? part[t - off] : 0;
        __syncthreads();
        part[t] += v;
        __syncthreads();
    }
    int run = part[t] - s;
    for (int i = 0; i < CH; i++) {
        int n = base + i;
        if (n < Nn) { offs[n] = run; run += cnt[n] + 1; cursor[n] = 0; }
    }
    if (t == 1023) offs[Nn] = part[1023];
}

// W1/W2 -> MFMA frag order (for k_ffn)
__global__ void k_wprep(const float* __restrict__ wf,
                        ushort* __restrict__ W1s, ushort* __restrict__ W2s) {
    int i = blockIdx.x * 256 + threadIdx.x;
    if (i >= 65536) return;
    int j = i & 7, lane = (i >> 3) & 63, g = i >> 9;
    int c = lane & 15, q = lane >> 4;
    int kk = g & 3, ht = g >> 2;
    W1s[i] = f2bu(wf[WF_W1 + (kk * 32 + q * 8 + j) * 512 + ht * 16 + c]);
    int kk2 = g & 15, nt = g >> 4;
    W2s[i] = f2bu(wf[WF_W2 + (kk2 * 32 + q * 8 + j) * 128 + nt * 16 + c]);
}

// MFMA FFN + residual + LN2 -> fp32 out
__global__ void __launch_bounds__(128) k_ffn(const ushort* __restrict__ x1b,
                                             const float* __restrict__ wf,
                                             const ushort* __restrict__ W1s,
                                             const ushort* __restrict__ W2s,
                                             float* __restrict__ out) {
    __shared__ ushort hb[2][16 * 520];
    __shared__ ushort xsb[2][16 * 136];
    int wv = threadIdx.x >> 6;
    int lane = threadIdx.x & 63;
    int c = lane & 15, q = lane >> 4;
    long n0 = (long)blockIdx.x * 32 + wv * 16;
    if (n0 >= Nn) return;
    ushort* h = hb[wv];
    ushort* xs = xsb[wv];

    short8 B1[4];
    const uint4* x1row = (const uint4*)(x1b + (n0 + c) * 128);
    #pragma unroll
    for (int kk = 0; kk < 4; kk++) {
        union { uint4 u; short8 s; } cv; cv.u = x1row[kk * 4 + q]; B1[kk] = cv.s;
    }
    for (int i = lane; i < 256; i += 64) {
        int row = i >> 4, col = i & 15;
        *(uint4*)(xs + row * 136 + col * 8) = *(const uint4*)(x1b + (n0 + row) * 128 + col * 8);
    }
    const uint4* W1v = (const uint4*)W1s;
    for (int ht = 0; ht < 32; ht++) {
        float4v acc = (float4v){0.f, 0.f, 0.f, 0.f};
        #pragma unroll
        for (int kk = 0; kk < 4; kk++) {
            union { uint4 u; short8 s; } a; a.u = W1v[(ht * 4 + kk) * 64 + lane];
            acc = __builtin_amdgcn_mfma_f32_16x16x32_bf16(a.s, B1[kk], acc, 0, 0, 0);
        }
        float4 bb = *(const float4*)(wf + WF_b1 + ht * 16 + q * 4);
        uint2 pk;
        pk.x = (uint32)f2bu(fmaxf(acc[0] + bb.x, 0.f)) | ((uint32)f2bu(fmaxf(acc[1] + bb.y, 0.f)) << 16);
        pk.y = (uint32)f2bu(fmaxf(acc[2] + bb.z, 0.f)) | ((uint32)f2bu(fmaxf(acc[3] + bb.w, 0.f)) << 16);
        *(uint2*)(h + c * 520 + ht * 16 + q * 4) = pk;
    }
    const uint4* W2v = (const uint4*)W2s;
    float4v acc2[8];
    #pragma unroll
    for (int nt = 0; nt < 8; nt++) acc2[nt] = (float4v){0.f, 0.f, 0.f, 0.f};
    for (int kk2 = 0; kk2 < 16; kk2++) {
        union { uint4 u; short8 s; } a2;
        a2.u = *(const uint4*)(h + c * 520 + kk2 * 32 + q * 8);
        #pragma unroll
        for (int nt = 0; nt < 8; nt++) {
            union { uint4 u; short8 s; } b2f_;
            b2f_.u = W2v[(nt * 16 + kk2) * 64 + lane];
            acc2[nt] = __builtin_amdgcn_mfma_f32_16x16x32_bf16(a2.s, b2f_.s, acc2[nt], 0, 0, 0);
        }
    }
    float b2v[8], g2v[8], be2v[8];
    #pragma unroll
    for (int nt = 0; nt < 8; nt++) {
        b2v[nt]  = wf[WF_b2  + nt * 16 + c];
        g2v[nt]  = wf[WF_g2  + nt * 16 + c];
        be2v[nt] = wf[WF_be2 + nt * 16 + c];
    }
    float yv[8][4];
    float sum[4] = {0.f, 0.f, 0.f, 0.f}, sq[4] = {0.f, 0.f, 0.f, 0.f};
    #pragma unroll
    for (int nt = 0; nt < 8; nt++) {
        #pragma unroll
        for (int r = 0; r < 4; r++) {
            float v = acc2[nt][r] + b2v[nt] + up1(xs[(q * 4 + r) * 136 + nt * 16 + c]);
            yv[nt][r] = v;
            sum[r] += v; sq[r] += v * v;
        }
    }
    #pragma unroll
    for (int mask = 1; mask < 16; mask <<= 1) {
        #pragma unroll
        for (int r = 0; r < 4; r++) {
            sum[r] += __shfl_xor(sum[r], mask);
            sq[r]  += __shfl_xor(sq[r], mask);
        }
    }
    #pragma unroll
    for (int r = 0; r < 4; r++) {
        float mean = sum[r] * (1.0f / 128.0f);
        float var = sq[r] * (1.0f / 128.0f) - mean * mean;
        float rstd = rsqrtf(var + 1e-5f);
        long nodeb = (n0 + q * 4 + r) * 128;
        #pragma unroll
        for (int nt = 0; nt < 8; nt++) {
            out[nodeb + nt * 16 + c] = san((yv[nt][r] - mean) * rstd * g2v[nt] + be2v[nt]);
        }
    }
}

// ================= PLAN A kernels =================
__global__ void k_wprepL(const float* __restrict__ wf,
                         ushort* __restrict__ Wls, ushort* __restrict__ Wrs) {
    int i = blockIdx.x * 256 + threadIdx.x;
    if (i >= 16384) return;
    int j = i & 7, lane = (i >> 3) & 63, g = i >> 9;
    int c = lane & 15, q = lane >> 4;
    int kk = g & 3, ot = g >> 2;
    int kin = kk * 32 + q * 8 + j, outd = ot * 16 + c;
    Wls[i] = f2bu(wf[WF_Wl + kin * 128 + outd]);
    Wrs[i] = f2bu(wf[WF_Wr + kin * 128 + outd]);
}

__global__ void __launch_bounds__(256) k_linlr(const void* __restrict__ x,
                                               const float* __restrict__ wf,
                                               const ushort* __restrict__ Wls,
                                               const ushort* __restrict__ Wrs,
                                               const int* __restrict__ flagp,
                                               ushort* __restrict__ xl,
                                               ushort* __restrict__ xr) {
    int isf32 = flagp[0];
    int wv = threadIdx.x >> 6, lane = threadIdx.x & 63;
    int c = lane & 15, q = lane >> 4;
    long n0 = ((long)blockIdx.x * 4 + wv) * 16;
    if (n0 >= Nn) return;
    short8 B[4];
    if (isf32) {
        const float* xrow = (const float*)x + (n0 + c) * 128;
        #pragma unroll
        for (int kk = 0; kk < 4; kk++)
            #pragma unroll
            for (int j = 0; j < 8; j++)
                B[kk][j] = (short)f2bu(xrow[kk * 32 + q * 8 + j]);
    } else {
        const uint4* xrow = (const uint4*)((const ushort*)x + (n0 + c) * 128);
        #pragma unroll
        for (int kk = 0; kk < 4; kk++) {
            union { uint4 u; short8 s; } cv; cv.u = xrow[kk * 4 + q]; B[kk] = cv.s;
        }
    }
    const uint4* Al = (const uint4*)Wls;
    const uint4* Ar = (const uint4*)Wrs;
    #pragma unroll
    for (int ot = 0; ot < 8; ot++) {
        float4v aL = (float4v){0.f, 0.f, 0.f, 0.f};
        float4v aR = (float4v){0.f, 0.f, 0.f, 0.f};
        #pragma unroll
        for (int kk = 0; kk < 4; kk++) {
            union { uint4 u; short8 s; } a, b;
            a.u = Al[(ot * 4 + kk) * 64 + lane];
            b.u = Ar[(ot * 4 + kk) * 64 + lane];
            aL = __builtin_amdgcn_mfma_f32_16x16x32_bf16(a.s, B[kk], aL, 0, 0, 0);
            aR = __builtin_amdgcn_mfma_f32_16x16x32_bf16(b.s, B[kk], aR, 0, 0, 0);
        }
        float4 bl4 = *(const float4*)(wf + WF_bl + ot * 16 + q * 4);
        float4 br4 = *(const float4*)(wf + WF_br + ot * 16 + q * 4);
        uint2 pl, pr;
        pl.x = (uint32)f2bu(san(aL[0] + bl4.x)) | ((uint32)f2bu(san(aL[1] + bl4.y)) << 16);
        pl.y = (uint32)f2bu(san(aL[2] + bl4.z)) | ((uint32)f2bu(san(aL[3] + bl4.w)) << 16);
        pr.x = (uint32)f2bu(san(aR[0] + br4.x)) | ((uint32)f2bu(san(aR[1] + br4.y)) << 16);
        pr.y = (uint32)f2bu(san(aR[2] + br4.z)) | ((uint32)f2bu(san(aR[3] + br4.w)) << 16);
        *(uint2*)(xl + (n0 + c) * 128 + ot * 16 + q * 4) = pl;
        *(uint2*)(xr + (n0 + c) * 128 + ot * 16 + q * 4) = pr;
    }
}

__global__ void __launch_bounds__(256) k_fill2(const int* __restrict__ eix,
                                               const void* __restrict__ eattr,
                                               const int* __restrict__ flagp,
                                               int* __restrict__ cur,
                                               const int* __restrict__ offs,
                                               ushort* __restrict__ eap,
                                               int* __restrict__ srcp,
                                               int* __restrict__ dstp) {
    int isf32 = flagp[1];
    int gid = blockIdx.x * 256 + threadIdx.x;
    int e = gid >> 2, sub = gid & 3;
    int lane = threadIdx.x & 63;
    int d = eix[Ee + e];
    int p = 0;
    if (sub == 0) p = offs[d] + atomicAdd(&cur[d], 1);
    p = __shfl(p, lane & ~3);
    if (sub == 0) { srcp[p] = eix[e]; dstp[p] = d; }
    uint4 o;
    if (isf32) {
        const float* r = (const float*)eattr + (long)e * 32 + sub * 8;
        o.x = (uint32)f2bu(r[0]) | ((uint32)f2bu(r[1]) << 16);
        o.y = (uint32)f2bu(r[2]) | ((uint32)f2bu(r[3]) << 16);
        o.z = (uint32)f2bu(r[4]) | ((uint32)f2bu(r[5]) << 16);
        o.w = (uint32)f2bu(r[6]) | ((uint32)f2bu(r[7]) << 16);
    } else {
        o = ((const uint4*)eattr)[(long)e * 4 + sub];
    }
    *(uint4*)(eap + (long)p * 32 + sub * 8) = o;
}

__global__ void __launch_bounds__(256) k_self(const int* __restrict__ offs,
                                              ushort* __restrict__ eap,
                                              int* __restrict__ srcp,
                                              int* __restrict__ dstp) {
    int lane = threadIdx.x & 63;
    int n = (blockIdx.x * 256 + threadIdx.x) >> 6;
    if (n >= Nn) return;
    int off = offs[n], deg1 = offs[n + 1] - 1 - off;
    int k = lane & 31, half = lane >> 5;
    float acc = 0.f;
    for (int i = half; i < deg1; i += 2)
        acc += up1(eap[(long)(off + i) * 32 + k]);
    acc += __shfl_xor(acc, 32);
    float inv = 1.0f / fmaxf((float)deg1, 1.0f);
    long ps = off + deg1;
    if (lane < 32) eap[ps * 32 + k] = f2bu(san(acc * inv));
    if (lane == 0) { srcp[ps] = n; dstp[ps] = n; }
}

__global__ void __launch_bounds__(256) k_score2(const ushort* __restrict__ eap,
                                                const int* __restrict__ srcp,
                                                const int* __restrict__ dstp,
                                                const float* __restrict__ wf,
                                                const uint32* __restrict__ xlu,
                                                const uint32* __restrict__ xru,
                                                uint4* __restrict__ score16) {
    int t256 = threadIdx.x;
    int lane = t256 & 63;
    int c0 = lane & 15, q = lane >> 4;
    int w = (blockIdx.x * 256 + t256) >> 6;
    int nw = (gridDim.x * 256) >> 6;

    short8 A[8];
    float att[8][4];
    #pragma unroll
    for (int t = 0; t < 8; t++) {
        #pragma unroll
        for (int j = 0; j < 8; j++)
            A[t][j] = (short)f2bu(wf[WF_We + (q * 8 + j) * 128 + t * 16 + c0]);
        #pragma unroll
        for (int r = 0; r < 4; r++)
            att[t][r] = wf[WF_att + t * 16 + q * 4 + r];
    }

    for (int T = w; T < NT; T += nw) {
        int slot = T * 16 + c0;
        int srcn = srcp[slot], dstn = dstp[slot];
        union { uint4 u; short8 s; } cv;
        cv.u = *(const uint4*)(eap + (long)slot * 32 + q * 8);
        short8 B = cv.s;

        float4v acc[8];
        #pragma unroll
        for (int t = 0; t < 8; t++) {
            acc[t] = (float4v){0.f, 0.f, 0.f, 0.f};
            acc[t] = __builtin_amdgcn_mfma_f32_16x16x32_bf16(A[t], B, acc[t], 0, 0, 0);
        }
        uint2 xg[8], rg[8];
        #pragma unroll
        for (int t = 0; t < 8; t++) {
            xg[t] = ((const uint2*)xlu)[(long)srcn * 32 + t * 4 + q];
            rg[t] = ((const uint2*)xru)[(long)dstn * 32 + t * 4 + q];
        }
        float st[8];
        #pragma unroll
        for (int t = 0; t < 8; t++) {
            float2 xa = up2(xg[t].x), xb2 = up2(xg[t].y);
            float2 ra = up2(rg[t].x), rb = up2(rg[t].y);
            float v0 = acc[t][0] + xa.x + ra.x;
            float v1 = acc[t][1] + xa.y + ra.y;
            float v2 = acc[t][2] + xb2.x + rb.x;
            float v3 = acc[t][3] + xb2.y + rb.y;
            v0 = v0 > 0.f ? v0 : 0.2f * v0;
            v1 = v1 > 0.f ? v1 : 0.2f * v1;
            v2 = v2 > 0.f ? v2 : 0.2f * v2;
            v3 = v3 > 0.f ? v3 : 0.2f * v3;
            st[t] = att[t][0] * v0 + att[t][1] * v1 + att[t][2] * v2 + att[t][3] * v3;
        }
        #pragma unroll
        for (int t = 0; t < 8; t++) {
            st[t] += __shfl_xor(st[t], 16);
            st[t] += __shfl_xor(st[t], 32);
        }
        if (q == 0) {
            uint4 o;
            o.x = (uint32)f2bu(san(st[0])) | ((uint32)f2bu(san(st[1])) << 16);
            o.y = (uint32)f2bu(san(st[2])) | ((uint32)f2bu(san(st[3])) << 16);
            o.z = (uint32)f2bu(san(st[4])) | ((uint32)f2bu(san(st[5])) << 16);
            o.w = (uint32)f2bu(san(st[6])) | ((uint32)f2bu(san(st[7])) << 16);
            score16[slot] = o;
        }
    }
}

__global__ void __launch_bounds__(256) k_agg2(const ushort* __restrict__ scu,
                                              const int* __restrict__ offs,
                                              const int* __restrict__ srcp,
                                              const uint32* __restrict__ xlu,
                                              const void* __restrict__ x,
                                              const float* __restrict__ wf,
                                              const int* __restrict__ flagp,
                                              uint4* __restrict__ x1) {
    int isf32 = flagp[0];
    int lane = threadIdx.x & 63;
    int n = (blockIdx.x * 256 + threadIdx.x) >> 6;
    int off = offs[n], deg = offs[n + 1] - off;

    float m[8], s[8];
    #pragma unroll
    for (int h = 0; h < 8; h++) { m[h] = -1e30f; s[h] = 0.f; }
    for (int i = lane; i < deg; i += 64) {
        uint4 qv = *((const uint4*)(scu + (long)(off + i) * 8));
        float2 p0 = up2(qv.x), p1 = up2(qv.y), p2 = up2(qv.z), p3 = up2(qv.w);
        float sc[8] = {p0.x, p0.y, p1.x, p1.y, p2.x, p2.y, p3.x, p3.y};
        #pragma unroll
        for (int h = 0; h < 8; h++) {
            float mn = fmaxf(m[h], sc[h]);
            s[h] = s[h] * __expf(m[h] - mn) + __expf(sc[h] - mn);
            m[h] = mn;
        }
    }
    #pragma unroll
    for (int mask = 1; mask < 64; mask <<= 1) {
        #pragma unroll
        for (int h = 0; h < 8; h++) {
            float m2 = __shfl_xor(m[h], mask);
            float s2 = __shfl_xor(s[h], mask);
            float mn = fmaxf(m[h], m2);
            s[h] = s[h] * __expf(m[h] - mn) + s2 * __expf(m2 - mn);
            m[h] = mn;
        }
    }
    int g = lane >> 3, hh = lane & 7;
    float mh = m[0], sh = s[0];
    #pragma unroll
    for (int j = 1; j < 8; j++) { if (hh == j) { mh = m[j]; sh = s[j]; } }
    float inv = 1.0f / sh;

    float acc[16];
    #pragma unroll
    for (int j = 0; j < 16; j++) acc[j] = 0.f;
    for (int i = g; i < deg; i += 8) {
        long sl = off + i;
        float alpha = __expf(up1(scu[sl * 8 + hh]) - mh) * inv;
        int srcn = srcp[sl];
        uint4 a = ((const uint4*)xlu)[(long)srcn * 16 + hh * 2];
        uint4 b = ((const uint4*)xlu)[(long)srcn * 16 + hh * 2 + 1];
        float2 v0 = up2(a.x), v1 = up2(a.y), v2 = up2(a.z), v3 = up2(a.w);
        float2 v4 = up2(b.x), v5 = up2(b.y), v6 = up2(b.z), v7 = up2(b.w);
        acc[0] += alpha * v0.x;  acc[1] += alpha * v0.y;
        acc[2] += alpha * v1.x;  acc[3] += alpha * v1.y;
        acc[4] += alpha * v2.x;  acc[5] += alpha * v2.y;
        acc[6] += alpha * v3.x;  acc[7] += alpha * v3.y;
        acc[8] += alpha * v4.x;  acc[9] += alpha * v4.y;
        acc[10] += alpha * v5.x; acc[11] += alpha * v5.y;
        acc[12] += alpha * v6.x; acc[13] += alpha * v6.y;
        acc[14] += alpha * v7.x; acc[15] += alpha * v7.y;
    }
    #pragma unroll
    for (int mask = 8; mask < 64; mask <<= 1) {
        #pragma unroll
        for (int j = 0; j < 16; j++) acc[j] += __shfl_xor(acc[j], mask);
    }
    float y[16];
    if (g == 0) {
        int d0 = hh * 16;
        if (isf32) {
            const float4* xf = (const float4*)x;
            #pragma unroll
            for (int c = 0; c < 4; c++) {
                float4 xv = xf[(long)n * 32 + hh * 4 + c];
                y[c*4+0] = acc[c*4+0] + xv.x + wf[WF_bias + d0 + c*4+0];
                y[c*4+1] = acc[c*4+1] + xv.y + wf[WF_bias + d0 + c*4+1];
                y[c*4+2] = acc[c*4+2] + xv.z + wf[WF_bias + d0 + c*4+2];
                y[c*4+3] = acc[c*4+3] + xv.w + wf[WF_bias + d0 + c*4+3];
            }
        } else {
            const uint4* xb = (const uint4*)x;
            uint4 a = xb[(long)n * 16 + hh * 2];
            uint4 b = xb[(long)n * 16 + hh * 2 + 1];
            uint32 ww[8] = {a.x, a.y, a.z, a.w, b.x, b.y, b.z, b.w};
            #pragma unroll
            for (int c = 0; c < 8; c++) {
                float2 v = up2(ww[c]);
                y[c*2+0] = acc[c*2+0] + v.x + wf[WF_bias + d0 + c*2+0];
                y[c*2+1] = acc[c*2+1] + v.y + wf[WF_bias + d0 + c*2+1];
            }
        }
    }
    float sum = 0.f, sq = 0.f;
    if (g == 0) {
        #pragma unroll
        for (int j = 0; j < 16; j++) { sum += y[j]; sq += y[j] * y[j]; }
    }
    #pragma unroll
    for (int mask = 1; mask < 8; mask <<= 1) { sum += __shfl_xor(sum, mask); sq += __shfl_xor(sq, mask); }
    if (g == 0) {
        int d0 = hh * 16;
        float mean = sum * (1.0f / 128.0f);
        float var = sq * (1.0f / 128.0f) - mean * mean;
        float rstd = rsqrtf(var + 1e-5f);
        uint32 o[8];
        #pragma unroll
        for (int c = 0; c < 8; c++) {
            float o0 = san((y[c*2+0] - mean) * rstd * wf[WF_g1 + d0 + c*2+0] + wf[WF_be1 + d0 + c*2+0]);
            float o1 = san((y[c*2+1] - mean) * rstd * wf[WF_g1 + d0 + c*2+1] + wf[WF_be1 + d0 + c*2+1]);
            o[c] = (uint32)f2bu(o0) | ((uint32)f2bu(o1) << 16);
        }
        x1[(long)n * 16 + hh * 2]     = make_uint4(o[0], o[1], o[2], o[3]);
        x1[(long)n * 16 + hh * 2 + 1] = make_uint4(o[4], o[5], o[6], o[7]);
    }
}

// ================= PLAN B (round-7) kernels =================
__global__ void k_fill(const int* __restrict__ eix, int* __restrict__ cursor,
                       const int* __restrict__ offs, int* __restrict__ csr) {
    int e = blockIdx.x * 256 + threadIdx.x;
    if (e >= EF) return;
    int d = (e < Ee) ? eix[Ee + e] : (e - Ee);
    int p = atomicAdd(&cursor[d], 1);
    csr[offs[d] + p] = e;
}

__global__ void __launch_bounds__(256) k_loopattr(const void* __restrict__ eattr,
                                                  const int* __restrict__ csr,
                                                  const int* __restrict__ offs,
                                                  const int* __restrict__ flagp,
                                                  __hip_bfloat16* __restrict__ la) {
    int isf32 = flagp[1];
    int lane = threadIdx.x & 63;
    int n = (blockIdx.x * 256 + threadIdx.x) >> 6;
    if (n >= Nn) return;
    int off = offs[n], deg = offs[n + 1] - off;
    int k = lane & 31, half = lane >> 5;
    const float* ef = (const float*)eattr;
    const __hip_bfloat16* eb = (const __hip_bfloat16*)eattr;
    float acc = 0.f;
    for (int i = half; i < deg; i += 2) {
        int e = csr[off + i];
        if (e < Ee) acc += isf32 ? ef[(long)e * 32 + k] : b2f(eb[(long)e * 32 + k]);
    }
    acc += __shfl_xor(acc, 32);
    float inv = 1.0f / fmaxf((float)(deg - 1), 1.0f);
    if (lane < 32) la[(long)n * 32 + k] = __float2bfloat16(san(acc * inv));
}

__global__ void __launch_bounds__(256) k_lin(const void* __restrict__ x,
                                             const float* __restrict__ Wf,
                                             const float* __restrict__ bf_,
                                             const int* __restrict__ flagp,
                                             __hip_bfloat16* __restrict__ out) {
    __shared__ ushort Wlds[128][130];
    __shared__ float xrow[2][128];
    int isf32 = flagp[0];
    int t = threadIdx.x, col = t & 127, sub = t >> 7;
    for (int i = t; i < 16384; i += 256) Wlds[i >> 7][i & 127] = f2bu(Wf[i]);
    float bias = bf_[col];
    const float* xf = (const float*)x;
    const __hip_bfloat16* xb = (const __hip_bfloat16*)x;
    int rpb = (Nn + gridDim.x - 1) / gridDim.x;
    int r0 = blockIdx.x * rpb, r1 = min(r0 + rpb, Nn);
    __syncthreads();
    for (int r = r0; r < r1; r += 2) {
        int rr = r + sub;
        if (rr < r1) xrow[sub][col] = isf32 ? xf[(long)rr * 128 + col]
                                            : b2f(xb[(long)rr * 128 + col]);
        __syncthreads();
        float acc = bias;
        #pragma unroll 16
        for (int k = 0; k < 128; k++) {
            union { uint32 i; float f; } u; u.i = ((uint32)Wlds[k][col]) << 16;
            acc += xrow[sub][k] * u.f;
        }
        if (rr < r1) out[(long)rr * 128 + col] = __float2bfloat16(san(acc));
        __syncthreads();
    }
}

__global__ void __launch_bounds__(256) k_score(const void* __restrict__ eattr,
                                               const int* __restrict__ eix,
                                               const uint32* __restrict__ la_u,
                                               const float* __restrict__ wf,
                                               const int* __restrict__ flagp,
                                               const uint32* __restrict__ xlu,
                                               const uint32* __restrict__ xru,
                                               uint4* __restrict__ score16) {
    int isf32 = flagp[1];
    int t256 = threadIdx.x;
    int lane = t256 & 63;
    int c0 = lane & 15, q = lane >> 4;
    int w = (blockIdx.x * 256 + t256) >> 6;
    int nw = (gridDim.x * 256) >> 6;
    short8 A[8];
    float att[8][4];
    #pragma unroll
    for (int t = 0; t < 8; t++) {
        #pragma unroll
        for (int j = 0; j < 8; j++)
            A[t][j] = (short)f2bu(wf[WF_We + (q * 8 + j) * 128 + t * 16 + c0]);
        #pragma unroll
        for (int r = 0; r < 4; r++)
            att[t][r] = wf[WF_att + t * 16 + q * 4 + r];
    }
    const float* ef = (const float*)eattr;
    const uint4* eb4 = (const uint4*)eattr;
    for (int T = w; T < NT; T += nw) {
        int row = T * 16 + c0;
        int srcn, dstn;
        short8 B;
        if (T < TE) {
            srcn = eix[row]; dstn = eix[Ee + row];
            if (isf32) {
                const float* p = ef + (long)row * 32 + q * 8;
                #pragma unroll
                for (int j = 0; j < 8; j++) B[j] = (short)f2bu(p[j]);
            } else {
                union { uint4 u; short8 s; } cv;
                cv.u = eb4[(long)row * 4 + q];
                B = cv.s;
            }
        } else {
            int n = row - Ee;
            srcn = n; dstn = n;
            union { uint4 u; short8 s; } cv;
            cv.u = ((const uint4*)la_u)[(long)n * 4 + q];
            B = cv.s;
        }
        float4v acc[8];
        #pragma unroll
        for (int t = 0; t < 8; t++) {
            acc[t] = (float4v){0.f, 0.f, 0.f, 0.f};
            acc[t] = __builtin_amdgcn_mfma_f32_16x16x32_bf16(A[t], B, acc[t], 0, 0, 0);
        }
        uint2 xg[8], rg[8];
        #pragma unroll
        for (int t = 0; t < 8; t++) {
            xg[t] = ((const uint2*)xlu)[(long)srcn * 32 + t * 4 + q];
            rg[t] = ((const uint2*)xru)[(long)dstn * 32 + t * 4 + q];
        }
        float st[8];
        #pragma unroll
        for (int t = 0; t < 8; t++) {
            float2 xa = up2(xg[t].x), xb2 = up2(xg[t].y);
            float2 ra = up2(rg[t].x), rb = up2(rg[t].y);
            float v0 = acc[t][0] + xa.x + ra.x;
            float v1 = acc[t][1] + xa.y + ra.y;
            float v2 = acc[t][2] + xb2.x + rb.x;
            float v3 = acc[t][3] + xb2.y + rb.y;
            v0 = v0 > 0.f ? v0 : 0.2f * v0;
            v1 = v1 > 0.f ? v1 : 0.2f * v1;
            v2 = v2 > 0.f ? v2 : 0.2f * v2;
            v3 = v3 > 0.f ? v3 : 0.2f * v3;
            st[t] = att[t][0] * v0 + att[t][1] * v1 + att[t][2] * v2 + att[t][3] * v3;
        }
        #pragma unroll
        for (int t = 0; t < 8; t++) {
            st[t] += __shfl_xor(st[t], 16);
            st[t] += __shfl_xor(st[t], 32);
        }
        if (q == 0) {
            uint4 o;
            o.x = (uint32)f2bu(san(st[0])) | ((uint32)f2bu(san(st[1])) << 16);
            o.y = (uint32)f2bu(san(st[2])) | ((uint32)f2bu(san(st[3])) << 16);
            o.z = (uint32)f2bu(san(st[4])) | ((uint32)f2bu(san(st[5])) << 16);
            o.w = (uint32)f2bu(san(st[6])) | ((uint32)f2bu(san(st[7])) << 16);
            score16[row] = o;
        }
    }
}

__global__ void __launch_bounds__(256) k_agg(const ushort* __restrict__ scu,
                                             const int* __restrict__ csr, const int* __restrict__ offs,
                                             const int* __restrict__ eix,
                                             const uint32* __restrict__ xlu,
                                             const void* __restrict__ x,
                                             const float* __restrict__ wf,
                                             const int* __restrict__ flagp,
                                             uint4* __restrict__ x1) {
    int isf32 = flagp[0];
    int lane = threadIdx.x & 63;
    int n = (blockIdx.x * 256 + threadIdx.x) >> 6;
    int off = offs[n], deg = offs[n + 1] - off;
    float m[8], s[8];
    #pragma unroll
    for (int h = 0; h < 8; h++) { m[h] = -1e30f; s[h] = 0.f; }
    for (int i = lane; i < deg; i += 64) {
        int e = csr[off + i];
        uint4 qv = *((const uint4*)(scu + (long)e * 8));
        float2 p0 = up2(qv.x), p1 = up2(qv.y), p2 = up2(qv.z), p3 = up2(qv.w);
        float sc[8] = {p0.x, p0.y, p1.x, p1.y, p2.x, p2.y, p3.x, p3.y};
        #pragma unroll
        for (int h = 0; h < 8; h++) {
            float mn = fmaxf(m[h], sc[h]);
            s[h] = s[h] * __expf(m[h] - mn) + __expf(sc[h] - mn);
            m[h] = mn;
        }
    }
    #pragma unroll
    for (int mask = 1; mask < 64; mask <<= 1) {
        #pragma unroll
        for (int h = 0; h < 8; h++) {
            float m2 = __shfl_xor(m[h], mask);
            float s2 = __shfl_xor(s[h], mask);
            float mn = fmaxf(m[h], m2);
            s[h] = s[h] * __expf(m[h] - mn) + s2 * __expf(m2 - mn);
            m[h] = mn;
        }
    }
    int g = lane >> 3, hh = lane & 7;
    float mh = m[0], sh = s[0];
    #pragma unroll
    for (int j = 1; j < 8; j++) { if (hh == j) { mh = m[j]; sh = s[j]; } }
    float inv = 1.0f / sh;
    float acc[16];
    #pragma unroll
    for (int j = 0; j < 16; j++) acc[j] = 0.f;
    for (int i = g; i < deg; i += 8) {
        int e = csr[off + i];
        float alpha = __expf(up1(scu[(long)e * 8 + hh]) - mh) * inv;
        int srcn = (e < Ee) ? eix[e] : (e - Ee);
        uint4 a = ((const uint4*)xlu)[(long)srcn * 16 + hh * 2];
        uint4 b = ((const uint4*)xlu)[(long)srcn * 16 + hh * 2 + 1];
        float2 v0 = up2(a.x), v1 = up2(a.y), v2 = up2(a.z), v3 = up2(a.w);
        float2 v4 = up2(b.x), v5 = up2(b.y), v6 = up2(b.z), v7 = up2(b.w);
        acc[0] += alpha * v0.x;  acc[1] += alpha * v0.y;
        acc[2] += alpha * v1.x;  acc[3] += alpha * v1.y;
        acc[4] += alpha * v2.x;  acc[5] += alpha * v2.y;
        acc[6] += alpha * v3.x;  acc[7] += alpha * v3.y;
        acc[8] += alpha * v4.x;  acc[9] += alpha * v4.y;
        acc[10] += alpha * v5.x; acc[11] += alpha * v5.y;
        acc[12] += alpha * v6.x; acc[13] += alpha * v6.y;
        acc[14] += alpha * v7.x; acc[15] += alpha * v7.y;
    }
    #pragma unroll
    for (int mask = 8; mask < 64; mask <<= 1) {
        #pragma unroll
        for (int j = 0; j < 16; j++) acc[j] += __shfl_xor(acc[j], mask);
    }
    float y[16];
    if (g == 0) {
        int d0 = hh * 16;
        if (isf32) {
            const float4* xf = (const float4*)x;
            #pragma unroll
            for (int c = 0; c < 4; c++) {
                float4 xv = xf[(long)n * 32 + hh * 4 + c];
                y[c*4+0] = acc[c*4+0] + xv.x + wf[WF_bias + d0 + c*4+0];
                y[c*4+1] = acc[c*4+1] + xv.y + wf[WF_bias + d0 + c*4+1];
                y[c*4+2] = acc[c*4+2] + xv.z + wf[WF_bias + d0 + c*4+2];
                y[c*4+3] = acc[c*4+3] + xv.w + wf[WF_bias + d0 + c*4+3];
            }
        } else {
            const uint4* xb = (const uint4*)x;
            uint4 a = xb[(long)n * 16 + hh * 2];
            uint4 b = xb[(long)n * 16 + hh * 2 + 1];
            uint32 ww[8] = {a.x, a.y, a.z, a.w, b.x, b.y, b.z, b.w};
            #pragma unroll
            for (int c = 0; c < 8; c++) {
                float2 v = up2(ww[c]);
                y[c*2+0] = acc[c*2+0] + v.x + wf[WF_bias + d0 + c*2+0];
                y[c*2+1] = acc[c*2+1] + v.y + wf[WF_bias + d0 + c*2+1];
            }
        }
    }
    float sum = 0.f, sq = 0.f;
    if (g == 0) {
        #pragma unroll
        for (int j = 0; j < 16; j++) { sum += y[j]; sq += y[j] * y[j]; }
    }
    #pragma unroll
    for (int mask = 1; mask < 8; mask <<= 1) { sum += __shfl_xor(sum, mask); sq += __shfl_xor(sq, mask); }
    if (g == 0) {
        int d0 = hh * 16;
        float mean = sum * (1.0f / 128.0f);
        float var = sq * (1.0f / 128.0f) - mean * mean;
        float rstd = rsqrtf(var + 1e-5f);
        uint32 o[8];
        #pragma unroll
        for (int c = 0; c < 8; c++) {
            float o0 = san((y[c*2+0] - mean) * rstd * wf[WF_g1 + d0 + c*2+0] + wf[WF_be1 + d0 + c*2+0]);
            float o1 = san((y[c*2+1] - mean) * rstd * wf[WF_g1 + d0 + c*2+1] + wf[WF_be1 + d0 + c*2+1]);
            o[c] = (uint32)f2bu(o0) | ((uint32)f2bu(o1) << 16);
        }
        x1[(long)n * 16 + hh * 2]     = make_uint4(o[0], o[1], o[2], o[3]);
        x1[(long)n * 16 + hh * 2 + 1] = make_uint4(o[4], o[5], o[6], o[7]);
    }
}

// ---------------- launch ----------------
extern "C" void kernel_launch(void* const* d_in, const int* in_sizes, int n_in,
                              void* d_out, int out_size, void* d_ws, size_t ws_size,
                              hipStream_t stream) {
    const void* x     = d_in[0];
    const int*  eraw  = (const int*)d_in[1];
    const void* eattr = d_in[2];
    char* wsb = (char*)d_ws;
    WSrc wsrc;
    for (int i = 0; i < 15; i++) wsrc.p[i] = d_in[3 + i];

    if (ws_size >= (size_t)NEED_A) {
        // ---- PLAN A: CSR-ordered edge pipeline ----
        ushort* eap = (ushort*)(wsb + A_EAP);
        int*   srcp = (int*)(wsb + A_SRC);
        int*   dstp = (int*)(wsb + A_DST);
        ushort* sc  = (ushort*)(wsb + A_SCO);
        int*   bsum = (int*)(wsb + A_SCO);                // scan scratch (dead region)
        int*   bpre = (int*)(wsb + A_SCO + 4096);
        ushort* Wls = (ushort*)(wsb + A_SCO);
        ushort* Wrs = (ushort*)(wsb + A_SCO + 32768);
        ushort* W1s = (ushort*)(wsb + A_SCO);
        ushort* W2s = (ushort*)(wsb + A_SCO + 131072);
        int*   eix  = (int*)(wsb + A_EIX);
        int*   cnt  = (int*)(wsb + A_CNT);
        int*   offs = (int*)(wsb + A_OFS);
        int*   cur  = (int*)(wsb + A_CUR);
        float* wf   = (float*)(wsb + A_WF);
        int*   flg  = (int*)(wsb + A_FLG);
        ushort* x1  = (ushort*)(wsb + A_EAP);             // alias: eap dead after k_score2
        ushort* xl  = (ushort*)d_out;
        ushort* xr  = (ushort*)d_out + (long)Nn * 128;

        hipMemsetAsync(cnt, 0, Nn * sizeof(int), stream);
        k_sniff<<<1, 64, 0, stream>>>((const uint32*)x, (const uint32*)eattr, flg);
        k_cvt<<<(2 * Ee + 255) / 256, 256, 0, stream>>>(eraw, eix, cnt);
        k_wcanon<<<(WF_TOT + 255) / 256, 256, 0, stream>>>(wsrc, flg, wf);
        k_scanA<<<SCAN_NB, 256, 0, stream>>>(cnt, bsum);
        k_scanB<<<1, 256, 0, stream>>>(bsum, bpre);
        k_scanC<<<SCAN_NB, 256, 0, stream>>>(cnt, bpre, offs, cur);
        k_wprepL<<<64, 256, 0, stream>>>(wf, Wls, Wrs);
        k_linlr<<<(Nn / 16 + 3) / 4, 256, 0, stream>>>(x, wf, Wls, Wrs, flg, xl, xr);
        k_fill2<<<Ee * 4 / 256, 256, 0, stream>>>(eix, eattr, flg, cur, offs, eap, srcp, dstp);
        k_self<<<(Nn + 3) / 4, 256, 0, stream>>>(offs, eap, srcp, dstp);
        k_score2<<<2048, 256, 0, stream>>>(eap, srcp, dstp, wf,
                                           (const uint32*)xl, (const uint32*)xr, (uint4*)sc);
        k_agg2<<<(Nn + 3) / 4, 256, 0, stream>>>(sc, offs, srcp, (const uint32*)xl,
                                                 x, wf, flg, (uint4*)x1);
        k_wprep<<<256, 256, 0, stream>>>(wf, W1s, W2s);
        k_ffn<<<(Nn + 31) / 32, 128, 0, stream>>>(x1, wf, W1s, W2s, (float*)d_out);
    } else {
        // ---- PLAN B: proven round-7 pipeline ----
        __hip_bfloat16* sc  = (__hip_bfloat16*)(wsb + B_SC);
        __hip_bfloat16* xl  = (__hip_bfloat16*)(wsb + B_XL);
        __hip_bfloat16* x1  = (__hip_bfloat16*)(wsb + B_X1);
        __hip_bfloat16* la  = (__hip_bfloat16*)(wsb + B_LA);
        int*   eix  = (int*)(wsb + B_EIX);
        int*   cnt  = (int*)(wsb + B_CNT);
        int*   offs = (int*)(wsb + B_OFS);
        int*   cur  = (int*)(wsb + B_CUR);
        int*   csr  = (int*)(wsb + B_CSR);
        float* wf   = (float*)(wsb + B_WF);
        int*   flg  = (int*)(wsb + B_FLG);
        __hip_bfloat16* xr  = (__hip_bfloat16*)d_out;
        ushort* W1s = (ushort*)(wsb + B_SC);
        ushort* W2s = (ushort*)(wsb + B_SC + 131072);

        hipMemsetAsync(cnt, 0, Nn * sizeof(int), stream);
        k_sniff<<<1, 64, 0, stream>>>((const uint32*)x, (const uint32*)eattr, flg);
        k_cvt<<<(2 * Ee + 255) / 256, 256, 0, stream>>>(eraw, eix, cnt);
        k_wcanon<<<(WF_TOT + 255) / 256, 256, 0, stream>>>(wsrc, flg, wf);
        k_scan<<<1, 1024, 0, stream>>>(cnt, offs, cur);
        k_fill<<<(EF + 255) / 256, 256, 0, stream>>>(eix, cur, offs, csr);
        k_loopattr<<<(Nn + 3) / 4, 256, 0, stream>>>(eattr, csr, offs, flg, la);
        k_lin<<<512, 256, 0, stream>>>(x, wf + WF_Wl, wf + WF_bl, flg, xl);
        k_lin<<<512, 256, 0, stream>>>(x, wf + WF_Wr, wf + WF_br, flg, xr);
        k_score<<<2048, 256, 0, stream>>>(eattr, eix, (const uint32*)la, wf, flg,
                                          (const uint32*)xl, (const uint32*)xr, (uint4*)sc);
        k_agg<<<(Nn + 3) / 4, 256, 0, stream>>>((const ushort*)sc, csr, offs, eix,
                                                (const uint32*)xl, x, wf, flg, (uint4*)x1);
        k_wprep<<<256, 256, 0, stream>>>(wf, W1s, W2s);
        k_ffn<<<(Nn + 31) / 32, 128, 0, stream>>>((const ushort*)x1, wf, W1s, W2s,
                                                  (float*)d_out);
    }
}

// Round 10
// 549.578 us; speedup vs baseline: 2.6730x; 1.0688x over previous
//
#include <hip/hip_runtime.h>
#include <hip/hip_bf16.h>

typedef unsigned int uint32;
typedef unsigned short ushort;
typedef __attribute__((ext_vector_type(8))) short short8;   // 8 bf16 (4 VGPRs)
typedef __attribute__((ext_vector_type(4))) float float4v;  // MFMA acc

// ---------------- problem constants ----------------
constexpr int Nn = 50000;
constexpr int Ee = 800000;
constexpr int EF = Ee + Nn;          // 850000, divisible by 16
constexpr int NT = EF / 16;          // 53125 MFMA tiles
constexpr int TE = Ee / 16;          // 50000
constexpr int SCAN_NB = 200;         // 200*256 = 51200 >= Nn

// ---------------- PLAN B (round-7) ws layout ----------------
constexpr long B_SC  = 0;
constexpr long B_XL  = 13600000;
constexpr long B_X1  = 26400000;
constexpr long B_LA  = 39200000;
constexpr long B_EIX = 42400000;
constexpr long B_CNT = 48800000;
constexpr long B_OFS = 49000000;
constexpr long B_CUR = 49200016;
constexpr long B_CSR = 49400016;
constexpr long B_WF  = 52800016;
constexpr long B_FLG = 53478416;

// ---------------- PLAN A ws layout (CSR-ordered edge data) ----------------
constexpr long A_EAP = 0;            // bf16 [EF*32]  54,400,000 (x1 aliases here after k_score2)
constexpr long A_SRC = 54400000;     // int  [EF]      3,400,000
constexpr long A_DST = 57800000;     // int  [EF]      3,400,000
constexpr long A_SCO = 61200000;     // bf16 [EF*8]   13,600,000 (bsum/bpre, Wls/Wrs, W1s/W2s alias)
constexpr long A_EIX = 74800000;     // int  [2*Ee]    6,400,000
constexpr long A_CNT = 81200000;
constexpr long A_OFS = 81400000;
constexpr long A_CUR = 81600016;
constexpr long A_WF  = 81800016;     // fp32 [169600]
constexpr long A_FLG = 82478416;
constexpr long NEED_A = 82478432;

// canonical weight float offsets
constexpr int WF_Wl = 0, WF_bl = 16384, WF_Wr = 16512, WF_br = 32896;
constexpr int WF_We = 33024, WF_att = 37120, WF_bias = 37248;
constexpr int WF_W1 = 37376, WF_b1 = 102912, WF_W2 = 103424, WF_b2 = 168960;
constexpr int WF_g1 = 169088, WF_be1 = 169216, WF_g2 = 169344, WF_be2 = 169472;
constexpr int WF_TOT = 169600;

static __device__ __forceinline__ float b2f(__hip_bfloat16 v) { return __bfloat162float(v); }
static __device__ __forceinline__ float2 up2(uint32 u) {
    union { uint32 i; float f; } a, b;
    a.i = (u & 0xFFFFu) << 16; b.i = u & 0xFFFF0000u;
    return make_float2(a.f, b.f);
}
static __device__ __forceinline__ float up1(ushort u) {
    union { uint32 i; float f; } a; a.i = ((uint32)u) << 16; return a.f;
}
static __device__ __forceinline__ ushort f2bu(float f) {
    __hip_bfloat16 h = __float2bfloat16(f); return *(ushort*)&h;
}
static __device__ __forceinline__ float san(float v) { return fminf(fmaxf(v, -1e4f), 1e4f); }

// ================= shared kernels =================
__global__ void k_sniff(const uint32* __restrict__ xu, const uint32* __restrict__ eu,
                        int* __restrict__ flg) {
    int lane = threadIdx.x;
    int xbf = 0, ebf = 0;
    #pragma unroll
    for (int j = 0; j < 8; j++) {
        uint32 ux = xu[lane * 8 + j];
        int ex = (ux >> 7) & 0xFF;
        xbf += (ex >= 100 && ex <= 135) ? 1 : 0;
        uint32 ue = eu[lane * 8 + j];
        int ee = (ue >> 7) & 0xFF;
        ebf += (ee >= 100 && ee <= 135) ? 1 : 0;
    }
    #pragma unroll
    for (int mk = 1; mk < 64; mk <<= 1) { xbf += __shfl_xor(xbf, mk); ebf += __shfl_xor(ebf, mk); }
    if (lane == 0) { flg[0] = (xbf > 256) ? 0 : 1; flg[1] = (ebf > 256) ? 0 : 1; }
}

__global__ void k_cvt(const int* __restrict__ raw, int* __restrict__ eix,
                      int* __restrict__ cnt) {
    __shared__ int is64;
    if (threadIdx.x == 0) {
        int z = 1;
        #pragma unroll
        for (int j = 1; j < 64; j += 2) z &= (raw[j] == 0);
        is64 = z;
    }
    __syncthreads();
    int i = blockIdx.x * 256 + threadIdx.x;
    if (i < 2 * Ee) {
        int v = is64 ? raw[2 * i] : raw[i];
        v = v < 0 ? 0 : (v >= Nn ? Nn - 1 : v);
        eix[i] = v;
        if (i >= Ee) atomicAdd(&cnt[v], 1);
    }
}

struct WSrc { const void* p[15]; };
__global__ void k_wcanon(WSrc s, const int* __restrict__ flagp, float* __restrict__ dst) {
    const int cum[16] = {0, 16384, 16512, 32896, 33024, 37120, 37248, 37376,
                         102912, 103424, 168960, 169088, 169216, 169344, 169472, 169600};
    int i = blockIdx.x * 256 + threadIdx.x;
    if (i >= WF_TOT) return;
    int isf32 = flagp[0];
    int seg = 0;
    #pragma unroll
    for (int j = 1; j < 16; j++) seg += (i >= cum[j]);
    int off = i - cum[seg];
    float v = isf32 ? ((const float*)s.p[seg])[off]
                    : b2f(((const __hip_bfloat16*)s.p[seg])[off]);
    dst[i] = v;
}

// ---- hierarchical scan ----
__global__ void __launch_bounds__(256) k_scanA(const int* __restrict__ cnt,
                                               int* __restrict__ bsum) {
    int i = blockIdx.x * 256 + threadIdx.x;
    int v = (i < Nn) ? cnt[i] + 1 : 0;
    #pragma unroll
    for (int mk = 1; mk < 64; mk <<= 1) v += __shfl_xor(v, mk);
    __shared__ int wt[4];
    if ((threadIdx.x & 63) == 0) wt[threadIdx.x >> 6] = v;
    __syncthreads();
    if (threadIdx.x == 0) bsum[blockIdx.x] = wt[0] + wt[1] + wt[2] + wt[3];
}

__global__ void __launch_bounds__(256) k_scanB(const int* __restrict__ bsum,
                                               int* __restrict__ bpre) {
    int t = threadIdx.x;
    int lane = t & 63, wv = t >> 6;
    int orig = (t < SCAN_NB) ? bsum[t] : 0;
    int v = orig;
    #pragma unroll
    for (int off = 1; off < 64; off <<= 1) {
        int u = __shfl_up(v, off);
        if (lane >= off) v += u;
    }
    __shared__ int wt[4];
    if (lane == 63) wt[wv] = v;
    __syncthreads();
    int add = 0;
    for (int w = 0; w < wv; w++) add += wt[w];
    if (t < SCAN_NB) bpre[t] = v + add - orig;   // exclusive
}

__global__ void __launch_bounds__(256) k_scanC(const int* __restrict__ cnt,
                                               const int* __restrict__ bpre,
                                               int* __restrict__ offs,
                                               int* __restrict__ cursor) {
    int i = blockIdx.x * 256 + threadIdx.x;
    int lane = threadIdx.x & 63, wv = threadIdx.x >> 6;
    int v = (i < Nn) ? cnt[i] + 1 : 0;
    int inc = v;
    #pragma unroll
    for (int off = 1; off < 64; off <<= 1) {
        int u = __shfl_up(inc, off);
        if (lane >= off) inc += u;
    }
    __shared__ int wt[4];
    if (lane == 63) wt[wv] = inc;
    __syncthreads();
    int add = bpre[blockIdx.x];
    for (int w = 0; w < wv; w++) add += wt[w];
    int exc = add + inc - v;
    if (i < Nn) { offs[i] = exc; cursor[i] = 0; }
    if (i == Nn - 1) offs[Nn] = exc + v;
}

// legacy single-block scan (Plan B only)
__global__ void __launch_bounds__(1024) k_scan(const int* __restrict__ cnt,
                                               int* __restrict__ offs, int* __restrict__ cursor) {
    __shared__ int part[1024];
    int t = threadIdx.x;
    const int CH = (Nn + 1023) / 1024;
    int base = t * CH;
    int s = 0;
    for (int i = 0; i < CH; i++) { int n = base + i; if (n < Nn) s += cnt[n] + 1; }
    part[t] = s;
    __syncthreads();
    for (int off = 1; off < 1024; off <<= 1) {
        int v = (t >= off) ? part[t - off] : 0;
        __syncthreads();
        part[t] += v;
        __syncthreads();
    }
    int run = part[t] - s;
    for (int i = 0; i < CH; i++) {
        int n = base + i;
        if (n < Nn) { offs[n] = run; run += cnt[n] + 1; cursor[n] = 0; }
    }
    if (t == 1023) offs[Nn] = part[1023];
}

// W1/W2 -> MFMA frag order (for k_ffn)
__global__ void k_wprep(const float* __restrict__ wf,
                        ushort* __restrict__ W1s, ushort* __restrict__ W2s) {
    int i = blockIdx.x * 256 + threadIdx.x;
    if (i >= 65536) return;
    int j = i & 7, lane = (i >> 3) & 63, g = i >> 9;
    int c = lane & 15, q = lane >> 4;
    int kk = g & 3, ht = g >> 2;
    W1s[i] = f2bu(wf[WF_W1 + (kk * 32 + q * 8 + j) * 512 + ht * 16 + c]);
    int kk2 = g & 15, nt = g >> 4;
    W2s[i] = f2bu(wf[WF_W2 + (kk2 * 32 + q * 8 + j) * 128 + nt * 16 + c]);
}

// MFMA FFN + residual + LN2 -> fp32 out
__global__ void __launch_bounds__(128) k_ffn(const ushort* __restrict__ x1b,
                                             const float* __restrict__ wf,
                                             const ushort* __restrict__ W1s,
                                             const ushort* __restrict__ W2s,
                                             float* __restrict__ out) {
    __shared__ ushort hb[2][16 * 520];
    __shared__ ushort xsb[2][16 * 136];
    int wv = threadIdx.x >> 6;
    int lane = threadIdx.x & 63;
    int c = lane & 15, q = lane >> 4;
    long n0 = (long)blockIdx.x * 32 + wv * 16;
    if (n0 >= Nn) return;
    ushort* h = hb[wv];
    ushort* xs = xsb[wv];

    short8 B1[4];
    const uint4* x1row = (const uint4*)(x1b + (n0 + c) * 128);
    #pragma unroll
    for (int kk = 0; kk < 4; kk++) {
        union { uint4 u; short8 s; } cv; cv.u = x1row[kk * 4 + q]; B1[kk] = cv.s;
    }
    for (int i = lane; i < 256; i += 64) {
        int row = i >> 4, col = i & 15;
        *(uint4*)(xs + row * 136 + col * 8) = *(const uint4*)(x1b + (n0 + row) * 128 + col * 8);
    }
    const uint4* W1v = (const uint4*)W1s;
    for (int ht = 0; ht < 32; ht++) {
        float4v acc = (float4v){0.f, 0.f, 0.f, 0.f};
        #pragma unroll
        for (int kk = 0; kk < 4; kk++) {
            union { uint4 u; short8 s; } a; a.u = W1v[(ht * 4 + kk) * 64 + lane];
            acc = __builtin_amdgcn_mfma_f32_16x16x32_bf16(a.s, B1[kk], acc, 0, 0, 0);
        }
        float4 bb = *(const float4*)(wf + WF_b1 + ht * 16 + q * 4);
        uint2 pk;
        pk.x = (uint32)f2bu(fmaxf(acc[0] + bb.x, 0.f)) | ((uint32)f2bu(fmaxf(acc[1] + bb.y, 0.f)) << 16);
        pk.y = (uint32)f2bu(fmaxf(acc[2] + bb.z, 0.f)) | ((uint32)f2bu(fmaxf(acc[3] + bb.w, 0.f)) << 16);
        *(uint2*)(h + c * 520 + ht * 16 + q * 4) = pk;
    }
    const uint4* W2v = (const uint4*)W2s;
    float4v acc2[8];
    #pragma unroll
    for (int nt = 0; nt < 8; nt++) acc2[nt] = (float4v){0.f, 0.f, 0.f, 0.f};
    for (int kk2 = 0; kk2 < 16; kk2++) {
        union { uint4 u; short8 s; } a2;
        a2.u = *(const uint4*)(h + c * 520 + kk2 * 32 + q * 8);
        #pragma unroll
        for (int nt = 0; nt < 8; nt++) {
            union { uint4 u; short8 s; } b2f_;
            b2f_.u = W2v[(nt * 16 + kk2) * 64 + lane];
            acc2[nt] = __builtin_amdgcn_mfma_f32_16x16x32_bf16(a2.s, b2f_.s, acc2[nt], 0, 0, 0);
        }
    }
    float b2v[8], g2v[8], be2v[8];
    #pragma unroll
    for (int nt = 0; nt < 8; nt++) {
        b2v[nt]  = wf[WF_b2  + nt * 16 + c];
        g2v[nt]  = wf[WF_g2  + nt * 16 + c];
        be2v[nt] = wf[WF_be2 + nt * 16 + c];
    }
    float yv[8][4];
    float sum[4] = {0.f, 0.f, 0.f, 0.f}, sq[4] = {0.f, 0.f, 0.f, 0.f};
    #pragma unroll
    for (int nt = 0; nt < 8; nt++) {
        #pragma unroll
        for (int r = 0; r < 4; r++) {
            float v = acc2[nt][r] + b2v[nt] + up1(xs[(q * 4 + r) * 136 + nt * 16 + c]);
            yv[nt][r] = v;
            sum[r] += v; sq[r] += v * v;
        }
    }
    #pragma unroll
    for (int mask = 1; mask < 16; mask <<= 1) {
        #pragma unroll
        for (int r = 0; r < 4; r++) {
            sum[r] += __shfl_xor(sum[r], mask);
            sq[r]  += __shfl_xor(sq[r], mask);
        }
    }
    #pragma unroll
    for (int r = 0; r < 4; r++) {
        float mean = sum[r] * (1.0f / 128.0f);
        float var = sq[r] * (1.0f / 128.0f) - mean * mean;
        float rstd = rsqrtf(var + 1e-5f);
        long nodeb = (n0 + q * 4 + r) * 128;
        #pragma unroll
        for (int nt = 0; nt < 8; nt++) {
            out[nodeb + nt * 16 + c] = san((yv[nt][r] - mean) * rstd * g2v[nt] + be2v[nt]);
        }
    }
}

// ================= PLAN A kernels =================
__global__ void k_wprepL(const float* __restrict__ wf,
                         ushort* __restrict__ Wls, ushort* __restrict__ Wrs) {
    int i = blockIdx.x * 256 + threadIdx.x;
    if (i >= 16384) return;
    int j = i & 7, lane = (i >> 3) & 63, g = i >> 9;
    int c = lane & 15, q = lane >> 4;
    int kk = g & 3, ot = g >> 2;
    int kin = kk * 32 + q * 8 + j, outd = ot * 16 + c;
    Wls[i] = f2bu(wf[WF_Wl + kin * 128 + outd]);
    Wrs[i] = f2bu(wf[WF_Wr + kin * 128 + outd]);
}

__global__ void __launch_bounds__(256) k_linlr(const void* __restrict__ x,
                                               const float* __restrict__ wf,
                                               const ushort* __restrict__ Wls,
                                               const ushort* __restrict__ Wrs,
                                               const int* __restrict__ flagp,
                                               ushort* __restrict__ xl,
                                               ushort* __restrict__ xr) {
    int isf32 = flagp[0];
    int wv = threadIdx.x >> 6, lane = threadIdx.x & 63;
    int c = lane & 15, q = lane >> 4;
    long n0 = ((long)blockIdx.x * 4 + wv) * 16;
    if (n0 >= Nn) return;
    short8 B[4];
    if (isf32) {
        const float* xrow = (const float*)x + (n0 + c) * 128;
        #pragma unroll
        for (int kk = 0; kk < 4; kk++)
            #pragma unroll
            for (int j = 0; j < 8; j++)
                B[kk][j] = (short)f2bu(xrow[kk * 32 + q * 8 + j]);
    } else {
        const uint4* xrow = (const uint4*)((const ushort*)x + (n0 + c) * 128);
        #pragma unroll
        for (int kk = 0; kk < 4; kk++) {
            union { uint4 u; short8 s; } cv; cv.u = xrow[kk * 4 + q]; B[kk] = cv.s;
        }
    }
    const uint4* Al = (const uint4*)Wls;
    const uint4* Ar = (const uint4*)Wrs;
    #pragma unroll
    for (int ot = 0; ot < 8; ot++) {
        float4v aL = (float4v){0.f, 0.f, 0.f, 0.f};
        float4v aR = (float4v){0.f, 0.f, 0.f, 0.f};
        #pragma unroll
        for (int kk = 0; kk < 4; kk++) {
            union { uint4 u; short8 s; } a, b;
            a.u = Al[(ot * 4 + kk) * 64 + lane];
            b.u = Ar[(ot * 4 + kk) * 64 + lane];
            aL = __builtin_amdgcn_mfma_f32_16x16x32_bf16(a.s, B[kk], aL, 0, 0, 0);
            aR = __builtin_amdgcn_mfma_f32_16x16x32_bf16(b.s, B[kk], aR, 0, 0, 0);
        }
        float4 bl4 = *(const float4*)(wf + WF_bl + ot * 16 + q * 4);
        float4 br4 = *(const float4*)(wf + WF_br + ot * 16 + q * 4);
        uint2 pl, pr;
        pl.x = (uint32)f2bu(san(aL[0] + bl4.x)) | ((uint32)f2bu(san(aL[1] + bl4.y)) << 16);
        pl.y = (uint32)f2bu(san(aL[2] + bl4.z)) | ((uint32)f2bu(san(aL[3] + bl4.w)) << 16);
        pr.x = (uint32)f2bu(san(aR[0] + br4.x)) | ((uint32)f2bu(san(aR[1] + br4.y)) << 16);
        pr.y = (uint32)f2bu(san(aR[2] + br4.z)) | ((uint32)f2bu(san(aR[3] + br4.w)) << 16);
        *(uint2*)(xl + (n0 + c) * 128 + ot * 16 + q * 4) = pl;
        *(uint2*)(xr + (n0 + c) * 128 + ot * 16 + q * 4) = pr;
    }
}

__global__ void __launch_bounds__(256) k_fill2(const int* __restrict__ eix,
                                               const void* __restrict__ eattr,
                                               const int* __restrict__ flagp,
                                               int* __restrict__ cur,
                                               const int* __restrict__ offs,
                                               ushort* __restrict__ eap,
                                               int* __restrict__ srcp,
                                               int* __restrict__ dstp) {
    int isf32 = flagp[1];
    int gid = blockIdx.x * 256 + threadIdx.x;
    int e = gid >> 2, sub = gid & 3;
    int lane = threadIdx.x & 63;
    int d = eix[Ee + e];
    int p = 0;
    if (sub == 0) p = offs[d] + atomicAdd(&cur[d], 1);
    p = __shfl(p, lane & ~3);
    if (sub == 0) { srcp[p] = eix[e]; dstp[p] = d; }
    uint4 o;
    if (isf32) {
        const float* r = (const float*)eattr + (long)e * 32 + sub * 8;
        o.x = (uint32)f2bu(r[0]) | ((uint32)f2bu(r[1]) << 16);
        o.y = (uint32)f2bu(r[2]) | ((uint32)f2bu(r[3]) << 16);
        o.z = (uint32)f2bu(r[4]) | ((uint32)f2bu(r[5]) << 16);
        o.w = (uint32)f2bu(r[6]) | ((uint32)f2bu(r[7]) << 16);
    } else {
        o = ((const uint4*)eattr)[(long)e * 4 + sub];
    }
    *(uint4*)(eap + (long)p * 32 + sub * 8) = o;
}

__global__ void __launch_bounds__(256) k_self(const int* __restrict__ offs,
                                              ushort* __restrict__ eap,
                                              int* __restrict__ srcp,
                                              int* __restrict__ dstp) {
    int lane = threadIdx.x & 63;
    int n = (blockIdx.x * 256 + threadIdx.x) >> 6;
    if (n >= Nn) return;
    int off = offs[n], deg1 = offs[n + 1] - 1 - off;
    int k = lane & 31, half = lane >> 5;
    float acc = 0.f;
    for (int i = half; i < deg1; i += 2)
        acc += up1(eap[(long)(off + i) * 32 + k]);
    acc += __shfl_xor(acc, 32);
    float inv = 1.0f / fmaxf((float)deg1, 1.0f);
    long ps = off + deg1;
    if (lane < 32) eap[ps * 32 + k] = f2bu(san(acc * inv));
    if (lane == 0) { srcp[ps] = n; dstp[ps] = n; }
}

__global__ void __launch_bounds__(256) k_score2(const ushort* __restrict__ eap,
                                                const int* __restrict__ srcp,
                                                const int* __restrict__ dstp,
                                                const float* __restrict__ wf,
                                                const uint32* __restrict__ xlu,
                                                const uint32* __restrict__ xru,
                                                uint4* __restrict__ score16) {
    int t256 = threadIdx.x;
    int lane = t256 & 63;
    int c0 = lane & 15, q = lane >> 4;
    int w = (blockIdx.x * 256 + t256) >> 6;
    int nw = (gridDim.x * 256) >> 6;

    short8 A[8];
    float att[8][4];
    #pragma unroll
    for (int t = 0; t < 8; t++) {
        #pragma unroll
        for (int j = 0; j < 8; j++)
            A[t][j] = (short)f2bu(wf[WF_We + (q * 8 + j) * 128 + t * 16 + c0]);
        #pragma unroll
        for (int r = 0; r < 4; r++)
            att[t][r] = wf[WF_att + t * 16 + q * 4 + r];
    }

    for (int T = w; T < NT; T += nw) {
        int slot = T * 16 + c0;
        int srcn = srcp[slot], dstn = dstp[slot];
        union { uint4 u; short8 s; } cv;
        cv.u = *(const uint4*)(eap + (long)slot * 32 + q * 8);
        short8 B = cv.s;

        float4v acc[8];
        #pragma unroll
        for (int t = 0; t < 8; t++) {
            acc[t] = (float4v){0.f, 0.f, 0.f, 0.f};
            acc[t] = __builtin_amdgcn_mfma_f32_16x16x32_bf16(A[t], B, acc[t], 0, 0, 0);
        }
        uint2 xg[8], rg[8];
        #pragma unroll
        for (int t = 0; t < 8; t++) {
            xg[t] = ((const uint2*)xlu)[(long)srcn * 32 + t * 4 + q];
            rg[t] = ((const uint2*)xru)[(long)dstn * 32 + t * 4 + q];
        }
        float st[8];
        #pragma unroll
        for (int t = 0; t < 8; t++) {
            float2 xa = up2(xg[t].x), xb2 = up2(xg[t].y);
            float2 ra = up2(rg[t].x), rb = up2(rg[t].y);
            float v0 = acc[t][0] + xa.x + ra.x;
            float v1 = acc[t][1] + xa.y + ra.y;
            float v2 = acc[t][2] + xb2.x + rb.x;
            float v3 = acc[t][3] + xb2.y + rb.y;
            v0 = v0 > 0.f ? v0 : 0.2f * v0;
            v1 = v1 > 0.f ? v1 : 0.2f * v1;
            v2 = v2 > 0.f ? v2 : 0.2f * v2;
            v3 = v3 > 0.f ? v3 : 0.2f * v3;
            st[t] = att[t][0] * v0 + att[t][1] * v1 + att[t][2] * v2 + att[t][3] * v3;
        }
        #pragma unroll
        for (int t = 0; t < 8; t++) {
            st[t] += __shfl_xor(st[t], 16);
            st[t] += __shfl_xor(st[t], 32);
        }
        if (q == 0) {
            uint4 o;
            o.x = (uint32)f2bu(san(st[0])) | ((uint32)f2bu(san(st[1])) << 16);
            o.y = (uint32)f2bu(san(st[2])) | ((uint32)f2bu(san(st[3])) << 16);
            o.z = (uint32)f2bu(san(st[4])) | ((uint32)f2bu(san(st[5])) << 16);
            o.w = (uint32)f2bu(san(st[6])) | ((uint32)f2bu(san(st[7])) << 16);
            score16[slot] = o;
        }
    }
}

// two-pass softmax + aggregate + bias + residual + LN1 (exp count ~deg/8 per wave)
__global__ void __launch_bounds__(256) k_agg2(const ushort* __restrict__ scu,
                                              const int* __restrict__ offs,
                                              const int* __restrict__ srcp,
                                              const uint32* __restrict__ xlu,
                                              const void* __restrict__ x,
                                              const float* __restrict__ wf,
                                              const int* __restrict__ flagp,
                                              uint4* __restrict__ x1) {
    int isf32 = flagp[0];
    int lane = threadIdx.x & 63;
    int n = (blockIdx.x * 256 + threadIdx.x) >> 6;
    int off = offs[n], deg = offs[n + 1] - off;
    int g = lane >> 3, hh = lane & 7;   // lane = g*8 + hh: edge-group g, head hh

    // pass 1: per-head max over this lane's edge stripe (no exp)
    float mx = -1e30f;
    for (int i = g; i < deg; i += 8)
        mx = fmaxf(mx, up1(scu[(long)(off + i) * 8 + hh]));
    #pragma unroll
    for (int mask = 8; mask < 64; mask <<= 1)
        mx = fmaxf(mx, __shfl_xor(mx, mask));

    // pass 2: unnormalized weighted aggregation + denom (1 exp per edge-stripe step)
    float s = 0.f;
    float acc[16];
    #pragma unroll
    for (int j = 0; j < 16; j++) acc[j] = 0.f;
    for (int i = g; i < deg; i += 8) {
        long sl = off + i;
        float e = __expf(up1(scu[sl * 8 + hh]) - mx);
        s += e;
        int srcn = srcp[sl];
        uint4 a = ((const uint4*)xlu)[(long)srcn * 16 + hh * 2];
        uint4 b = ((const uint4*)xlu)[(long)srcn * 16 + hh * 2 + 1];
        float2 v0 = up2(a.x), v1 = up2(a.y), v2 = up2(a.z), v3 = up2(a.w);
        float2 v4 = up2(b.x), v5 = up2(b.y), v6 = up2(b.z), v7 = up2(b.w);
        acc[0] += e * v0.x;  acc[1] += e * v0.y;
        acc[2] += e * v1.x;  acc[3] += e * v1.y;
        acc[4] += e * v2.x;  acc[5] += e * v2.y;
        acc[6] += e * v3.x;  acc[7] += e * v3.y;
        acc[8] += e * v4.x;  acc[9] += e * v4.y;
        acc[10] += e * v5.x; acc[11] += e * v5.y;
        acc[12] += e * v6.x; acc[13] += e * v6.y;
        acc[14] += e * v7.x; acc[15] += e * v7.y;
    }
    #pragma unroll
    for (int mask = 8; mask < 64; mask <<= 1) {
        s += __shfl_xor(s, mask);
        #pragma unroll
        for (int j = 0; j < 16; j++) acc[j] += __shfl_xor(acc[j], mask);
    }
    float inv = 1.0f / s;

    // lanes g==0: scale, + residual + bias, LN1, store
    float y[16];
    if (g == 0) {
        int d0 = hh * 16;
        if (isf32) {
            const float4* xf = (const float4*)x;
            #pragma unroll
            for (int c = 0; c < 4; c++) {
                float4 xv = xf[(long)n * 32 + hh * 4 + c];
                y[c*4+0] = acc[c*4+0] * inv + xv.x + wf[WF_bias + d0 + c*4+0];
                y[c*4+1] = acc[c*4+1] * inv + xv.y + wf[WF_bias + d0 + c*4+1];
                y[c*4+2] = acc[c*4+2] * inv + xv.z + wf[WF_bias + d0 + c*4+2];
                y[c*4+3] = acc[c*4+3] * inv + xv.w + wf[WF_bias + d0 + c*4+3];
            }
        } else {
            const uint4* xb = (const uint4*)x;
            uint4 a = xb[(long)n * 16 + hh * 2];
            uint4 b = xb[(long)n * 16 + hh * 2 + 1];
            uint32 ww[8] = {a.x, a.y, a.z, a.w, b.x, b.y, b.z, b.w};
            #pragma unroll
            for (int c = 0; c < 8; c++) {
                float2 v = up2(ww[c]);
                y[c*2+0] = acc[c*2+0] * inv + v.x + wf[WF_bias + d0 + c*2+0];
                y[c*2+1] = acc[c*2+1] * inv + v.y + wf[WF_bias + d0 + c*2+1];
            }
        }
    }
    float sum = 0.f, sq = 0.f;
    if (g == 0) {
        #pragma unroll
        for (int j = 0; j < 16; j++) { sum += y[j]; sq += y[j] * y[j]; }
    }
    #pragma unroll
    for (int mask = 1; mask < 8; mask <<= 1) { sum += __shfl_xor(sum, mask); sq += __shfl_xor(sq, mask); }
    if (g == 0) {
        int d0 = hh * 16;
        float mean = sum * (1.0f / 128.0f);
        float var = sq * (1.0f / 128.0f) - mean * mean;
        float rstd = rsqrtf(var + 1e-5f);
        uint32 o[8];
        #pragma unroll
        for (int c = 0; c < 8; c++) {
            float o0 = san((y[c*2+0] - mean) * rstd * wf[WF_g1 + d0 + c*2+0] + wf[WF_be1 + d0 + c*2+0]);
            float o1 = san((y[c*2+1] - mean) * rstd * wf[WF_g1 + d0 + c*2+1] + wf[WF_be1 + d0 + c*2+1]);
            o[c] = (uint32)f2bu(o0) | ((uint32)f2bu(o1) << 16);
        }
        x1[(long)n * 16 + hh * 2]     = make_uint4(o[0], o[1], o[2], o[3]);
        x1[(long)n * 16 + hh * 2 + 1] = make_uint4(o[4], o[5], o[6], o[7]);
    }
}

// ================= PLAN B (round-7) kernels =================
__global__ void k_fill(const int* __restrict__ eix, int* __restrict__ cursor,
                       const int* __restrict__ offs, int* __restrict__ csr) {
    int e = blockIdx.x * 256 + threadIdx.x;
    if (e >= EF) return;
    int d = (e < Ee) ? eix[Ee + e] : (e - Ee);
    int p = atomicAdd(&cursor[d], 1);
    csr[offs[d] + p] = e;
}

__global__ void __launch_bounds__(256) k_loopattr(const void* __restrict__ eattr,
                                                  const int* __restrict__ csr,
                                                  const int* __restrict__ offs,
                                                  const int* __restrict__ flagp,
                                                  __hip_bfloat16* __restrict__ la) {
    int isf32 = flagp[1];
    int lane = threadIdx.x & 63;
    int n = (blockIdx.x * 256 + threadIdx.x) >> 6;
    if (n >= Nn) return;
    int off = offs[n], deg = offs[n + 1] - off;
    int k = lane & 31, half = lane >> 5;
    const float* ef = (const float*)eattr;
    const __hip_bfloat16* eb = (const __hip_bfloat16*)eattr;
    float acc = 0.f;
    for (int i = half; i < deg; i += 2) {
        int e = csr[off + i];
        if (e < Ee) acc += isf32 ? ef[(long)e * 32 + k] : b2f(eb[(long)e * 32 + k]);
    }
    acc += __shfl_xor(acc, 32);
    float inv = 1.0f / fmaxf((float)(deg - 1), 1.0f);
    if (lane < 32) la[(long)n * 32 + k] = __float2bfloat16(san(acc * inv));
}

__global__ void __launch_bounds__(256) k_lin(const void* __restrict__ x,
                                             const float* __restrict__ Wf,
                                             const float* __restrict__ bf_,
                                             const int* __restrict__ flagp,
                                             __hip_bfloat16* __restrict__ out) {
    __shared__ ushort Wlds[128][130];
    __shared__ float xrow[2][128];
    int isf32 = flagp[0];
    int t = threadIdx.x, col = t & 127, sub = t >> 7;
    for (int i = t; i < 16384; i += 256) Wlds[i >> 7][i & 127] = f2bu(Wf[i]);
    float bias = bf_[col];
    const float* xf = (const float*)x;
    const __hip_bfloat16* xb = (const __hip_bfloat16*)x;
    int rpb = (Nn + gridDim.x - 1) / gridDim.x;
    int r0 = blockIdx.x * rpb, r1 = min(r0 + rpb, Nn);
    __syncthreads();
    for (int r = r0; r < r1; r += 2) {
        int rr = r + sub;
        if (rr < r1) xrow[sub][col] = isf32 ? xf[(long)rr * 128 + col]
                                            : b2f(xb[(long)rr * 128 + col]);
        __syncthreads();
        float acc = bias;
        #pragma unroll 16
        for (int k = 0; k < 128; k++) {
            union { uint32 i; float f; } u; u.i = ((uint32)Wlds[k][col]) << 16;
            acc += xrow[sub][k] * u.f;
        }
        if (rr < r1) out[(long)rr * 128 + col] = __float2bfloat16(san(acc));
        __syncthreads();
    }
}

__global__ void __launch_bounds__(256) k_score(const void* __restrict__ eattr,
                                               const int* __restrict__ eix,
                                               const uint32* __restrict__ la_u,
                                               const float* __restrict__ wf,
                                               const int* __restrict__ flagp,
                                               const uint32* __restrict__ xlu,
                                               const uint32* __restrict__ xru,
                                               uint4* __restrict__ score16) {
    int isf32 = flagp[1];
    int t256 = threadIdx.x;
    int lane = t256 & 63;
    int c0 = lane & 15, q = lane >> 4;
    int w = (blockIdx.x * 256 + t256) >> 6;
    int nw = (gridDim.x * 256) >> 6;
    short8 A[8];
    float att[8][4];
    #pragma unroll
    for (int t = 0; t < 8; t++) {
        #pragma unroll
        for (int j = 0; j < 8; j++)
            A[t][j] = (short)f2bu(wf[WF_We + (q * 8 + j) * 128 + t * 16 + c0]);
        #pragma unroll
        for (int r = 0; r < 4; r++)
            att[t][r] = wf[WF_att + t * 16 + q * 4 + r];
    }
    const float* ef = (const float*)eattr;
    const uint4* eb4 = (const uint4*)eattr;
    for (int T = w; T < NT; T += nw) {
        int row = T * 16 + c0;
        int srcn, dstn;
        short8 B;
        if (T < TE) {
            srcn = eix[row]; dstn = eix[Ee + row];
            if (isf32) {
                const float* p = ef + (long)row * 32 + q * 8;
                #pragma unroll
                for (int j = 0; j < 8; j++) B[j] = (short)f2bu(p[j]);
            } else {
                union { uint4 u; short8 s; } cv;
                cv.u = eb4[(long)row * 4 + q];
                B = cv.s;
            }
        } else {
            int n = row - Ee;
            srcn = n; dstn = n;
            union { uint4 u; short8 s; } cv;
            cv.u = ((const uint4*)la_u)[(long)n * 4 + q];
            B = cv.s;
        }
        float4v acc[8];
        #pragma unroll
        for (int t = 0; t < 8; t++) {
            acc[t] = (float4v){0.f, 0.f, 0.f, 0.f};
            acc[t] = __builtin_amdgcn_mfma_f32_16x16x32_bf16(A[t], B, acc[t], 0, 0, 0);
        }
        uint2 xg[8], rg[8];
        #pragma unroll
        for (int t = 0; t < 8; t++) {
            xg[t] = ((const uint2*)xlu)[(long)srcn * 32 + t * 4 + q];
            rg[t] = ((const uint2*)xru)[(long)dstn * 32 + t * 4 + q];
        }
        float st[8];
        #pragma unroll
        for (int t = 0; t < 8; t++) {
            float2 xa = up2(xg[t].x), xb2 = up2(xg[t].y);
            float2 ra = up2(rg[t].x), rb = up2(rg[t].y);
            float v0 = acc[t][0] + xa.x + ra.x;
            float v1 = acc[t][1] + xa.y + ra.y;
            float v2 = acc[t][2] + xb2.x + rb.x;
            float v3 = acc[t][3] + xb2.y + rb.y;
            v0 = v0 > 0.f ? v0 : 0.2f * v0;
            v1 = v1 > 0.f ? v1 : 0.2f * v1;
            v2 = v2 > 0.f ? v2 : 0.2f * v2;
            v3 = v3 > 0.f ? v3 : 0.2f * v3;
            st[t] = att[t][0] * v0 + att[t][1] * v1 + att[t][2] * v2 + att[t][3] * v3;
        }
        #pragma unroll
        for (int t = 0; t < 8; t++) {
            st[t] += __shfl_xor(st[t], 16);
            st[t] += __shfl_xor(st[t], 32);
        }
        if (q == 0) {
            uint4 o;
            o.x = (uint32)f2bu(san(st[0])) | ((uint32)f2bu(san(st[1])) << 16);
            o.y = (uint32)f2bu(san(st[2])) | ((uint32)f2bu(san(st[3])) << 16);
            o.z = (uint32)f2bu(san(st[4])) | ((uint32)f2bu(san(st[5])) << 16);
            o.w = (uint32)f2bu(san(st[6])) | ((uint32)f2bu(san(st[7])) << 16);
            score16[row] = o;
        }
    }
}

__global__ void __launch_bounds__(256) k_agg(const ushort* __restrict__ scu,
                                             const int* __restrict__ csr, const int* __restrict__ offs,
                                             const int* __restrict__ eix,
                                             const uint32* __restrict__ xlu,
                                             const void* __restrict__ x,
                                             const float* __restrict__ wf,
                                             const int* __restrict__ flagp,
                                             uint4* __restrict__ x1) {
    int isf32 = flagp[0];
    int lane = threadIdx.x & 63;
    int n = (blockIdx.x * 256 + threadIdx.x) >> 6;
    int off = offs[n], deg = offs[n + 1] - off;
    int g = lane >> 3, hh = lane & 7;
    float mx = -1e30f;
    for (int i = g; i < deg; i += 8) {
        int e = csr[off + i];
        mx = fmaxf(mx, up1(scu[(long)e * 8 + hh]));
    }
    #pragma unroll
    for (int mask = 8; mask < 64; mask <<= 1)
        mx = fmaxf(mx, __shfl_xor(mx, mask));
    float s = 0.f;
    float acc[16];
    #pragma unroll
    for (int j = 0; j < 16; j++) acc[j] = 0.f;
    for (int i = g; i < deg; i += 8) {
        int e = csr[off + i];
        float ev = __expf(up1(scu[(long)e * 8 + hh]) - mx);
        s += ev;
        int srcn = (e < Ee) ? eix[e] : (e - Ee);
        uint4 a = ((const uint4*)xlu)[(long)srcn * 16 + hh * 2];
        uint4 b = ((const uint4*)xlu)[(long)srcn * 16 + hh * 2 + 1];
        float2 v0 = up2(a.x), v1 = up2(a.y), v2 = up2(a.z), v3 = up2(a.w);
        float2 v4 = up2(b.x), v5 = up2(b.y), v6 = up2(b.z), v7 = up2(b.w);
        acc[0] += ev * v0.x;  acc[1] += ev * v0.y;
        acc[2] += ev * v1.x;  acc[3] += ev * v1.y;
        acc[4] += ev * v2.x;  acc[5] += ev * v2.y;
        acc[6] += ev * v3.x;  acc[7] += ev * v3.y;
        acc[8] += ev * v4.x;  acc[9] += ev * v4.y;
        acc[10] += ev * v5.x; acc[11] += ev * v5.y;
        acc[12] += ev * v6.x; acc[13] += ev * v6.y;
        acc[14] += ev * v7.x; acc[15] += ev * v7.y;
    }
    #pragma unroll
    for (int mask = 8; mask < 64; mask <<= 1) {
        s += __shfl_xor(s, mask);
        #pragma unroll
        for (int j = 0; j < 16; j++) acc[j] += __shfl_xor(acc[j], mask);
    }
    float inv = 1.0f / s;
    float y[16];
    if (g == 0) {
        int d0 = hh * 16;
        if (isf32) {
            const float4* xf = (const float4*)x;
            #pragma unroll
            for (int c = 0; c < 4; c++) {
                float4 xv = xf[(long)n * 32 + hh * 4 + c];
                y[c*4+0] = acc[c*4+0] * inv + xv.x + wf[WF_bias + d0 + c*4+0];
                y[c*4+1] = acc[c*4+1] * inv + xv.y + wf[WF_bias + d0 + c*4+1];
                y[c*4+2] = acc[c*4+2] * inv + xv.z + wf[WF_bias + d0 + c*4+2];
                y[c*4+3] = acc[c*4+3] * inv + xv.w + wf[WF_bias + d0 + c*4+3];
            }
        } else {
            const uint4* xb = (const uint4*)x;
            uint4 a = xb[(long)n * 16 + hh * 2];
            uint4 b = xb[(long)n * 16 + hh * 2 + 1];
            uint32 ww[8] = {a.x, a.y, a.z, a.w, b.x, b.y, b.z, b.w};
            #pragma unroll
            for (int c = 0; c < 8; c++) {
                float2 v = up2(ww[c]);
                y[c*2+0] = acc[c*2+0] * inv + v.x + wf[WF_bias + d0 + c*2+0];
                y[c*2+1] = acc[c*2+1] * inv + v.y + wf[WF_bias + d0 + c*2+1];
            }
        }
    }
    float sum = 0.f, sq = 0.f;
    if (g == 0) {
        #pragma unroll
        for (int j = 0; j < 16; j++) { sum += y[j]; sq += y[j] * y[j]; }
    }
    #pragma unroll
    for (int mask = 1; mask < 8; mask <<= 1) { sum += __shfl_xor(sum, mask); sq += __shfl_xor(sq, mask); }
    if (g == 0) {
        int d0 = hh * 16;
        float mean = sum * (1.0f / 128.0f);
        float var = sq * (1.0f / 128.0f) - mean * mean;
        float rstd = rsqrtf(var + 1e-5f);
        uint32 o[8];
        #pragma unroll
        for (int c = 0; c < 8; c++) {
            float o0 = san((y[c*2+0] - mean) * rstd * wf[WF_g1 + d0 + c*2+0] + wf[WF_be1 + d0 + c*2+0]);
            float o1 = san((y[c*2+1] - mean) * rstd * wf[WF_g1 + d0 + c*2+1] + wf[WF_be1 + d0 + c*2+1]);
            o[c] = (uint32)f2bu(o0) | ((uint32)f2bu(o1) << 16);
        }
        x1[(long)n * 16 + hh * 2]     = make_uint4(o[0], o[1], o[2], o[3]);
        x1[(long)n * 16 + hh * 2 + 1] = make_uint4(o[4], o[5], o[6], o[7]);
    }
}

// ---------------- launch ----------------
extern "C" void kernel_launch(void* const* d_in, const int* in_sizes, int n_in,
                              void* d_out, int out_size, void* d_ws, size_t ws_size,
                              hipStream_t stream) {
    const void* x     = d_in[0];
    const int*  eraw  = (const int*)d_in[1];
    const void* eattr = d_in[2];
    char* wsb = (char*)d_ws;
    WSrc wsrc;
    for (int i = 0; i < 15; i++) wsrc.p[i] = d_in[3 + i];

    if (ws_size >= (size_t)NEED_A) {
        // ---- PLAN A: CSR-ordered edge pipeline ----
        ushort* eap = (ushort*)(wsb + A_EAP);
        int*   srcp = (int*)(wsb + A_SRC);
        int*   dstp = (int*)(wsb + A_DST);
        ushort* sc  = (ushort*)(wsb + A_SCO);
        int*   bsum = (int*)(wsb + A_SCO);
        int*   bpre = (int*)(wsb + A_SCO + 4096);
        ushort* Wls = (ushort*)(wsb + A_SCO);
        ushort* Wrs = (ushort*)(wsb + A_SCO + 32768);
        ushort* W1s = (ushort*)(wsb + A_SCO);
        ushort* W2s = (ushort*)(wsb + A_SCO + 131072);
        int*   eix  = (int*)(wsb + A_EIX);
        int*   cnt  = (int*)(wsb + A_CNT);
        int*   offs = (int*)(wsb + A_OFS);
        int*   cur  = (int*)(wsb + A_CUR);
        float* wf   = (float*)(wsb + A_WF);
        int*   flg  = (int*)(wsb + A_FLG);
        ushort* x1  = (ushort*)(wsb + A_EAP);
        ushort* xl  = (ushort*)d_out;
        ushort* xr  = (ushort*)d_out + (long)Nn * 128;

        hipMemsetAsync(cnt, 0, Nn * sizeof(int), stream);
        k_sniff<<<1, 64, 0, stream>>>((const uint32*)x, (const uint32*)eattr, flg);
        k_cvt<<<(2 * Ee + 255) / 256, 256, 0, stream>>>(eraw, eix, cnt);
        k_wcanon<<<(WF_TOT + 255) / 256, 256, 0, stream>>>(wsrc, flg, wf);
        k_scanA<<<SCAN_NB, 256, 0, stream>>>(cnt, bsum);
        k_scanB<<<1, 256, 0, stream>>>(bsum, bpre);
        k_scanC<<<SCAN_NB, 256, 0, stream>>>(cnt, bpre, offs, cur);
        k_wprepL<<<64, 256, 0, stream>>>(wf, Wls, Wrs);
        k_linlr<<<(Nn / 16 + 3) / 4, 256, 0, stream>>>(x, wf, Wls, Wrs, flg, xl, xr);
        k_fill2<<<Ee * 4 / 256, 256, 0, stream>>>(eix, eattr, flg, cur, offs, eap, srcp, dstp);
        k_self<<<(Nn + 3) / 4, 256, 0, stream>>>(offs, eap, srcp, dstp);
        k_score2<<<2048, 256, 0, stream>>>(eap, srcp, dstp, wf,
                                           (const uint32*)xl, (const uint32*)xr, (uint4*)sc);
        k_agg2<<<(Nn + 3) / 4, 256, 0, stream>>>(sc, offs, srcp, (const uint32*)xl,
                                                 x, wf, flg, (uint4*)x1);
        k_wprep<<<256, 256, 0, stream>>>(wf, W1s, W2s);
        k_ffn<<<(Nn + 31) / 32, 128, 0, stream>>>(x1, wf, W1s, W2s, (float*)d_out);
    } else {
        // ---- PLAN B: proven round-7 pipeline ----
        __hip_bfloat16* sc  = (__hip_bfloat16*)(wsb + B_SC);
        __hip_bfloat16* xl  = (__hip_bfloat16*)(wsb + B_XL);
        __hip_bfloat16* x1  = (__hip_bfloat16*)(wsb + B_X1);
        __hip_bfloat16* la  = (__hip_bfloat16*)(wsb + B_LA);
        int*   eix  = (int*)(wsb + B_EIX);
        int*   cnt  = (int*)(wsb + B_CNT);
        int*   offs = (int*)(wsb + B_OFS);
        int*   cur  = (int*)(wsb + B_CUR);
        int*   csr  = (int*)(wsb + B_CSR);
        float* wf   = (float*)(wsb + B_WF);
        int*   flg  = (int*)(wsb + B_FLG);
        __hip_bfloat16* xr  = (__hip_bfloat16*)d_out;
        ushort* W1s = (ushort*)(wsb + B_SC);
        ushort* W2s = (ushort*)(wsb + B_SC + 131072);

        hipMemsetAsync(cnt, 0, Nn * sizeof(int), stream);
        k_sniff<<<1, 64, 0, stream>>>((const uint32*)x, (const uint32*)eattr, flg);
        k_cvt<<<(2 * Ee + 255) / 256, 256, 0, stream>>>(eraw, eix, cnt);
        k_wcanon<<<(WF_TOT + 255) / 256, 256, 0, stream>>>(wsrc, flg, wf);
        k_scan<<<1, 1024, 0, stream>>>(cnt, offs, cur);
        k_fill<<<(EF + 255) / 256, 256, 0, stream>>>(eix, cur, offs, csr);
        k_loopattr<<<(Nn + 3) / 4, 256, 0, stream>>>(eattr, csr, offs, flg, la);
        k_lin<<<512, 256, 0, stream>>>(x, wf + WF_Wl, wf + WF_bl, flg, xl);
        k_lin<<<512, 256, 0, stream>>>(x, wf + WF_Wr, wf + WF_br, flg, xr);
        k_score<<<2048, 256, 0, stream>>>(eattr, eix, (const uint32*)la, wf, flg,
                                          (const uint32*)xl, (const uint32*)xr, (uint4*)sc);
        k_agg<<<(Nn + 3) / 4, 256, 0, stream>>>((const ushort*)sc, csr, offs, eix,
                                                (const uint32*)xl, x, wf, flg, (uint4*)x1);
        k_wprep<<<256, 256, 0, stream>>>(wf, W1s, W2s);
        k_ffn<<<(Nn + 31) / 32, 128, 0, stream>>>((const ushort*)x1, wf, W1s, W2s,
                                                  (float*)d_out);
    }
}